// Round 1
// 684.454 us; speedup vs baseline: 1.7997x; 1.7997x over previous
//
#include <hip/hip_runtime.h>
#include <hip/hip_bf16.h>
#include <stdint.h>

// Problem constants
#define B_    2
#define S_    4096
#define H_    1024
#define NKH_  8
#define NVH_  16
#define DK_   64
#define DV_   64
#define KEYD_ 512          // NKH*DK
#define CDIM_ 2048         // 2*KEYD + VAL_DIM
#define VALD_ 1024         // NVH*DV
#define NCHUNK_ 64         // S_/64
#define CS_   64           // chunk size

using bf16 = __hip_bfloat16;
using bf16x8 = __attribute__((ext_vector_type(8))) short;  // 8 bf16 = 4 VGPRs
using f32x4  = __attribute__((ext_vector_type(4))) float;

__device__ inline float bsh2f(short s) {
  union { ushort u; bf16 h; } c; c.u = (ushort)s; return __bfloat162float(c.h);
}
__device__ inline short f2bsh(float f) {
  union { ushort u; bf16 h; } c; c.h = __float2bfloat16(f); return (short)c.u;
}

// ---------------------------------------------------------------------------
// fp32 -> bf16 cast, 4 elems/thread (n % 4 == 0). (r2-validated structure)
// ---------------------------------------------------------------------------
__global__ __launch_bounds__(256) void castf2b(const float* __restrict__ x,
                                               bf16* __restrict__ y, long n) {
  const long i = ((long)blockIdx.x * 256 + threadIdx.x) * 4;
  if (i >= n) return;
  float4 v = *(const float4*)(x + i);
  union { ushort4 u; bf16 h[4]; } o;
  o.h[0] = __float2bfloat16(v.x);
  o.h[1] = __float2bfloat16(v.y);
  o.h[2] = __float2bfloat16(v.z);
  o.h[3] = __float2bfloat16(v.w);
  *(ushort4*)(y + i) = o.u;
}

// ---------------------------------------------------------------------------
// MFMA GEMM (r9-validated): C[m,n] = sum_k A[m,k]*B[n,k]; A,B bf16;
// C bf16 or fp32. 128x128 tile, 4 waves 2x2, 4x4 of 16x16x32 MFMA, BK=32.
// ---------------------------------------------------------------------------
template <typename OT>
__global__ __launch_bounds__(256) void gemm_bt(const bf16* __restrict__ A,
                                               const bf16* __restrict__ Bm,
                                               OT* __restrict__ C,
                                               int M, int N, int K) {
  __shared__ short Asm[128 * 32];
  __shared__ short Bsm[128 * 32];
  const int t = threadIdx.x;
  const int w = t >> 6, l = t & 63;
  const int ntn = N >> 7;
  const int bm = blockIdx.x / ntn, bn = blockIdx.x % ntn;
  const int m0 = bm << 7, n0 = bn << 7;
  const int wm = (w >> 1) << 6, wn = (w & 1) << 6;

  f32x4 acc[4][4] = {};

  const int srow = t >> 2;            // 0..63
  const int scol8 = (t & 3) << 3;     // 0,8,16,24
  const bf16* Ag = A + (long)(m0 + srow) * K + scol8;
  const bf16* Bg = Bm + (long)(n0 + srow) * K + scol8;
  const long rstep = (long)64 * K;

  const int lm = l & 15;
  const int kk = (l >> 4) << 3;
  const short* ar0 = &Asm[(wm + lm) * 32 + kk];
  const short* br0 = &Bsm[(wn + lm) * 32 + kk];

  for (int k0 = 0; k0 < K; k0 += 32) {
    bf16x8 a0 = *(const bf16x8*)(Ag + k0);
    bf16x8 a1 = *(const bf16x8*)(Ag + k0 + rstep);
    bf16x8 b0 = *(const bf16x8*)(Bg + k0);
    bf16x8 b1 = *(const bf16x8*)(Bg + k0 + rstep);
    __syncthreads();
    *(bf16x8*)&Asm[srow * 32 + scol8]        = a0;
    *(bf16x8*)&Asm[(64 + srow) * 32 + scol8] = a1;
    *(bf16x8*)&Bsm[srow * 32 + scol8]        = b0;
    *(bf16x8*)&Bsm[(64 + srow) * 32 + scol8] = b1;
    __syncthreads();
    bf16x8 af[4], bfr[4];
#pragma unroll
    for (int mi = 0; mi < 4; ++mi) af[mi] = *(const bf16x8*)(ar0 + mi * 16 * 32);
#pragma unroll
    for (int ni = 0; ni < 4; ++ni) bfr[ni] = *(const bf16x8*)(br0 + ni * 16 * 32);
#pragma unroll
    for (int mi = 0; mi < 4; ++mi)
#pragma unroll
      for (int ni = 0; ni < 4; ++ni)
        acc[mi][ni] = __builtin_amdgcn_mfma_f32_16x16x32_bf16(af[mi], bfr[ni],
                                                              acc[mi][ni], 0, 0, 0);
  }

  // C/D layout: col = l&15, row = (l>>4)*4 + reg
  const int r0 = (l >> 4) << 2;
  const int cn = l & 15;
#pragma unroll
  for (int mi = 0; mi < 4; ++mi)
#pragma unroll
    for (int ni = 0; ni < 4; ++ni) {
      long base = (long)(m0 + wm + mi * 16 + r0) * N + (n0 + wn + ni * 16 + cn);
#pragma unroll
      for (int r = 0; r < 4; ++r) {
        if constexpr (sizeof(OT) == 2)
          C[base + (long)r * N] = __float2bfloat16(acc[mi][ni][r]);
        else
          C[base + (long)r * N] = acc[mi][ni][r];
      }
    }
}

// ---------------------------------------------------------------------------
// conv2 (r8/r9-validated): causal depthwise k=4 cross-corr, silu, q-scale.
// ---------------------------------------------------------------------------
__global__ __launch_bounds__(256) void conv2(const bf16* __restrict__ mixed,
                                             const float* __restrict__ cw,
                                             bf16* __restrict__ qkv) {
  const long idx = (long)blockIdx.x * 256 + threadIdx.x;  // M*2048
  const int c = (int)(idx & (CDIM_ - 1));
  const long row = idx >> 11;
  const int s = (int)(row & (S_ - 1));
  float acc = 0.f;
#pragma unroll
  for (int j = 0; j < 4; ++j) {
    const int ss = s - 3 + j;
    if (ss >= 0)
      acc = fmaf(cw[c * 4 + j], (float)mixed[(row + j - 3) * CDIM_ + c], acc);
  }
  float y = acc / (1.f + __expf(-acc));        // silu
  if (c < KEYD_) y *= 0.125f;                  // q * DK^-0.5
  union { uint16_t u; bf16 h; } o; o.h = __float2bfloat16(y);
  ((uint16_t*)qkv)[row * CDIM_ + c] = o.u;
}

// ---------------------------------------------------------------------------
// proj_ba (r9-validated): beta=sigmoid(hs.Wb), g=-exp(A)*softplus(hs.Wa+dtb).
// ---------------------------------------------------------------------------
__global__ __launch_bounds__(256) void proj_ba(const float* __restrict__ hs,
                                               const float* __restrict__ Wb,
                                               const float* __restrict__ Wa,
                                               const float* __restrict__ dtb,
                                               const float* __restrict__ Alog,
                                               float* __restrict__ beta,
                                               float* __restrict__ g) {
  __shared__ float hrow[H_];
  const int row = blockIdx.x;
  const int t = threadIdx.x;
  const float* hp = hs + (long)row * H_;
  for (int i = t; i < H_; i += 256) hrow[i] = hp[i];
  __syncthreads();
  const int j = t >> 3;   // 0..31
  const int p = t & 7;    // 0..7
  const float* Wp = (j < 16) ? (Wb + (long)j * H_) : (Wa + (long)(j - 16) * H_);
  float acc = 0.f;
  for (int i = p; i < H_; i += 8) acc += hrow[i] * Wp[i];
  acc += __shfl_xor(acc, 1);
  acc += __shfl_xor(acc, 2);
  acc += __shfl_xor(acc, 4);
  if (p == 0) {
    if (j < 16) {
      beta[(long)row * NVH_ + j] = 1.f / (1.f + __expf(-acc));
    } else {
      const int hh = j - 16;
      const float x = acc + dtb[hh];
      const float sp = (x > 20.f) ? x : log1pf(__expf(x));
      g[(long)row * NVH_ + hh] = -__expf(Alog[hh]) * sp;
    }
  }
}

// ---------------------------------------------------------------------------
// chunk_pre: per (b,h,chunk) task, build the UT-transform matrices.
//   lg[t]   = cumsum of g within chunk  (stored for phase 2)
//   T[t,i]  = beta_t * exp(lg_t - lg_i) * (k_t . k_i),  i < t (strictly lower)
//   W  = (I+T)^{-1} diag(beta*exp(lg)) K     [64 x dk]  (bf16)
//   U0 = (I+T)^{-1} diag(beta) V             [64 x dv]  (bf16)
// Forward substitution in fp32, one column per thread (128 threads: 64 W cols
// + 64 U0 cols); x[64] fully unrolled so it stays in VGPRs.
// ---------------------------------------------------------------------------
__global__ __launch_bounds__(128) void chunk_pre(const bf16* __restrict__ qkv,
                                                 const float* __restrict__ beta,
                                                 const float* __restrict__ g,
                                                 bf16* __restrict__ Wws,
                                                 bf16* __restrict__ U0ws,
                                                 float* __restrict__ lgws) {
  __shared__ short Ksm[64][72];
  __shared__ short Vsm[64][72];
  __shared__ float Tsm[64][64];
  __shared__ float lgs[64];
  __shared__ float bts[64];

  const int task = blockIdx.x;        // ((b*16+h)*64 + c)
  const int c = task & 63;
  const int h = (task >> 6) & 15;
  const int b = task >> 10;
  const int kh = h >> 1;              // GQA repeat_interleave(2)
  const long t0 = (long)b * S_ + (long)c * CS_;
  const int tid = threadIdx.x;

  // stage K,V: 64 rows x 64 bf16. Thread: row=tid>>1, 32 shorts.
  {
    const int row = tid >> 1, off = (tid & 1) * 32;
    const bf16* kp = qkv + (t0 + row) * CDIM_ + KEYD_ + kh * 64 + off;
    const bf16* vp = qkv + (t0 + row) * CDIM_ + 2 * KEYD_ + h * 64 + off;
#pragma unroll
    for (int j = 0; j < 32; j += 8) {
      *(bf16x8*)&Ksm[row][off + j] = *(const bf16x8*)(kp + j);
      *(bf16x8*)&Vsm[row][off + j] = *(const bf16x8*)(vp + j);
    }
  }
  if (tid < 64) {
    bts[tid] = beta[(t0 + tid) * NVH_ + h];
    lgs[tid] = g[(t0 + tid) * NVH_ + h];
  }
  __syncthreads();
  if (tid == 0) {  // serial prefix sum (64 adds, negligible)
    float a = 0.f;
    for (int t = 0; t < CS_; ++t) { a += lgs[t]; lgs[t] = a; }
  }
  __syncthreads();

  // KK = K K^T -> T (masked, decayed). 2 waves x 2 m-tiles x 4 n-tiles.
  {
    const int wv = tid >> 6, l = tid & 63;
    const int lm = l & 15, lk = (l >> 4) << 3;
    f32x4 acc[2][4] = {};
#pragma unroll
    for (int ks = 0; ks < 2; ++ks) {
      bf16x8 bfr[4];
#pragma unroll
      for (int ni = 0; ni < 4; ++ni)
        bfr[ni] = *(const bf16x8*)&Ksm[ni * 16 + lm][lk + ks * 32];
#pragma unroll
      for (int mi = 0; mi < 2; ++mi) {
        bf16x8 afr = *(const bf16x8*)&Ksm[(wv * 2 + mi) * 16 + lm][lk + ks * 32];
#pragma unroll
        for (int ni = 0; ni < 4; ++ni)
          acc[mi][ni] = __builtin_amdgcn_mfma_f32_16x16x32_bf16(afr, bfr[ni],
                                                                acc[mi][ni], 0, 0, 0);
      }
    }
    const int r0 = (l >> 4) << 2, cn = l & 15;
#pragma unroll
    for (int mi = 0; mi < 2; ++mi)
#pragma unroll
      for (int ni = 0; ni < 4; ++ni)
#pragma unroll
        for (int r = 0; r < 4; ++r) {
          const int t = (wv * 2 + mi) * 16 + r0 + r;
          const int i = ni * 16 + cn;
          Tsm[t][i] = (i < t) ? bts[t] * __expf(lgs[t] - lgs[i]) * acc[mi][ni][r]
                              : 0.f;
        }
  }
  __syncthreads();

  // forward substitution: (I+T) x = rhs, one column per thread.
  const int colW = tid & 63;
  const bool isW = tid < 64;
  float x[64];
#pragma unroll
  for (int t = 0; t < CS_; ++t) {
    float rhs;
    if (isW) rhs = bts[t] * __expf(lgs[t]) * bsh2f(Ksm[t][colW]);
    else     rhs = bts[t] * bsh2f(Vsm[t][colW]);
#pragma unroll
    for (int j = 0; j < t; ++j) rhs -= Tsm[t][j] * x[j];  // Tsm row: LDS broadcast
    x[t] = rhs;
  }

  // store (coalesced per row: wave0 writes W rows, wave1 writes U0 rows)
  bf16* dst = (isW ? Wws : U0ws) + (long)task * 4096 + colW;
#pragma unroll
  for (int t = 0; t < CS_; ++t) dst[(long)t * 64] = __float2bfloat16(x[t]);
  if (tid < 64) lgws[(long)task * 64 + tid] = lgs[tid];
}

// ---------------------------------------------------------------------------
// chunk_scan: serial over 64 chunks, one workgroup per (b,h); 4 waves, wave w
// owns dv columns [16w, 16w+16). Per chunk (all MFMA 16x16x32 bf16):
//   A[t,i]  = (q_t.k_i) * exp(lg_t - lg_i), i<=t            (8 MFMA/wave, coop)
//   Dt[v,t] = U0[t,v] - (S0v . W^T)[v,t]                    (8 MFMA)
//   O[t,v]  = (e^{lg} q)_t . S0v  +  A . Dt                 (16 MFMA)
//   S[v,dk] = e^{lg_63} S + Dt . K'^T, K'[t]=e^{lg63-lg_t}k (8 MFMA)
// Master state in fp32 fragment registers; bf16 only on MFMA operands.
// ---------------------------------------------------------------------------
__global__ __launch_bounds__(256) void chunk_scan(const bf16* __restrict__ qkv,
                                                  const bf16* __restrict__ Wws,
                                                  const bf16* __restrict__ U0ws,
                                                  const float* __restrict__ lgws,
                                                  float* __restrict__ o) {
  __shared__ short Qsm[64][72];   // q rows (later scaled in place by exp(lg_t))
  __shared__ short Ksm[64][72];   // k rows
  __shared__ short Ktm[64][72];   // K'^T : [dk][t], decayed
  __shared__ short Wsm[64][72];   // W rows [t][dk]
  __shared__ short Usm[64][72];   // U0 rows [t][v]
  __shared__ short Amm[64][72];   // A rows [t][i]
  __shared__ short Dsm[64][72];   // Dt rows [v][t] (wave-private 16-row bands)
  __shared__ short Ssm[64][72];   // state bf16 [v][dk] (wave-private bands)
  __shared__ float lgs[64];

  const int hb = blockIdx.x;      // b*16+h
  const int h = hb & 15, b = hb >> 4, kh = h >> 1;
  const int tid = threadIdx.x, wv = tid >> 6, l = tid & 63;
  const int lm = l & 15, lk8 = (l >> 4) << 3;
  const int r0 = (l >> 4) << 2, cn = l & 15;
  const int srow = tid >> 2, scol = (tid & 3) * 16;  // staging map (16 shorts)

  for (int i = tid; i < 64 * 72; i += 256) ((short*)Ssm)[i] = 0;
  f32x4 Sreg[4] = {};   // fp32 master state: S[v=r0+r (wave band)][dk=ni*16+cn]

  for (int c = 0; c < NCHUNK_; ++c) {
    __syncthreads();  // previous iteration's reads done before restaging
    const long task = (long)hb * 64 + c;
    const long sb = (long)b * S_ + (long)c * CS_;
    {
      const bf16* qp = qkv + (sb + srow) * CDIM_ + kh * 64 + scol;
      const bf16* kp = qkv + (sb + srow) * CDIM_ + KEYD_ + kh * 64 + scol;
      const bf16* wp = Wws + task * 4096 + srow * 64 + scol;
      const bf16* up = U0ws + task * 4096 + srow * 64 + scol;
      *(bf16x8*)&Qsm[srow][scol]     = *(const bf16x8*)(qp);
      *(bf16x8*)&Qsm[srow][scol + 8] = *(const bf16x8*)(qp + 8);
      *(bf16x8*)&Ksm[srow][scol]     = *(const bf16x8*)(kp);
      *(bf16x8*)&Ksm[srow][scol + 8] = *(const bf16x8*)(kp + 8);
      *(bf16x8*)&Wsm[srow][scol]     = *(const bf16x8*)(wp);
      *(bf16x8*)&Wsm[srow][scol + 8] = *(const bf16x8*)(wp + 8);
      *(bf16x8*)&Usm[srow][scol]     = *(const bf16x8*)(up);
      *(bf16x8*)&Usm[srow][scol + 8] = *(const bf16x8*)(up + 8);
      if (tid < 64) lgs[tid] = lgws[task * 64 + tid];
    }
    __syncthreads();

    // A matrix: wave computes its 16 t-rows x all i.
    {
      f32x4 aacc[4] = {};
#pragma unroll
      for (int ks = 0; ks < 2; ++ks) {
        bf16x8 qa = *(const bf16x8*)&Qsm[wv * 16 + lm][lk8 + ks * 32];
#pragma unroll
        for (int ni = 0; ni < 4; ++ni) {
          bf16x8 kb = *(const bf16x8*)&Ksm[ni * 16 + lm][lk8 + ks * 32];
          aacc[ni] = __builtin_amdgcn_mfma_f32_16x16x32_bf16(qa, kb, aacc[ni], 0, 0, 0);
        }
      }
#pragma unroll
      for (int ni = 0; ni < 4; ++ni)
#pragma unroll
        for (int r = 0; r < 4; ++r) {
          const int t = wv * 16 + r0 + r, i = ni * 16 + cn;
          Amm[t][i] = f2bsh((i <= t) ? aacc[ni][r] * __expf(lgs[t] - lgs[i]) : 0.f);
        }
    }
    __syncthreads();  // all A-reads of Qsm done; now safe to scale Q in place

    {
      const float sc  = __expf(lgs[srow]);          // Lambda_t
      const float sce = __expf(lgs[63] - lgs[srow]);// K' decay
#pragma unroll
      for (int j = 0; j < 16; ++j) {
        const float qv = bsh2f(Qsm[srow][scol + j]);
        Qsm[srow][scol + j] = f2bsh(sc * qv);
        Ktm[scol + j][srow] = f2bsh(sce * bsh2f(Ksm[srow][scol + j]));  // transpose
      }
    }
    __syncthreads();

    // state fragments (shared as M1 A-operand and M2 B-operand)
    bf16x8 sfr[2];
    sfr[0] = *(const bf16x8*)&Ssm[wv * 16 + lm][lk8];
    sfr[1] = *(const bf16x8*)&Ssm[wv * 16 + lm][lk8 + 32];

    // M1': Dt[v,t] = U0[t,v] - sum_k S0v[v,k] W[t,k]
    {
      f32x4 dacc[4] = {};
#pragma unroll
      for (int ks = 0; ks < 2; ++ks)
#pragma unroll
        for (int ni = 0; ni < 4; ++ni) {
          bf16x8 wb = *(const bf16x8*)&Wsm[ni * 16 + lm][lk8 + ks * 32];
          dacc[ni] = __builtin_amdgcn_mfma_f32_16x16x32_bf16(sfr[ks], wb, dacc[ni], 0, 0, 0);
        }
#pragma unroll
      for (int ni = 0; ni < 4; ++ni)
#pragma unroll
        for (int r = 0; r < 4; ++r) {
          const int t = ni * 16 + cn, v = r0 + r;
          Dsm[wv * 16 + v][t] = f2bsh(bsh2f(Usm[t][wv * 16 + v]) - dacc[ni][r]);
        }
    }
    // wave-private Dsm: in-wave ds ordering + compiler lgkmcnt suffice (no barrier)
    bf16x8 dfr[2];
    dfr[0] = *(const bf16x8*)&Dsm[wv * 16 + lm][lk8];
    dfr[1] = *(const bf16x8*)&Dsm[wv * 16 + lm][lk8 + 32];

    // M2+M3: O[t, v16] = LambdaQ . S0v + A . Dt
    {
      f32x4 oacc[4] = {};
#pragma unroll
      for (int ks = 0; ks < 2; ++ks)
#pragma unroll
        for (int mi = 0; mi < 4; ++mi) {
          bf16x8 qa = *(const bf16x8*)&Qsm[mi * 16 + lm][lk8 + ks * 32];
          oacc[mi] = __builtin_amdgcn_mfma_f32_16x16x32_bf16(qa, sfr[ks], oacc[mi], 0, 0, 0);
        }
#pragma unroll
      for (int ks = 0; ks < 2; ++ks)
#pragma unroll
        for (int mi = 0; mi < 4; ++mi) {
          bf16x8 aa = *(const bf16x8*)&Amm[mi * 16 + lm][lk8 + ks * 32];
          oacc[mi] = __builtin_amdgcn_mfma_f32_16x16x32_bf16(aa, dfr[ks], oacc[mi], 0, 0, 0);
        }
#pragma unroll
      for (int mi = 0; mi < 4; ++mi)
#pragma unroll
        for (int r = 0; r < 4; ++r) {
          const int t = mi * 16 + r0 + r;
          o[(sb + t) * VALD_ + h * 64 + wv * 16 + cn] = oacc[mi][r];
        }
    }

    // M4: S[v,dk] = e^{lg63} S + sum_t Dt[v,t] K'[t,dk]
    {
      f32x4 kacc[4] = {};
#pragma unroll
      for (int ks = 0; ks < 2; ++ks)
#pragma unroll
        for (int ni = 0; ni < 4; ++ni) {
          bf16x8 kb = *(const bf16x8*)&Ktm[ni * 16 + lm][lk8 + ks * 32];
          kacc[ni] = __builtin_amdgcn_mfma_f32_16x16x32_bf16(dfr[ks], kb, kacc[ni], 0, 0, 0);
        }
      const float eend = __expf(lgs[63]);
#pragma unroll
      for (int ni = 0; ni < 4; ++ni)
#pragma unroll
        for (int r = 0; r < 4; ++r) {
          Sreg[ni][r] = eend * Sreg[ni][r] + kacc[ni][r];
          Ssm[wv * 16 + r0 + r][ni * 16 + cn] = f2bsh(Sreg[ni][r]);
        }
    }
  }
}

// ---------------------------------------------------------------------------
// gnorm2 (r9-validated): h = o*silu(z); rmsnorm; *w -> bf16 hn.
// ---------------------------------------------------------------------------
__global__ __launch_bounds__(256) void gnorm2(const float* __restrict__ o,
                                              const float* __restrict__ z,
                                              const float* __restrict__ nw,
                                              bf16* __restrict__ hn) {
  const long idx = (long)blockIdx.x * 256 + threadIdx.x;  // M*16
  const float* op = o + idx * 64;
  const float* zp = z + idx * 64;
  float hv[64];
  float ss = 0.f;
#pragma unroll
  for (int i = 0; i < 64; ++i) {
    const float zz = zp[i];
    const float hh = op[i] * (zz / (1.f + __expf(-zz)));
    hv[i] = hh;
    ss = fmaf(hh, hh, ss);
  }
  const float r = rsqrtf(ss * (1.f / 64.f) + 1e-6f);
#pragma unroll
  for (int i = 0; i < 64; ++i)
    hn[idx * 64 + i] = __float2bfloat16(hv[i] * r * nw[i]);
}

// ---------------------------------------------------------------------------
extern "C" void kernel_launch(void* const* d_in, const int* in_sizes, int n_in,
                              void* d_out, int out_size, void* d_ws, size_t ws_size,
                              hipStream_t stream) {
  float* out = (float*)d_out;   // fp32 output (r8-confirmed)
  const int M = B_ * S_;        // 8192

  // input mapping (dict order confirmed; size-based fallback kept)
  int ih, iqkv, icw, iz, ib, ia, idtb, ialog, inw, iout;
  if (n_in >= 10 && in_sizes[0] == 8388608) {
    ih = 0; iqkv = 1; icw = 2; iz = 3; ib = 4; ia = 5;
    idtb = 6; ialog = 7; inw = 8; iout = 9;
  } else {
    ih = iqkv = icw = iz = ib = ia = idtb = ialog = inw = iout = -1;
    for (int i = 0; i < n_in; ++i) {
      switch (in_sizes[i]) {
        case 8388608: ih = i; break;
        case 2097152: iqkv = i; break;
        case 8192:    icw = i; break;
        case 64:      inw = i; break;
        case 1048576: if (iz < 0) iz = i; else iout = i; break;
        case 16384:   if (ib < 0) ib = i; else ia = i; break;
        case 16:      if (idtb < 0) idtb = i; else ialog = i; break;
        default: break;
      }
    }
  }
  const float* hs   = (const float*)d_in[ih];
  const float* Wqkv = (const float*)d_in[iqkv];
  const float* cw   = (const float*)d_in[icw];
  const float* Wz   = (const float*)d_in[iz];
  const float* Wb   = (const float*)d_in[ib];
  const float* Wa   = (const float*)d_in[ia];
  const float* dtb  = (const float*)d_in[idtb];
  const float* Alog = (const float*)d_in[ialog];
  const float* nwv  = (const float*)d_in[inw];
  const float* Wout = (const float*)d_in[iout];

  // workspace (~106 MiB): r9 layout + W/U0/lg chunk buffers appended
  char* p = (char*)d_ws;
  bf16*  mixed = (bf16*)p;                                 // region1: 32 MiB
  float* of    = (float*)p; p += (size_t)M * CDIM_ * 2;    //   of aliases mixed
  bf16*  hs_b  = (bf16*)p;                                 // region2 (16 MiB; dead after z-gemm)
  bf16*  qkvb  = (bf16*)p;                                 //   full region2
  bf16*  hn    = (bf16*)p; p += (size_t)M * CDIM_ * 2;     //   hn aliases qkvb
  bf16*  Wqkv_b= (bf16*)p; p += (size_t)CDIM_ * H_ * 2;    // 4 MiB
  bf16*  Wz_b  = (bf16*)p; p += (size_t)H_ * H_ * 2;       // 2 MiB
  bf16*  Wout_b= (bf16*)p; p += (size_t)H_ * H_ * 2;       // 2 MiB
  float* betaf = (float*)p; p += (size_t)M * NVH_ * 4;     // 512 KiB
  float* gf    = (float*)p; p += (size_t)M * NVH_ * 4;     // 512 KiB
  bf16*  Wws   = (bf16*)p; p += (size_t)2048 * 4096 * 2;   // 16 MiB
  bf16*  U0ws  = (bf16*)p; p += (size_t)2048 * 4096 * 2;   // 16 MiB
  float* lgws  = (float*)p; p += (size_t)2048 * 64 * 4;    // 512 KiB
  float* zb    = out;   // z fp32 staged in d_out, consumed by gnorm2

  // 0) casts fp32 -> bf16 for MFMA operands
  {
    long n;
    n = (long)M * H_;     castf2b<<<(int)(n / 4 / 256), 256, 0, stream>>>(hs,   hs_b,   n);
    n = (long)CDIM_ * H_; castf2b<<<(int)(n / 4 / 256), 256, 0, stream>>>(Wqkv, Wqkv_b, n);
    n = (long)H_ * H_;    castf2b<<<(int)(n / 4 / 256), 256, 0, stream>>>(Wz,   Wz_b,   n);
    n = (long)H_ * H_;    castf2b<<<(int)(n / 4 / 256), 256, 0, stream>>>(Wout, Wout_b, n);
  }
  // 1) mixed = hs @ Wqkv^T  [8192 x 2048] -> bf16 (MFMA)
  gemm_bt<bf16><<<(M / 128) * (CDIM_ / 128), 256, 0, stream>>>(hs_b, Wqkv_b, mixed, M, CDIM_, H_);
  // 2) z = hs @ Wz^T  [8192 x 1024] -> fp32 in d_out (MFMA)
  gemm_bt<float><<<(M / 128) * (H_ / 128), 256, 0, stream>>>(hs_b, Wz_b, zb, M, H_, H_);
  // 3) beta, g
  proj_ba<<<M, 256, 0, stream>>>(hs, Wb, Wa, dtb, Alog, betaf, gf);
  // 4) causal depthwise conv + silu + q-scale -> bf16
  conv2<<<(int)(((long)M * CDIM_) / 256), 256, 0, stream>>>(mixed, cw, qkvb);
  // 5) chunked delta-rule: UT-transform precompute + chunk-serial MFMA scan
  chunk_pre<<<2048, 128, 0, stream>>>(qkvb, betaf, gf, Wws, U0ws, lgws);
  chunk_scan<<<32, 256, 0, stream>>>(qkvb, Wws, U0ws, lgws, of);
  // 6) gated RMSNorm -> hn bf16
  gnorm2<<<(M * NVH_) / 256, 256, 0, stream>>>(of, zb, nwv, hn);
  // 7) out = hn @ Wout^T -> d_out fp32 (MFMA)
  gemm_bt<float><<<(M / 128) * (H_ / 128), 256, 0, stream>>>(hn, Wout_b, out, M, H_, H_);
}

// Round 2
// 587.054 us; speedup vs baseline: 2.0983x; 1.1659x over previous
//
#include <hip/hip_runtime.h>
#include <hip/hip_bf16.h>
#include <stdint.h>

// Problem constants
#define B_    2
#define S_    4096
#define H_    1024
#define NKH_  8
#define NVH_  16
#define DK_   64
#define DV_   64
#define KEYD_ 512          // NKH*DK
#define CDIM_ 2048         // 2*KEYD + VAL_DIM
#define VALD_ 1024         // NVH*DV
#define NCHUNK_ 64         // S_/64
#define CS_   64           // chunk size

using bf16 = __hip_bfloat16;
using bf16x8 = __attribute__((ext_vector_type(8))) short;  // 8 bf16 = 4 VGPRs
using f32x4  = __attribute__((ext_vector_type(4))) float;

__device__ inline float bsh2f(short s) {
  union { ushort u; bf16 h; } c; c.u = (ushort)s; return __bfloat162float(c.h);
}
__device__ inline short f2bsh(float f) {
  union { ushort u; bf16 h; } c; c.h = __float2bfloat16(f); return (short)c.u;
}

// ---------------------------------------------------------------------------
// fp32 -> bf16 cast, 4 elems/thread (n % 4 == 0). (r2-validated structure)
// ---------------------------------------------------------------------------
__global__ __launch_bounds__(256) void castf2b(const float* __restrict__ x,
                                               bf16* __restrict__ y, long n) {
  const long i = ((long)blockIdx.x * 256 + threadIdx.x) * 4;
  if (i >= n) return;
  float4 v = *(const float4*)(x + i);
  union { ushort4 u; bf16 h[4]; } o;
  o.h[0] = __float2bfloat16(v.x);
  o.h[1] = __float2bfloat16(v.y);
  o.h[2] = __float2bfloat16(v.z);
  o.h[3] = __float2bfloat16(v.w);
  *(ushort4*)(y + i) = o.u;
}

// ---------------------------------------------------------------------------
// MFMA GEMM (r9-validated): C[m,n] = sum_k A[m,k]*B[n,k]; A,B bf16;
// C bf16 or fp32. 128x128 tile, 4 waves 2x2, 4x4 of 16x16x32 MFMA, BK=32.
// ---------------------------------------------------------------------------
template <typename OT>
__global__ __launch_bounds__(256) void gemm_bt(const bf16* __restrict__ A,
                                               const bf16* __restrict__ Bm,
                                               OT* __restrict__ C,
                                               int M, int N, int K) {
  __shared__ short Asm[128 * 32];
  __shared__ short Bsm[128 * 32];
  const int t = threadIdx.x;
  const int w = t >> 6, l = t & 63;
  const int ntn = N >> 7;
  const int bm = blockIdx.x / ntn, bn = blockIdx.x % ntn;
  const int m0 = bm << 7, n0 = bn << 7;
  const int wm = (w >> 1) << 6, wn = (w & 1) << 6;

  f32x4 acc[4][4] = {};

  const int srow = t >> 2;            // 0..63
  const int scol8 = (t & 3) << 3;     // 0,8,16,24
  const bf16* Ag = A + (long)(m0 + srow) * K + scol8;
  const bf16* Bg = Bm + (long)(n0 + srow) * K + scol8;
  const long rstep = (long)64 * K;

  const int lm = l & 15;
  const int kk = (l >> 4) << 3;
  const short* ar0 = &Asm[(wm + lm) * 32 + kk];
  const short* br0 = &Bsm[(wn + lm) * 32 + kk];

  for (int k0 = 0; k0 < K; k0 += 32) {
    bf16x8 a0 = *(const bf16x8*)(Ag + k0);
    bf16x8 a1 = *(const bf16x8*)(Ag + k0 + rstep);
    bf16x8 b0 = *(const bf16x8*)(Bg + k0);
    bf16x8 b1 = *(const bf16x8*)(Bg + k0 + rstep);
    __syncthreads();
    *(bf16x8*)&Asm[srow * 32 + scol8]        = a0;
    *(bf16x8*)&Asm[(64 + srow) * 32 + scol8] = a1;
    *(bf16x8*)&Bsm[srow * 32 + scol8]        = b0;
    *(bf16x8*)&Bsm[(64 + srow) * 32 + scol8] = b1;
    __syncthreads();
    bf16x8 af[4], bfr[4];
#pragma unroll
    for (int mi = 0; mi < 4; ++mi) af[mi] = *(const bf16x8*)(ar0 + mi * 16 * 32);
#pragma unroll
    for (int ni = 0; ni < 4; ++ni) bfr[ni] = *(const bf16x8*)(br0 + ni * 16 * 32);
#pragma unroll
    for (int mi = 0; mi < 4; ++mi)
#pragma unroll
      for (int ni = 0; ni < 4; ++ni)
        acc[mi][ni] = __builtin_amdgcn_mfma_f32_16x16x32_bf16(af[mi], bfr[ni],
                                                              acc[mi][ni], 0, 0, 0);
  }

  // C/D layout: col = l&15, row = (l>>4)*4 + reg
  const int r0 = (l >> 4) << 2;
  const int cn = l & 15;
#pragma unroll
  for (int mi = 0; mi < 4; ++mi)
#pragma unroll
    for (int ni = 0; ni < 4; ++ni) {
      long base = (long)(m0 + wm + mi * 16 + r0) * N + (n0 + wn + ni * 16 + cn);
#pragma unroll
      for (int r = 0; r < 4; ++r) {
        if constexpr (sizeof(OT) == 2)
          C[base + (long)r * N] = __float2bfloat16(acc[mi][ni][r]);
        else
          C[base + (long)r * N] = acc[mi][ni][r];
      }
    }
}

// ---------------------------------------------------------------------------
// conv2 (r8/r9-validated): causal depthwise k=4 cross-corr, silu, q-scale.
// ---------------------------------------------------------------------------
__global__ __launch_bounds__(256) void conv2(const bf16* __restrict__ mixed,
                                             const float* __restrict__ cw,
                                             bf16* __restrict__ qkv) {
  const long idx = (long)blockIdx.x * 256 + threadIdx.x;  // M*2048
  const int c = (int)(idx & (CDIM_ - 1));
  const long row = idx >> 11;
  const int s = (int)(row & (S_ - 1));
  float acc = 0.f;
#pragma unroll
  for (int j = 0; j < 4; ++j) {
    const int ss = s - 3 + j;
    if (ss >= 0)
      acc = fmaf(cw[c * 4 + j], (float)mixed[(row + j - 3) * CDIM_ + c], acc);
  }
  float y = acc / (1.f + __expf(-acc));        // silu
  if (c < KEYD_) y *= 0.125f;                  // q * DK^-0.5
  union { uint16_t u; bf16 h; } o; o.h = __float2bfloat16(y);
  ((uint16_t*)qkv)[row * CDIM_ + c] = o.u;
}

// ---------------------------------------------------------------------------
// proj_ba (r9-validated): beta=sigmoid(hs.Wb), g=-exp(A)*softplus(hs.Wa+dtb).
// ---------------------------------------------------------------------------
__global__ __launch_bounds__(256) void proj_ba(const float* __restrict__ hs,
                                               const float* __restrict__ Wb,
                                               const float* __restrict__ Wa,
                                               const float* __restrict__ dtb,
                                               const float* __restrict__ Alog,
                                               float* __restrict__ beta,
                                               float* __restrict__ g) {
  __shared__ float hrow[H_];
  const int row = blockIdx.x;
  const int t = threadIdx.x;
  const float* hp = hs + (long)row * H_;
  for (int i = t; i < H_; i += 256) hrow[i] = hp[i];
  __syncthreads();
  const int j = t >> 3;   // 0..31
  const int p = t & 7;    // 0..7
  const float* Wp = (j < 16) ? (Wb + (long)j * H_) : (Wa + (long)(j - 16) * H_);
  float acc = 0.f;
  for (int i = p; i < H_; i += 8) acc += hrow[i] * Wp[i];
  acc += __shfl_xor(acc, 1);
  acc += __shfl_xor(acc, 2);
  acc += __shfl_xor(acc, 4);
  if (p == 0) {
    if (j < 16) {
      beta[(long)row * NVH_ + j] = 1.f / (1.f + __expf(-acc));
    } else {
      const int hh = j - 16;
      const float x = acc + dtb[hh];
      const float sp = (x > 20.f) ? x : log1pf(__expf(x));
      g[(long)row * NVH_ + hh] = -__expf(Alog[hh]) * sp;
    }
  }
}

// ---------------------------------------------------------------------------
// chunk_pre (r1-validated): per (b,h,chunk) task, build UT-transform matrices.
//   lg[t]   = cumsum of g within chunk  (stored for later phases)
//   T[t,i]  = beta_t * exp(lg_t - lg_i) * (k_t . k_i),  i < t (strictly lower)
//   W  = (I+T)^{-1} diag(beta*exp(lg)) K     [64 x dk]  (bf16)
//   U0 = (I+T)^{-1} diag(beta) V             [64 x dv]  (bf16)
// ---------------------------------------------------------------------------
__global__ __launch_bounds__(128) void chunk_pre(const bf16* __restrict__ qkv,
                                                 const float* __restrict__ beta,
                                                 const float* __restrict__ g,
                                                 bf16* __restrict__ Wws,
                                                 bf16* __restrict__ U0ws,
                                                 float* __restrict__ lgws) {
  __shared__ short Ksm[64][72];
  __shared__ short Vsm[64][72];
  __shared__ float Tsm[64][64];
  __shared__ float lgs[64];
  __shared__ float bts[64];

  const int task = blockIdx.x;        // ((b*16+h)*64 + c)
  const int c = task & 63;
  const int h = (task >> 6) & 15;
  const int b = task >> 10;
  const int kh = h >> 1;              // GQA repeat_interleave(2)
  const long t0 = (long)b * S_ + (long)c * CS_;
  const int tid = threadIdx.x;

  // stage K,V: 64 rows x 64 bf16. Thread: row=tid>>1, 32 shorts.
  {
    const int row = tid >> 1, off = (tid & 1) * 32;
    const bf16* kp = qkv + (t0 + row) * CDIM_ + KEYD_ + kh * 64 + off;
    const bf16* vp = qkv + (t0 + row) * CDIM_ + 2 * KEYD_ + h * 64 + off;
#pragma unroll
    for (int j = 0; j < 32; j += 8) {
      *(bf16x8*)&Ksm[row][off + j] = *(const bf16x8*)(kp + j);
      *(bf16x8*)&Vsm[row][off + j] = *(const bf16x8*)(vp + j);
    }
  }
  if (tid < 64) {
    bts[tid] = beta[(t0 + tid) * NVH_ + h];
    lgs[tid] = g[(t0 + tid) * NVH_ + h];
  }
  __syncthreads();
  if (tid == 0) {  // serial prefix sum (64 adds, negligible)
    float a = 0.f;
    for (int t = 0; t < CS_; ++t) { a += lgs[t]; lgs[t] = a; }
  }
  __syncthreads();

  // KK = K K^T -> T (masked, decayed). 2 waves x 2 m-tiles x 4 n-tiles.
  {
    const int wv = tid >> 6, l = tid & 63;
    const int lm = l & 15, lk = (l >> 4) << 3;
    f32x4 acc[2][4] = {};
#pragma unroll
    for (int ks = 0; ks < 2; ++ks) {
      bf16x8 bfr[4];
#pragma unroll
      for (int ni = 0; ni < 4; ++ni)
        bfr[ni] = *(const bf16x8*)&Ksm[ni * 16 + lm][lk + ks * 32];
#pragma unroll
      for (int mi = 0; mi < 2; ++mi) {
        bf16x8 afr = *(const bf16x8*)&Ksm[(wv * 2 + mi) * 16 + lm][lk + ks * 32];
#pragma unroll
        for (int ni = 0; ni < 4; ++ni)
          acc[mi][ni] = __builtin_amdgcn_mfma_f32_16x16x32_bf16(afr, bfr[ni],
                                                                acc[mi][ni], 0, 0, 0);
      }
    }
    const int r0 = (l >> 4) << 2, cn = l & 15;
#pragma unroll
    for (int mi = 0; mi < 2; ++mi)
#pragma unroll
      for (int ni = 0; ni < 4; ++ni)
#pragma unroll
        for (int r = 0; r < 4; ++r) {
          const int t = (wv * 2 + mi) * 16 + r0 + r;
          const int i = ni * 16 + cn;
          Tsm[t][i] = (i < t) ? bts[t] * __expf(lgs[t] - lgs[i]) * acc[mi][ni][r]
                              : 0.f;
        }
  }
  __syncthreads();

  // forward substitution: (I+T) x = rhs, one column per thread.
  const int colW = tid & 63;
  const bool isW = tid < 64;
  float x[64];
#pragma unroll
  for (int t = 0; t < CS_; ++t) {
    float rhs;
    if (isW) rhs = bts[t] * __expf(lgs[t]) * bsh2f(Ksm[t][colW]);
    else     rhs = bts[t] * bsh2f(Vsm[t][colW]);
#pragma unroll
    for (int j = 0; j < t; ++j) rhs -= Tsm[t][j] * x[j];  // Tsm row: LDS broadcast
    x[t] = rhs;
  }

  // store (coalesced per row: wave0 writes W rows, wave1 writes U0 rows)
  bf16* dst = (isW ? Wws : U0ws) + (long)task * 4096 + colW;
#pragma unroll
  for (int t = 0; t < CS_; ++t) dst[(long)t * 64] = __float2bfloat16(x[t]);
  if (tid < 64) lgws[(long)task * 64 + tid] = lgs[tid];
}

// ---------------------------------------------------------------------------
// chunk_mb (new): per chunk, the affine state-transition pieces:
//   K'[t,k]   = exp(lg63 - lg_t) * k[t,k]
//   McT[k',k] = -sum_t K'[t,k'] * W[t,k]      [dk x dk]  (bf16)
//   Bc[v,k']  =  sum_t U0[t,v]  * K'[t,k']    [dv x dk]  (bf16)
// so that S_{c+1}[v,k'] = e^{lg63} S_c[v,k'] + sum_k S_c[v,k] McT[k',k] + Bc.
// Fully parallel over 2048 tasks; MFMA after LDS transposes.
// ---------------------------------------------------------------------------
__global__ __launch_bounds__(256) void chunk_mb(const bf16* __restrict__ qkv,
                                                const bf16* __restrict__ Wws,
                                                const bf16* __restrict__ U0ws,
                                                const float* __restrict__ lgws,
                                                bf16* __restrict__ McT,
                                                bf16* __restrict__ Bc) {
  __shared__ short Ksm[64][72];
  __shared__ short Wsm[64][72];
  __shared__ short Usm[64][72];
  __shared__ short KpT[64][72];   // K'^T rows [k][t]
  __shared__ short WT[64][72];    // W^T  rows [k][t]
  __shared__ short U0T[64][72];   // U0^T rows [v][t]
  __shared__ float lgs[64];

  const int blk = blockIdx.x;
  const int hb = blk & 31, c = blk >> 5;      // hb fast: qkv-row L2 reuse
  const long task = (long)hb * 64 + c;
  const int h = hb & 15, b = hb >> 4, kh = h >> 1;
  const long sb = (long)b * S_ + (long)c * CS_;
  const int tid = threadIdx.x, wv = tid >> 6, l = tid & 63;
  const int lm = l & 15, lk8 = (l >> 4) << 3;
  const int r0 = (l >> 4) << 2, cn = l & 15;
  const int srow = tid >> 2, scol = (tid & 3) * 16;

  // stage K, W, U0 (16 shorts / thread / matrix) + lgs
  {
    const bf16* kp = qkv + (sb + srow) * CDIM_ + KEYD_ + kh * 64 + scol;
    const bf16* wp = Wws + task * 4096 + srow * 64 + scol;
    const bf16* up = U0ws + task * 4096 + srow * 64 + scol;
    *(bf16x8*)&Ksm[srow][scol]     = *(const bf16x8*)(kp);
    *(bf16x8*)&Ksm[srow][scol + 8] = *(const bf16x8*)(kp + 8);
    *(bf16x8*)&Wsm[srow][scol]     = *(const bf16x8*)(wp);
    *(bf16x8*)&Wsm[srow][scol + 8] = *(const bf16x8*)(wp + 8);
    *(bf16x8*)&Usm[srow][scol]     = *(const bf16x8*)(up);
    *(bf16x8*)&Usm[srow][scol + 8] = *(const bf16x8*)(up + 8);
    if (tid < 64) lgs[tid] = lgws[task * 64 + tid];
  }
  __syncthreads();

  // transpose (+ K' decay on t=srow)
  {
    const float dec = __expf(lgs[63] - lgs[srow]);
#pragma unroll
    for (int j = 0; j < 16; ++j) {
      WT[scol + j][srow]  = Wsm[srow][scol + j];
      U0T[scol + j][srow] = Usm[srow][scol + j];
      KpT[scol + j][srow] = f2bsh(dec * bsh2f(Ksm[srow][scol + j]));
    }
  }
  __syncthreads();

  // McT = -(K'^T)(W^T)^T : C[m=k'][n=k] = sum_t KpT[k'][t] WT[k][t]
  {
    f32x4 macc[4] = {};
#pragma unroll
    for (int ks = 0; ks < 2; ++ks) {
      bf16x8 afr = *(const bf16x8*)&KpT[wv * 16 + lm][lk8 + ks * 32];
#pragma unroll
      for (int ni = 0; ni < 4; ++ni) {
        bf16x8 bfr = *(const bf16x8*)&WT[ni * 16 + lm][lk8 + ks * 32];
        macc[ni] = __builtin_amdgcn_mfma_f32_16x16x32_bf16(afr, bfr, macc[ni], 0, 0, 0);
      }
    }
#pragma unroll
    for (int ni = 0; ni < 4; ++ni)
#pragma unroll
      for (int r = 0; r < 4; ++r)
        McT[task * 4096 + (wv * 16 + r0 + r) * 64 + ni * 16 + cn] =
            __float2bfloat16(-macc[ni][r]);
  }
  // Bc : C[m=v][n=k'] = sum_t U0T[v][t] KpT[k'][t]
  {
    f32x4 bacc[4] = {};
#pragma unroll
    for (int ks = 0; ks < 2; ++ks) {
      bf16x8 afr = *(const bf16x8*)&U0T[wv * 16 + lm][lk8 + ks * 32];
#pragma unroll
      for (int ni = 0; ni < 4; ++ni) {
        bf16x8 bfr = *(const bf16x8*)&KpT[ni * 16 + lm][lk8 + ks * 32];
        bacc[ni] = __builtin_amdgcn_mfma_f32_16x16x32_bf16(afr, bfr, bacc[ni], 0, 0, 0);
      }
    }
#pragma unroll
    for (int ni = 0; ni < 4; ++ni)
#pragma unroll
      for (int r = 0; r < 4; ++r)
        Bc[task * 4096 + (wv * 16 + r0 + r) * 64 + ni * 16 + cn] =
            __float2bfloat16(bacc[ni][r]);
  }
}

// ---------------------------------------------------------------------------
// chunk_state (new): serial over 64 chunks, one WG per (b,h); light per step:
//   store Sbound[c] = S_c (start-of-chunk state, bf16)
//   S_{c+1} = e^{lg63_c} * S_c (fp32 regs)  +  S_c_bf16 . McT_c (8 MFMA/wave)
//             + Bc_c
// Mc/Bc prefetched 2 chunks ahead into triple-buffered LDS -> HBM/L2 latency
// off the serial critical path. fp32 master state preserved (decay path).
// ---------------------------------------------------------------------------
__global__ __launch_bounds__(256) void chunk_state(const bf16* __restrict__ McT,
                                                   const bf16* __restrict__ Bc,
                                                   const float* __restrict__ lgws,
                                                   bf16* __restrict__ Sb) {
  __shared__ short Msm[3][64][72];
  __shared__ short Bsm[3][64][72];
  __shared__ short Ssm[64][72];   // bf16 state rows [v][k] (wave-private bands)
  __shared__ float lgb[3];

  const int hb = blockIdx.x;      // b*16+h
  const int tid = threadIdx.x, wv = tid >> 6, l = tid & 63;
  const int lm = l & 15, lk8 = (l >> 4) << 3;
  const int r0 = (l >> 4) << 2, cn = l & 15;
  const int srow = tid >> 2, scol = (tid & 3) * 16;

  for (int i = tid; i < 64 * 72; i += 256) ((short*)Ssm)[i] = 0;
  f32x4 Sreg[4] = {};   // fp32 master: S[v = wv*16+r0+r][k = ni*16+cn]

  auto stage = [&](int cc, int bu) {
    const long tt = (long)hb * 64 + cc;
    const bf16* mp = McT + tt * 4096 + srow * 64 + scol;
    const bf16* bp = Bc + tt * 4096 + srow * 64 + scol;
    *(bf16x8*)&Msm[bu][srow][scol]     = *(const bf16x8*)(mp);
    *(bf16x8*)&Msm[bu][srow][scol + 8] = *(const bf16x8*)(mp + 8);
    *(bf16x8*)&Bsm[bu][srow][scol]     = *(const bf16x8*)(bp);
    *(bf16x8*)&Bsm[bu][srow][scol + 8] = *(const bf16x8*)(bp + 8);
    if (tid == 0) lgb[bu] = lgws[tt * 64 + 63];
  };
  stage(0, 0);
  stage(1, 1);

  for (int c = 0; c < NCHUNK_; ++c) {
    __syncthreads();   // buf[c%3] staging complete; prev-step reads done
    if (c + 2 < NCHUNK_) stage(c + 2, (c + 2) % 3);
    const int bu = c % 3;

    // store boundary state S_c (start of chunk c); off critical path
    {
      bf16* sp = Sb + ((long)hb * 64 + c) * 4096;
#pragma unroll
      for (int ni = 0; ni < 4; ++ni)
#pragma unroll
        for (int r = 0; r < 4; ++r)
          sp[(wv * 16 + r0 + r) * 64 + ni * 16 + cn] = __float2bfloat16(Sreg[ni][r]);
    }

    bf16x8 sfr0 = *(const bf16x8*)&Ssm[wv * 16 + lm][lk8];
    bf16x8 sfr1 = *(const bf16x8*)&Ssm[wv * 16 + lm][lk8 + 32];
    f32x4 kacc[4] = {};
#pragma unroll
    for (int ni = 0; ni < 4; ++ni) {
      bf16x8 b0 = *(const bf16x8*)&Msm[bu][ni * 16 + lm][lk8];
      kacc[ni] = __builtin_amdgcn_mfma_f32_16x16x32_bf16(sfr0, b0, kacc[ni], 0, 0, 0);
      bf16x8 b1 = *(const bf16x8*)&Msm[bu][ni * 16 + lm][lk8 + 32];
      kacc[ni] = __builtin_amdgcn_mfma_f32_16x16x32_bf16(sfr1, b1, kacc[ni], 0, 0, 0);
    }
    const float eend = __expf(lgb[bu]);
#pragma unroll
    for (int ni = 0; ni < 4; ++ni)
#pragma unroll
      for (int r = 0; r < 4; ++r) {
        const float bv = bsh2f(Bsm[bu][wv * 16 + r0 + r][ni * 16 + cn]);
        Sreg[ni][r] = eend * Sreg[ni][r] + kacc[ni][r] + bv;
        Ssm[wv * 16 + r0 + r][ni * 16 + cn] = f2bsh(Sreg[ni][r]);
      }
  }
}

// ---------------------------------------------------------------------------
// chunk_out (new): fully parallel over 2048 (b,h,chunk) tasks. Old chunk_scan
// body minus the serial loop / Ktm / M4; S0 read from Sbound.
//   A[t,i]  = (q_t.k_i) * exp(lg_t - lg_i), i<=t
//   Dt[v,t] = U0[t,v] - (S0v . W^T)[v,t]
//   O[t,v]  = (e^{lg} q)_t . S0v  +  A . Dt
// ---------------------------------------------------------------------------
__global__ __launch_bounds__(256) void chunk_out(const bf16* __restrict__ qkv,
                                                 const bf16* __restrict__ Wws,
                                                 const bf16* __restrict__ U0ws,
                                                 const float* __restrict__ lgws,
                                                 const bf16* __restrict__ Sb,
                                                 float* __restrict__ o) {
  __shared__ short Qsm[64][72];   // q rows (later scaled in place by exp(lg_t))
  __shared__ short Ksm[64][72];   // k rows
  __shared__ short Wsm[64][72];   // W rows [t][dk]
  __shared__ short Usm[64][72];   // U0 rows [t][v]
  __shared__ short Amm[64][72];   // A rows [t][i]
  __shared__ short Dsm[64][72];   // Dt rows [v][t] (wave-private 16-row bands)
  __shared__ float lgs[64];

  const int blk = blockIdx.x;
  const int hb = blk & 31, c = blk >> 5;      // hb fast: qkv-row L2 reuse
  const long task = (long)hb * 64 + c;
  const int h = hb & 15, b = hb >> 4, kh = h >> 1;
  const long sb = (long)b * S_ + (long)c * CS_;
  const int tid = threadIdx.x, wv = tid >> 6, l = tid & 63;
  const int lm = l & 15, lk8 = (l >> 4) << 3;
  const int r0 = (l >> 4) << 2, cn = l & 15;
  const int srow = tid >> 2, scol = (tid & 3) * 16;

  // S0 fragments straight from global (issued early; L2-resident after
  // chunk_state). Rows [v][k], wave band wv.
  const bf16* sp = Sb + task * 4096 + (wv * 16 + lm) * 64 + lk8;
  bf16x8 sfr0 = *(const bf16x8*)(sp);
  bf16x8 sfr1 = *(const bf16x8*)(sp + 32);

  {
    const bf16* qp = qkv + (sb + srow) * CDIM_ + kh * 64 + scol;
    const bf16* kp = qkv + (sb + srow) * CDIM_ + KEYD_ + kh * 64 + scol;
    const bf16* wp = Wws + task * 4096 + srow * 64 + scol;
    const bf16* up = U0ws + task * 4096 + srow * 64 + scol;
    *(bf16x8*)&Qsm[srow][scol]     = *(const bf16x8*)(qp);
    *(bf16x8*)&Qsm[srow][scol + 8] = *(const bf16x8*)(qp + 8);
    *(bf16x8*)&Ksm[srow][scol]     = *(const bf16x8*)(kp);
    *(bf16x8*)&Ksm[srow][scol + 8] = *(const bf16x8*)(kp + 8);
    *(bf16x8*)&Wsm[srow][scol]     = *(const bf16x8*)(wp);
    *(bf16x8*)&Wsm[srow][scol + 8] = *(const bf16x8*)(wp + 8);
    *(bf16x8*)&Usm[srow][scol]     = *(const bf16x8*)(up);
    *(bf16x8*)&Usm[srow][scol + 8] = *(const bf16x8*)(up + 8);
    if (tid < 64) lgs[tid] = lgws[task * 64 + tid];
  }
  __syncthreads();

  // A matrix: wave computes its 16 t-rows x all i.
  {
    f32x4 aacc[4] = {};
#pragma unroll
    for (int ks = 0; ks < 2; ++ks) {
      bf16x8 qa = *(const bf16x8*)&Qsm[wv * 16 + lm][lk8 + ks * 32];
#pragma unroll
      for (int ni = 0; ni < 4; ++ni) {
        bf16x8 kb = *(const bf16x8*)&Ksm[ni * 16 + lm][lk8 + ks * 32];
        aacc[ni] = __builtin_amdgcn_mfma_f32_16x16x32_bf16(qa, kb, aacc[ni], 0, 0, 0);
      }
    }
#pragma unroll
    for (int ni = 0; ni < 4; ++ni)
#pragma unroll
      for (int r = 0; r < 4; ++r) {
        const int t = wv * 16 + r0 + r, i = ni * 16 + cn;
        Amm[t][i] = f2bsh((i <= t) ? aacc[ni][r] * __expf(lgs[t] - lgs[i]) : 0.f);
      }
  }
  __syncthreads();  // all A-reads of Qsm done; now safe to scale Q in place

  {
    const float sc = __expf(lgs[srow]);       // Lambda_t
#pragma unroll
    for (int j = 0; j < 16; ++j)
      Qsm[srow][scol + j] = f2bsh(sc * bsh2f(Qsm[srow][scol + j]));
  }
  __syncthreads();

  // M1: Dt[v,t] = U0[t,v] - sum_k S0v[v,k] W[t,k]
  {
    f32x4 dacc[4] = {};
#pragma unroll
    for (int ni = 0; ni < 4; ++ni) {
      bf16x8 w0 = *(const bf16x8*)&Wsm[ni * 16 + lm][lk8];
      dacc[ni] = __builtin_amdgcn_mfma_f32_16x16x32_bf16(sfr0, w0, dacc[ni], 0, 0, 0);
      bf16x8 w1 = *(const bf16x8*)&Wsm[ni * 16 + lm][lk8 + 32];
      dacc[ni] = __builtin_amdgcn_mfma_f32_16x16x32_bf16(sfr1, w1, dacc[ni], 0, 0, 0);
    }
#pragma unroll
    for (int ni = 0; ni < 4; ++ni)
#pragma unroll
      for (int r = 0; r < 4; ++r) {
        const int t = ni * 16 + cn, v = r0 + r;
        Dsm[wv * 16 + v][t] = f2bsh(bsh2f(Usm[t][wv * 16 + v]) - dacc[ni][r]);
      }
  }
  // wave-private Dsm: in-wave ds ordering + compiler lgkmcnt suffice (no barrier)
  bf16x8 dfr0 = *(const bf16x8*)&Dsm[wv * 16 + lm][lk8];
  bf16x8 dfr1 = *(const bf16x8*)&Dsm[wv * 16 + lm][lk8 + 32];

  // M2+M3: O[t, v16] = LambdaQ . S0v + A . Dt
  {
    f32x4 oacc[4] = {};
#pragma unroll
    for (int mi = 0; mi < 4; ++mi) {
      bf16x8 q0 = *(const bf16x8*)&Qsm[mi * 16 + lm][lk8];
      oacc[mi] = __builtin_amdgcn_mfma_f32_16x16x32_bf16(q0, sfr0, oacc[mi], 0, 0, 0);
      bf16x8 q1 = *(const bf16x8*)&Qsm[mi * 16 + lm][lk8 + 32];
      oacc[mi] = __builtin_amdgcn_mfma_f32_16x16x32_bf16(q1, sfr1, oacc[mi], 0, 0, 0);
    }
#pragma unroll
    for (int mi = 0; mi < 4; ++mi) {
      bf16x8 a0 = *(const bf16x8*)&Amm[mi * 16 + lm][lk8];
      oacc[mi] = __builtin_amdgcn_mfma_f32_16x16x32_bf16(a0, dfr0, oacc[mi], 0, 0, 0);
      bf16x8 a1 = *(const bf16x8*)&Amm[mi * 16 + lm][lk8 + 32];
      oacc[mi] = __builtin_amdgcn_mfma_f32_16x16x32_bf16(a1, dfr1, oacc[mi], 0, 0, 0);
    }
#pragma unroll
    for (int mi = 0; mi < 4; ++mi)
#pragma unroll
      for (int r = 0; r < 4; ++r) {
        const int t = mi * 16 + r0 + r;
        o[(sb + t) * VALD_ + h * 64 + wv * 16 + cn] = oacc[mi][r];
      }
  }
}

// ---------------------------------------------------------------------------
// gnorm2 (r9-validated): h = o*silu(z); rmsnorm; *w -> bf16 hn.
// ---------------------------------------------------------------------------
__global__ __launch_bounds__(256) void gnorm2(const float* __restrict__ o,
                                              const float* __restrict__ z,
                                              const float* __restrict__ nw,
                                              bf16* __restrict__ hn) {
  const long idx = (long)blockIdx.x * 256 + threadIdx.x;  // M*16
  const float* op = o + idx * 64;
  const float* zp = z + idx * 64;
  float hv[64];
  float ss = 0.f;
#pragma unroll
  for (int i = 0; i < 64; ++i) {
    const float zz = zp[i];
    const float hh = op[i] * (zz / (1.f + __expf(-zz)));
    hv[i] = hh;
    ss = fmaf(hh, hh, ss);
  }
  const float r = rsqrtf(ss * (1.f / 64.f) + 1e-6f);
#pragma unroll
  for (int i = 0; i < 64; ++i)
    hn[idx * 64 + i] = __float2bfloat16(hv[i] * r * nw[i]);
}

// ---------------------------------------------------------------------------
extern "C" void kernel_launch(void* const* d_in, const int* in_sizes, int n_in,
                              void* d_out, int out_size, void* d_ws, size_t ws_size,
                              hipStream_t stream) {
  float* out = (float*)d_out;   // fp32 output (r8-confirmed)
  const int M = B_ * S_;        // 8192

  // input mapping (dict order confirmed; size-based fallback kept)
  int ih, iqkv, icw, iz, ib, ia, idtb, ialog, inw, iout;
  if (n_in >= 10 && in_sizes[0] == 8388608) {
    ih = 0; iqkv = 1; icw = 2; iz = 3; ib = 4; ia = 5;
    idtb = 6; ialog = 7; inw = 8; iout = 9;
  } else {
    ih = iqkv = icw = iz = ib = ia = idtb = ialog = inw = iout = -1;
    for (int i = 0; i < n_in; ++i) {
      switch (in_sizes[i]) {
        case 8388608: ih = i; break;
        case 2097152: iqkv = i; break;
        case 8192:    icw = i; break;
        case 64:      inw = i; break;
        case 1048576: if (iz < 0) iz = i; else iout = i; break;
        case 16384:   if (ib < 0) ib = i; else ia = i; break;
        case 16:      if (idtb < 0) idtb = i; else ialog = i; break;
        default: break;
      }
    }
  }
  const float* hs   = (const float*)d_in[ih];
  const float* Wqkv = (const float*)d_in[iqkv];
  const float* cw   = (const float*)d_in[icw];
  const float* Wz   = (const float*)d_in[iz];
  const float* Wb   = (const float*)d_in[ib];
  const float* Wa   = (const float*)d_in[ia];
  const float* dtb  = (const float*)d_in[idtb];
  const float* Alog = (const float*)d_in[ialog];
  const float* nwv  = (const float*)d_in[inw];
  const float* Wout = (const float*)d_in[iout];

  // workspace (~122 MiB): r1 layout + Sbound; Mc/Bc alias region1 (mixed is
  // dead after conv2; of not written until chunk_out).
  char* p = (char*)d_ws;
  bf16*  mixed = (bf16*)p;                                 // region1: 32 MiB
  float* of    = (float*)p;                                //   of aliases mixed
  bf16*  McTw  = (bf16*)p;                                 //   McT: first 16 MiB
  bf16*  Bcw   = (bf16*)(p + (size_t)2048 * 4096 * 2);     //   Bc: second 16 MiB
  p += (size_t)M * CDIM_ * 2;
  bf16*  hs_b  = (bf16*)p;                                 // region2 (16 MiB; dead after z-gemm)
  bf16*  qkvb  = (bf16*)p;                                 //   full region2
  bf16*  hn    = (bf16*)p; p += (size_t)M * CDIM_ * 2;     //   hn aliases qkvb
  bf16*  Wqkv_b= (bf16*)p; p += (size_t)CDIM_ * H_ * 2;    // 4 MiB
  bf16*  Wz_b  = (bf16*)p; p += (size_t)H_ * H_ * 2;       // 2 MiB
  bf16*  Wout_b= (bf16*)p; p += (size_t)H_ * H_ * 2;       // 2 MiB
  float* betaf = (float*)p; p += (size_t)M * NVH_ * 4;     // 512 KiB
  float* gf    = (float*)p; p += (size_t)M * NVH_ * 4;     // 512 KiB
  bf16*  Wws   = (bf16*)p; p += (size_t)2048 * 4096 * 2;   // 16 MiB
  bf16*  U0ws  = (bf16*)p; p += (size_t)2048 * 4096 * 2;   // 16 MiB
  float* lgws  = (float*)p; p += (size_t)2048 * 64 * 4;    // 512 KiB
  bf16*  Sbw   = (bf16*)p; p += (size_t)2048 * 4096 * 2;   // 16 MiB (boundary states)
  float* zb    = out;   // z fp32 staged in d_out, consumed by gnorm2

  // 0) casts fp32 -> bf16 for MFMA operands
  {
    long n;
    n = (long)M * H_;     castf2b<<<(int)(n / 4 / 256), 256, 0, stream>>>(hs,   hs_b,   n);
    n = (long)CDIM_ * H_; castf2b<<<(int)(n / 4 / 256), 256, 0, stream>>>(Wqkv, Wqkv_b, n);
    n = (long)H_ * H_;    castf2b<<<(int)(n / 4 / 256), 256, 0, stream>>>(Wz,   Wz_b,   n);
    n = (long)H_ * H_;    castf2b<<<(int)(n / 4 / 256), 256, 0, stream>>>(Wout, Wout_b, n);
  }
  // 1) mixed = hs @ Wqkv^T  [8192 x 2048] -> bf16 (MFMA)
  gemm_bt<bf16><<<(M / 128) * (CDIM_ / 128), 256, 0, stream>>>(hs_b, Wqkv_b, mixed, M, CDIM_, H_);
  // 2) z = hs @ Wz^T  [8192 x 1024] -> fp32 in d_out (MFMA)
  gemm_bt<float><<<(M / 128) * (H_ / 128), 256, 0, stream>>>(hs_b, Wz_b, zb, M, H_, H_);
  // 3) beta, g
  proj_ba<<<M, 256, 0, stream>>>(hs, Wb, Wa, dtb, Alog, betaf, gf);
  // 4) causal depthwise conv + silu + q-scale -> bf16
  conv2<<<(int)(((long)M * CDIM_) / 256), 256, 0, stream>>>(mixed, cw, qkvb);
  // 5) chunked delta-rule, decoupled:
  //    a) UT-transform precompute (parallel 2048)
  chunk_pre<<<2048, 128, 0, stream>>>(qkvb, betaf, gf, Wws, U0ws, lgws);
  //    b) per-chunk affine transition pieces (parallel 2048)
  chunk_mb<<<2048, 256, 0, stream>>>(qkvb, Wws, U0ws, lgws, McTw, Bcw);
  //    c) serial-but-light boundary-state recurrence (32 WGs, prefetch depth 2)
  chunk_state<<<32, 256, 0, stream>>>(McTw, Bcw, lgws, Sbw);
  //    d) per-chunk outputs (parallel 2048)
  chunk_out<<<2048, 256, 0, stream>>>(qkvb, Wws, U0ws, lgws, Sbw, of);
  // 6) gated RMSNorm -> hn bf16
  gnorm2<<<(M * NVH_) / 256, 256, 0, stream>>>(of, zb, nwv, hn);
  // 7) out = hn @ Wout^T -> d_out fp32 (MFMA)
  gemm_bt<float><<<(M / 128) * (H_ / 128), 256, 0, stream>>>(hn, Wout_b, out, M, H_, H_);
}

// Round 3
// 552.605 us; speedup vs baseline: 2.2291x; 1.0623x over previous
//
#include <hip/hip_runtime.h>
#include <hip/hip_bf16.h>
#include <stdint.h>

// Problem constants
#define B_    2
#define S_    4096
#define H_    1024
#define NKH_  8
#define NVH_  16
#define DK_   64
#define DV_   64
#define KEYD_ 512          // NKH*DK
#define CDIM_ 2048         // 2*KEYD + VAL_DIM
#define VALD_ 1024         // NVH*DV
#define NCHUNK_ 64         // S_/64
#define CS_   64           // chunk size

using bf16 = __hip_bfloat16;
using bf16x8 = __attribute__((ext_vector_type(8))) short;  // 8 bf16 = 4 VGPRs
using f32x4  = __attribute__((ext_vector_type(4))) float;

__device__ inline float bsh2f(short s) {
  union { ushort u; bf16 h; } c; c.u = (ushort)s; return __bfloat162float(c.h);
}
__device__ inline short f2bsh(float f) {
  union { ushort u; bf16 h; } c; c.h = __float2bfloat16(f); return (short)c.u;
}

// ---------------------------------------------------------------------------
// fp32 -> bf16 cast, 4 elems/thread (n % 4 == 0). (r2-validated structure)
// ---------------------------------------------------------------------------
__global__ __launch_bounds__(256) void castf2b(const float* __restrict__ x,
                                               bf16* __restrict__ y, long n) {
  const long i = ((long)blockIdx.x * 256 + threadIdx.x) * 4;
  if (i >= n) return;
  float4 v = *(const float4*)(x + i);
  union { ushort4 u; bf16 h[4]; } o;
  o.h[0] = __float2bfloat16(v.x);
  o.h[1] = __float2bfloat16(v.y);
  o.h[2] = __float2bfloat16(v.z);
  o.h[3] = __float2bfloat16(v.w);
  *(ushort4*)(y + i) = o.u;
}

// ---------------------------------------------------------------------------
// MFMA GEMM (r9-validated): C[m,n] = sum_k A[m,k]*B[n,k]; A,B bf16;
// C bf16 or fp32. 128x128 tile, 4 waves 2x2, 4x4 of 16x16x32 MFMA, BK=32.
// ---------------------------------------------------------------------------
template <typename OT>
__global__ __launch_bounds__(256) void gemm_bt(const bf16* __restrict__ A,
                                               const bf16* __restrict__ Bm,
                                               OT* __restrict__ C,
                                               int M, int N, int K) {
  __shared__ short Asm[128 * 32];
  __shared__ short Bsm[128 * 32];
  const int t = threadIdx.x;
  const int w = t >> 6, l = t & 63;
  const int ntn = N >> 7;
  const int bm = blockIdx.x / ntn, bn = blockIdx.x % ntn;
  const int m0 = bm << 7, n0 = bn << 7;
  const int wm = (w >> 1) << 6, wn = (w & 1) << 6;

  f32x4 acc[4][4] = {};

  const int srow = t >> 2;            // 0..63
  const int scol8 = (t & 3) << 3;     // 0,8,16,24
  const bf16* Ag = A + (long)(m0 + srow) * K + scol8;
  const bf16* Bg = Bm + (long)(n0 + srow) * K + scol8;
  const long rstep = (long)64 * K;

  const int lm = l & 15;
  const int kk = (l >> 4) << 3;
  const short* ar0 = &Asm[(wm + lm) * 32 + kk];
  const short* br0 = &Bsm[(wn + lm) * 32 + kk];

  for (int k0 = 0; k0 < K; k0 += 32) {
    bf16x8 a0 = *(const bf16x8*)(Ag + k0);
    bf16x8 a1 = *(const bf16x8*)(Ag + k0 + rstep);
    bf16x8 b0 = *(const bf16x8*)(Bg + k0);
    bf16x8 b1 = *(const bf16x8*)(Bg + k0 + rstep);
    __syncthreads();
    *(bf16x8*)&Asm[srow * 32 + scol8]        = a0;
    *(bf16x8*)&Asm[(64 + srow) * 32 + scol8] = a1;
    *(bf16x8*)&Bsm[srow * 32 + scol8]        = b0;
    *(bf16x8*)&Bsm[(64 + srow) * 32 + scol8] = b1;
    __syncthreads();
    bf16x8 af[4], bfr[4];
#pragma unroll
    for (int mi = 0; mi < 4; ++mi) af[mi] = *(const bf16x8*)(ar0 + mi * 16 * 32);
#pragma unroll
    for (int ni = 0; ni < 4; ++ni) bfr[ni] = *(const bf16x8*)(br0 + ni * 16 * 32);
#pragma unroll
    for (int mi = 0; mi < 4; ++mi)
#pragma unroll
      for (int ni = 0; ni < 4; ++ni)
        acc[mi][ni] = __builtin_amdgcn_mfma_f32_16x16x32_bf16(af[mi], bfr[ni],
                                                              acc[mi][ni], 0, 0, 0);
  }

  // C/D layout: col = l&15, row = (l>>4)*4 + reg
  const int r0 = (l >> 4) << 2;
  const int cn = l & 15;
#pragma unroll
  for (int mi = 0; mi < 4; ++mi)
#pragma unroll
    for (int ni = 0; ni < 4; ++ni) {
      long base = (long)(m0 + wm + mi * 16 + r0) * N + (n0 + wn + ni * 16 + cn);
#pragma unroll
      for (int r = 0; r < 4; ++r) {
        if constexpr (sizeof(OT) == 2)
          C[base + (long)r * N] = __float2bfloat16(acc[mi][ni][r]);
        else
          C[base + (long)r * N] = acc[mi][ni][r];
      }
    }
}

// ---------------------------------------------------------------------------
// conv2 (r8/r9-validated): causal depthwise k=4 cross-corr, silu, q-scale.
// ---------------------------------------------------------------------------
__global__ __launch_bounds__(256) void conv2(const bf16* __restrict__ mixed,
                                             const float* __restrict__ cw,
                                             bf16* __restrict__ qkv) {
  const long idx = (long)blockIdx.x * 256 + threadIdx.x;  // M*2048
  const int c = (int)(idx & (CDIM_ - 1));
  const long row = idx >> 11;
  const int s = (int)(row & (S_ - 1));
  float acc = 0.f;
#pragma unroll
  for (int j = 0; j < 4; ++j) {
    const int ss = s - 3 + j;
    if (ss >= 0)
      acc = fmaf(cw[c * 4 + j], (float)mixed[(row + j - 3) * CDIM_ + c], acc);
  }
  float y = acc / (1.f + __expf(-acc));        // silu
  if (c < KEYD_) y *= 0.125f;                  // q * DK^-0.5
  union { uint16_t u; bf16 h; } o; o.h = __float2bfloat16(y);
  ((uint16_t*)qkv)[row * CDIM_ + c] = o.u;
}

// ---------------------------------------------------------------------------
// proj_ba2 (r3): 8 rows per block -> W_b/W_a L2 traffic cut 8x. Thread (r,j)
// computes one full 1024-dot from LDS-staged hs rows; no shuffle reduce.
// ---------------------------------------------------------------------------
__global__ __launch_bounds__(256) void proj_ba2(const float* __restrict__ hs,
                                                const float* __restrict__ Wb,
                                                const float* __restrict__ Wa,
                                                const float* __restrict__ dtb,
                                                const float* __restrict__ Alog,
                                                float* __restrict__ beta,
                                                float* __restrict__ g) {
  __shared__ float4 hrow[8][257];   // +1 float4 pad: lanes r=0..7 hit distinct banks
  const long row0 = (long)blockIdx.x * 8;
  const int tid = threadIdx.x;
  for (int i = tid; i < 2048; i += 256) {
    const int r = i >> 8, c4 = i & 255;
    hrow[r][c4] = *(const float4*)(hs + (row0 + r) * H_ + (long)c4 * 4);
  }
  __syncthreads();
  const int j = tid >> 3, r = tid & 7;
  const float4* Wp = (const float4*)(j < 16 ? Wb + (long)j * H_
                                            : Wa + (long)(j - 16) * H_);
  float4 a4 = {0.f, 0.f, 0.f, 0.f};
#pragma unroll 4
  for (int i = 0; i < 256; ++i) {
    const float4 w = Wp[i];
    const float4 hv = hrow[r][i];
    a4.x = fmaf(w.x, hv.x, a4.x);
    a4.y = fmaf(w.y, hv.y, a4.y);
    a4.z = fmaf(w.z, hv.z, a4.z);
    a4.w = fmaf(w.w, hv.w, a4.w);
  }
  const float acc = (a4.x + a4.y) + (a4.z + a4.w);
  const long row = row0 + r;
  if (j < 16) {
    beta[row * NVH_ + j] = 1.f / (1.f + __expf(-acc));
  } else {
    const int hh = j - 16;
    const float x = acc + dtb[hh];
    const float sp = (x > 20.f) ? x : log1pf(__expf(x));
    g[row * NVH_ + hh] = -__expf(Alog[hh]) * sp;
  }
}

// ---------------------------------------------------------------------------
// chunk_pre (r3, fused): per (b,h,chunk) task:
//   lg = cumsum(g) (wave scan); T[t,i] = beta_t e^{lg_t-lg_i} (k_t.k_i), i<t
//   solve (I+T)X = [diag(beta e^lg)K | diag(beta)V]  -> W, U0   (fp32 exact)
//   K'[t,k] = e^{lg63-lg_t} k[t,k]
//   McT = -K'^T W ; Bc = U0^T K'  (MFMA, fused from old chunk_mb)
// Solve: right-looking, 8-col groups; per-thread solution column lives in LDS
// (runtime-indexable -> small looped code, no 2016-inst unroll / icache
// streaming), tail updates read T as uniform float4 broadcasts.
// ---------------------------------------------------------------------------
__global__ __launch_bounds__(256) void chunk_pre(const bf16* __restrict__ qkv,
                                                 const float* __restrict__ beta,
                                                 const float* __restrict__ g,
                                                 bf16* __restrict__ Wws,
                                                 bf16* __restrict__ U0ws,
                                                 float* __restrict__ lgws,
                                                 bf16* __restrict__ McT,
                                                 bf16* __restrict__ Bc) {
  __shared__ short Ksm[64][72];
  __shared__ short Vsm[64][72];       // reused as U0T after solve
  __shared__ float Tsm[64][64];       // reused as WT after solve
  __shared__ short KpT[64][72];       // K'^T rows [k][t]
  __shared__ float Xl[128][67];       // per-thread solution column (67: odd dword stride)
  __shared__ float lgs[64];
  __shared__ float bts[64];
  __shared__ float belg[64];

  const int blk = blockIdx.x;
  const int hb = blk & 31, c = blk >> 5;   // hb fast: qkv-row L2 reuse
  const long task = (long)hb * 64 + c;
  const int h = hb & 15, b = hb >> 4, kh = h >> 1;
  const long t0 = (long)b * S_ + (long)c * CS_;
  const int tid = threadIdx.x;
  const int wv = tid >> 6, l = tid & 63;
  const int lm = l & 15, lk8 = (l >> 4) << 3;
  const int r0 = (l >> 4) << 2, cn = l & 15;
  const int srow = tid >> 2, scol = (tid & 3) * 16;

  // stage K,V (all 256 threads, 16 shorts each per matrix)
  {
    const bf16* kp = qkv + (t0 + srow) * CDIM_ + KEYD_ + kh * 64 + scol;
    const bf16* vp = qkv + (t0 + srow) * CDIM_ + 2 * KEYD_ + h * 64 + scol;
    *(bf16x8*)&Ksm[srow][scol]     = *(const bf16x8*)(kp);
    *(bf16x8*)&Ksm[srow][scol + 8] = *(const bf16x8*)(kp + 8);
    *(bf16x8*)&Vsm[srow][scol]     = *(const bf16x8*)(vp);
    *(bf16x8*)&Vsm[srow][scol + 8] = *(const bf16x8*)(vp + 8);
  }
  if (tid < 64) {
    bts[tid] = beta[(t0 + tid) * NVH_ + tid * 0 + h];
    lgs[tid] = g[(t0 + tid) * NVH_ + h];
  }
  __syncthreads();

  // wave-parallel inclusive prefix sum of g (wave 0 only)
  if (tid < 64) {
    float x = lgs[tid];
#pragma unroll
    for (int d = 1; d < 64; d <<= 1) {
      const float y = __shfl_up(x, d);
      if (tid >= d) x += y;
    }
    lgs[tid] = x;
    belg[tid] = bts[tid] * __expf(x);
  }
  __syncthreads();

  if (tid < 128) {
    // KK^T -> T (masked, decayed). 2 waves x 2 m-tiles x 4 n-tiles.
    f32x4 acc[2][4] = {};
#pragma unroll
    for (int ks = 0; ks < 2; ++ks) {
      bf16x8 bfr[4];
#pragma unroll
      for (int ni = 0; ni < 4; ++ni)
        bfr[ni] = *(const bf16x8*)&Ksm[ni * 16 + lm][lk8 + ks * 32];
#pragma unroll
      for (int mi = 0; mi < 2; ++mi) {
        bf16x8 afr = *(const bf16x8*)&Ksm[(wv * 2 + mi) * 16 + lm][lk8 + ks * 32];
#pragma unroll
        for (int ni = 0; ni < 4; ++ni)
          acc[mi][ni] = __builtin_amdgcn_mfma_f32_16x16x32_bf16(afr, bfr[ni],
                                                                acc[mi][ni], 0, 0, 0);
      }
    }
#pragma unroll
    for (int mi = 0; mi < 2; ++mi)
#pragma unroll
      for (int ni = 0; ni < 4; ++ni)
#pragma unroll
        for (int r = 0; r < 4; ++r) {
          const int t = (wv * 2 + mi) * 16 + r0 + r;
          const int i = ni * 16 + cn;
          Tsm[t][i] = (i < t) ? bts[t] * __expf(lgs[t] - lgs[i]) * acc[mi][ni][r]
                              : 0.f;
        }
  } else {
    // waves 2-3: build K'^T (transpose + decay) in parallel with T-build
    const int idx = tid - 128;
    const int tt = idx >> 1;
    const int o2 = (idx & 1) * 32;
    const float dec = __expf(lgs[63] - lgs[tt]);
#pragma unroll 8
    for (int k = 0; k < 32; ++k)
      KpT[o2 + k][tt] = f2bsh(dec * bsh2f(Ksm[tt][o2 + k]));
  }
  __syncthreads();   // Tsm, KpT, belg ready

  // right-looking blocked forward substitution (waves 0-1; 128 columns)
  if (tid < 128) {
    const int colW = tid & 63;
    const bool isW = tid < 64;
#pragma unroll 8
    for (int t = 0; t < CS_; ++t)
      Xl[tid][t] = isW ? belg[t] * bsh2f(Ksm[t][colW])
                       : bts[t] * bsh2f(Vsm[t][colW]);
    for (int j = 0; j < CS_; j += 8) {
      float xs[8];
#pragma unroll
      for (int a = 0; a < 8; ++a) xs[a] = Xl[tid][j + a];
      // in-register 8x8 triangle finalization (uniform T reads)
#pragma unroll
      for (int a = 1; a < 8; ++a)
#pragma unroll
        for (int bb = 0; bb < a; ++bb)
          xs[a] = fmaf(-Tsm[j + a][j + bb], xs[bb], xs[a]);
#pragma unroll
      for (int a = 1; a < 8; ++a) Xl[tid][j + a] = xs[a];
      // tail update: 2 uniform float4 T reads per row, 8 MACs per LDS RMW
#pragma unroll 2
      for (int t = j + 8; t < CS_; ++t) {
        const float4 ta = *(const float4*)&Tsm[t][j];
        const float4 tb = *(const float4*)&Tsm[t][j + 4];
        float v = Xl[tid][t];
        v = fmaf(-ta.x, xs[0], v); v = fmaf(-ta.y, xs[1], v);
        v = fmaf(-ta.z, xs[2], v); v = fmaf(-ta.w, xs[3], v);
        v = fmaf(-tb.x, xs[4], v); v = fmaf(-tb.y, xs[5], v);
        v = fmaf(-tb.z, xs[6], v); v = fmaf(-tb.w, xs[7], v);
        Xl[tid][t] = v;
      }
    }
  }
  if (tid < 64) lgws[task * 64 + tid] = lgs[tid];
  __syncthreads();   // solve done everywhere; Tsm/Vsm now dead

  // write W/U0 to global (coalesced per row) + transposed bf16 into LDS
  short (*WT)[72] = (short (*)[72]) & Tsm[0][0];   // 9216B into 16384B region
  short (*U0T)[72] = Vsm;
  if (tid < 128) {
    const int colW = tid & 63;
    const bool isW = tid < 64;
    bf16* dst = (isW ? Wws : U0ws) + task * 4096 + colW;
    short (*XT)[72] = isW ? WT : U0T;
#pragma unroll 4
    for (int t = 0; t < CS_; t += 2) {
      const float v0 = Xl[tid][t], v1 = Xl[tid][t + 1];
      dst[(long)t * 64] = __float2bfloat16(v0);
      dst[(long)(t + 1) * 64] = __float2bfloat16(v1);
      short2 pk; pk.x = f2bsh(v0); pk.y = f2bsh(v1);
      *(short2*)&XT[colW][t] = pk;
    }
  }
  __syncthreads();   // WT/U0T ready

  // McT = -(K'^T)(W^T)^T : C[m=k'][n=k] = sum_t KpT[k'][t] WT[k][t]
  {
    f32x4 macc[4] = {};
#pragma unroll
    for (int ks = 0; ks < 2; ++ks) {
      bf16x8 afr = *(const bf16x8*)&KpT[wv * 16 + lm][lk8 + ks * 32];
#pragma unroll
      for (int ni = 0; ni < 4; ++ni) {
        bf16x8 bfr = *(const bf16x8*)&WT[ni * 16 + lm][lk8 + ks * 32];
        macc[ni] = __builtin_amdgcn_mfma_f32_16x16x32_bf16(afr, bfr, macc[ni], 0, 0, 0);
      }
    }
#pragma unroll
    for (int ni = 0; ni < 4; ++ni)
#pragma unroll
      for (int r = 0; r < 4; ++r)
        McT[task * 4096 + (wv * 16 + r0 + r) * 64 + ni * 16 + cn] =
            __float2bfloat16(-macc[ni][r]);
  }
  // Bc : C[m=v][n=k'] = sum_t U0T[v][t] KpT[k'][t]
  {
    f32x4 bacc[4] = {};
#pragma unroll
    for (int ks = 0; ks < 2; ++ks) {
      bf16x8 afr = *(const bf16x8*)&U0T[wv * 16 + lm][lk8 + ks * 32];
#pragma unroll
      for (int ni = 0; ni < 4; ++ni) {
        bf16x8 bfr = *(const bf16x8*)&KpT[ni * 16 + lm][lk8 + ks * 32];
        bacc[ni] = __builtin_amdgcn_mfma_f32_16x16x32_bf16(afr, bfr, bacc[ni], 0, 0, 0);
      }
    }
#pragma unroll
    for (int ni = 0; ni < 4; ++ni)
#pragma unroll
      for (int r = 0; r < 4; ++r)
        Bc[task * 4096 + (wv * 16 + r0 + r) * 64 + ni * 16 + cn] =
            __float2bfloat16(bacc[ni][r]);
  }
}

// ---------------------------------------------------------------------------
// chunk_state (r2-validated): serial over 64 chunks, one WG per (b,h):
//   store Sbound[c] = S_c; S_{c+1} = e^{lg63} S_c (fp32) + S_c.McT (MFMA) + Bc
// Mc/Bc prefetched 2 chunks ahead (triple-buffered LDS).
// ---------------------------------------------------------------------------
__global__ __launch_bounds__(256) void chunk_state(const bf16* __restrict__ McT,
                                                   const bf16* __restrict__ Bc,
                                                   const float* __restrict__ lgws,
                                                   bf16* __restrict__ Sb) {
  __shared__ short Msm[3][64][72];
  __shared__ short Bsm[3][64][72];
  __shared__ short Ssm[64][72];   // bf16 state rows [v][k] (wave-private bands)
  __shared__ float lgb[3];

  const int hb = blockIdx.x;      // b*16+h
  const int tid = threadIdx.x, wv = tid >> 6, l = tid & 63;
  const int lm = l & 15, lk8 = (l >> 4) << 3;
  const int r0 = (l >> 4) << 2, cn = l & 15;
  const int srow = tid >> 2, scol = (tid & 3) * 16;

  for (int i = tid; i < 64 * 72; i += 256) ((short*)Ssm)[i] = 0;
  f32x4 Sreg[4] = {};   // fp32 master: S[v = wv*16+r0+r][k = ni*16+cn]

  auto stage = [&](int cc, int bu) {
    const long tt = (long)hb * 64 + cc;
    const bf16* mp = McT + tt * 4096 + srow * 64 + scol;
    const bf16* bp = Bc + tt * 4096 + srow * 64 + scol;
    *(bf16x8*)&Msm[bu][srow][scol]     = *(const bf16x8*)(mp);
    *(bf16x8*)&Msm[bu][srow][scol + 8] = *(const bf16x8*)(mp + 8);
    *(bf16x8*)&Bsm[bu][srow][scol]     = *(const bf16x8*)(bp);
    *(bf16x8*)&Bsm[bu][srow][scol + 8] = *(const bf16x8*)(bp + 8);
    if (tid == 0) lgb[bu] = lgws[tt * 64 + 63];
  };
  stage(0, 0);
  stage(1, 1);

  for (int c = 0; c < NCHUNK_; ++c) {
    __syncthreads();   // buf[c%3] staging complete; prev-step reads done
    if (c + 2 < NCHUNK_) stage(c + 2, (c + 2) % 3);
    const int bu = c % 3;

    // store boundary state S_c (start of chunk c); off critical path
    {
      bf16* sp = Sb + ((long)hb * 64 + c) * 4096;
#pragma unroll
      for (int ni = 0; ni < 4; ++ni)
#pragma unroll
        for (int r = 0; r < 4; ++r)
          sp[(wv * 16 + r0 + r) * 64 + ni * 16 + cn] = __float2bfloat16(Sreg[ni][r]);
    }

    bf16x8 sfr0 = *(const bf16x8*)&Ssm[wv * 16 + lm][lk8];
    bf16x8 sfr1 = *(const bf16x8*)&Ssm[wv * 16 + lm][lk8 + 32];
    f32x4 kacc[4] = {};
#pragma unroll
    for (int ni = 0; ni < 4; ++ni) {
      bf16x8 b0 = *(const bf16x8*)&Msm[bu][ni * 16 + lm][lk8];
      kacc[ni] = __builtin_amdgcn_mfma_f32_16x16x32_bf16(sfr0, b0, kacc[ni], 0, 0, 0);
      bf16x8 b1 = *(const bf16x8*)&Msm[bu][ni * 16 + lm][lk8 + 32];
      kacc[ni] = __builtin_amdgcn_mfma_f32_16x16x32_bf16(sfr1, b1, kacc[ni], 0, 0, 0);
    }
    const float eend = __expf(lgb[bu]);
#pragma unroll
    for (int ni = 0; ni < 4; ++ni)
#pragma unroll
      for (int r = 0; r < 4; ++r) {
        const float bv = bsh2f(Bsm[bu][wv * 16 + r0 + r][ni * 16 + cn]);
        Sreg[ni][r] = eend * Sreg[ni][r] + kacc[ni][r] + bv;
        Ssm[wv * 16 + r0 + r][ni * 16 + cn] = f2bsh(Sreg[ni][r]);
      }
  }
}

// ---------------------------------------------------------------------------
// chunk_out (r2-validated): fully parallel over 2048 (b,h,chunk) tasks.
//   A[t,i]  = (q_t.k_i) * exp(lg_t - lg_i), i<=t
//   Dt[v,t] = U0[t,v] - (S0v . W^T)[v,t]
//   O[t,v]  = (e^{lg} q)_t . S0v  +  A . Dt
// ---------------------------------------------------------------------------
__global__ __launch_bounds__(256) void chunk_out(const bf16* __restrict__ qkv,
                                                 const bf16* __restrict__ Wws,
                                                 const bf16* __restrict__ U0ws,
                                                 const float* __restrict__ lgws,
                                                 const bf16* __restrict__ Sb,
                                                 float* __restrict__ o) {
  __shared__ short Qsm[64][72];   // q rows (later scaled in place by exp(lg_t))
  __shared__ short Ksm[64][72];   // k rows
  __shared__ short Wsm[64][72];   // W rows [t][dk]
  __shared__ short Usm[64][72];   // U0 rows [t][v]
  __shared__ short Amm[64][72];   // A rows [t][i]
  __shared__ short Dsm[64][72];   // Dt rows [v][t] (wave-private 16-row bands)
  __shared__ float lgs[64];

  const int blk = blockIdx.x;
  const int hb = blk & 31, c = blk >> 5;      // hb fast: qkv-row L2 reuse
  const long task = (long)hb * 64 + c;
  const int h = hb & 15, b = hb >> 4, kh = h >> 1;
  const long sb = (long)b * S_ + (long)c * CS_;
  const int tid = threadIdx.x, wv = tid >> 6, l = tid & 63;
  const int lm = l & 15, lk8 = (l >> 4) << 3;
  const int r0 = (l >> 4) << 2, cn = l & 15;
  const int srow = tid >> 2, scol = (tid & 3) * 16;

  // S0 fragments straight from global (issued early; L2-resident after
  // chunk_state). Rows [v][k], wave band wv.
  const bf16* sp = Sb + task * 4096 + (wv * 16 + lm) * 64 + lk8;
  bf16x8 sfr0 = *(const bf16x8*)(sp);
  bf16x8 sfr1 = *(const bf16x8*)(sp + 32);

  {
    const bf16* qp = qkv + (sb + srow) * CDIM_ + kh * 64 + scol;
    const bf16* kp = qkv + (sb + srow) * CDIM_ + KEYD_ + kh * 64 + scol;
    const bf16* wp = Wws + task * 4096 + srow * 64 + scol;
    const bf16* up = U0ws + task * 4096 + srow * 64 + scol;
    *(bf16x8*)&Qsm[srow][scol]     = *(const bf16x8*)(qp);
    *(bf16x8*)&Qsm[srow][scol + 8] = *(const bf16x8*)(qp + 8);
    *(bf16x8*)&Ksm[srow][scol]     = *(const bf16x8*)(kp);
    *(bf16x8*)&Ksm[srow][scol + 8] = *(const bf16x8*)(kp + 8);
    *(bf16x8*)&Wsm[srow][scol]     = *(const bf16x8*)(wp);
    *(bf16x8*)&Wsm[srow][scol + 8] = *(const bf16x8*)(wp + 8);
    *(bf16x8*)&Usm[srow][scol]     = *(const bf16x8*)(up);
    *(bf16x8*)&Usm[srow][scol + 8] = *(const bf16x8*)(up + 8);
    if (tid < 64) lgs[tid] = lgws[task * 64 + tid];
  }
  __syncthreads();

  // A matrix: wave computes its 16 t-rows x all i.
  {
    f32x4 aacc[4] = {};
#pragma unroll
    for (int ks = 0; ks < 2; ++ks) {
      bf16x8 qa = *(const bf16x8*)&Qsm[wv * 16 + lm][lk8 + ks * 32];
#pragma unroll
      for (int ni = 0; ni < 4; ++ni) {
        bf16x8 kb = *(const bf16x8*)&Ksm[ni * 16 + lm][lk8 + ks * 32];
        aacc[ni] = __builtin_amdgcn_mfma_f32_16x16x32_bf16(qa, kb, aacc[ni], 0, 0, 0);
      }
    }
#pragma unroll
    for (int ni = 0; ni < 4; ++ni)
#pragma unroll
      for (int r = 0; r < 4; ++r) {
        const int t = wv * 16 + r0 + r, i = ni * 16 + cn;
        Amm[t][i] = f2bsh((i <= t) ? aacc[ni][r] * __expf(lgs[t] - lgs[i]) : 0.f);
      }
  }
  __syncthreads();  // all A-reads of Qsm done; now safe to scale Q in place

  {
    const float sc = __expf(lgs[srow]);       // Lambda_t
#pragma unroll
    for (int j = 0; j < 16; ++j)
      Qsm[srow][scol + j] = f2bsh(sc * bsh2f(Qsm[srow][scol + j]));
  }
  __syncthreads();

  // M1: Dt[v,t] = U0[t,v] - sum_k S0v[v,k] W[t,k]
  {
    f32x4 dacc[4] = {};
#pragma unroll
    for (int ni = 0; ni < 4; ++ni) {
      bf16x8 w0 = *(const bf16x8*)&Wsm[ni * 16 + lm][lk8];
      dacc[ni] = __builtin_amdgcn_mfma_f32_16x16x32_bf16(sfr0, w0, dacc[ni], 0, 0, 0);
      bf16x8 w1 = *(const bf16x8*)&Wsm[ni * 16 + lm][lk8 + 32];
      dacc[ni] = __builtin_amdgcn_mfma_f32_16x16x32_bf16(sfr1, w1, dacc[ni], 0, 0, 0);
    }
#pragma unroll
    for (int ni = 0; ni < 4; ++ni)
#pragma unroll
      for (int r = 0; r < 4; ++r) {
        const int t = ni * 16 + cn, v = r0 + r;
        Dsm[wv * 16 + v][t] = f2bsh(bsh2f(Usm[t][wv * 16 + v]) - dacc[ni][r]);
      }
  }
  // wave-private Dsm: in-wave ds ordering + compiler lgkmcnt suffice (no barrier)
  bf16x8 dfr0 = *(const bf16x8*)&Dsm[wv * 16 + lm][lk8];
  bf16x8 dfr1 = *(const bf16x8*)&Dsm[wv * 16 + lm][lk8 + 32];

  // M2+M3: O[t, v16] = LambdaQ . S0v + A . Dt
  {
    f32x4 oacc[4] = {};
#pragma unroll
    for (int mi = 0; mi < 4; ++mi) {
      bf16x8 q0 = *(const bf16x8*)&Qsm[mi * 16 + lm][lk8];
      oacc[mi] = __builtin_amdgcn_mfma_f32_16x16x32_bf16(q0, sfr0, oacc[mi], 0, 0, 0);
      bf16x8 q1 = *(const bf16x8*)&Qsm[mi * 16 + lm][lk8 + 32];
      oacc[mi] = __builtin_amdgcn_mfma_f32_16x16x32_bf16(q1, sfr1, oacc[mi], 0, 0, 0);
    }
#pragma unroll
    for (int mi = 0; mi < 4; ++mi) {
      bf16x8 a0 = *(const bf16x8*)&Amm[mi * 16 + lm][lk8];
      oacc[mi] = __builtin_amdgcn_mfma_f32_16x16x32_bf16(a0, dfr0, oacc[mi], 0, 0, 0);
      bf16x8 a1 = *(const bf16x8*)&Amm[mi * 16 + lm][lk8 + 32];
      oacc[mi] = __builtin_amdgcn_mfma_f32_16x16x32_bf16(a1, dfr1, oacc[mi], 0, 0, 0);
    }
#pragma unroll
    for (int mi = 0; mi < 4; ++mi)
#pragma unroll
      for (int r = 0; r < 4; ++r) {
        const int t = mi * 16 + r0 + r;
        o[(sb + t) * VALD_ + h * 64 + wv * 16 + cn] = oacc[mi][r];
      }
  }
}

// ---------------------------------------------------------------------------
// gnorm2 (r9-validated): h = o*silu(z); rmsnorm; *w -> bf16 hn.
// ---------------------------------------------------------------------------
__global__ __launch_bounds__(256) void gnorm2(const float* __restrict__ o,
                                              const float* __restrict__ z,
                                              const float* __restrict__ nw,
                                              bf16* __restrict__ hn) {
  const long idx = (long)blockIdx.x * 256 + threadIdx.x;  // M*16
  const float* op = o + idx * 64;
  const float* zp = z + idx * 64;
  float hv[64];
  float ss = 0.f;
#pragma unroll
  for (int i = 0; i < 64; ++i) {
    const float zz = zp[i];
    const float hh = op[i] * (zz / (1.f + __expf(-zz)));
    hv[i] = hh;
    ss = fmaf(hh, hh, ss);
  }
  const float r = rsqrtf(ss * (1.f / 64.f) + 1e-6f);
#pragma unroll
  for (int i = 0; i < 64; ++i)
    hn[idx * 64 + i] = __float2bfloat16(hv[i] * r * nw[i]);
}

// ---------------------------------------------------------------------------
extern "C" void kernel_launch(void* const* d_in, const int* in_sizes, int n_in,
                              void* d_out, int out_size, void* d_ws, size_t ws_size,
                              hipStream_t stream) {
  float* out = (float*)d_out;   // fp32 output (r8-confirmed)
  const int M = B_ * S_;        // 8192

  // input mapping (dict order confirmed; size-based fallback kept)
  int ih, iqkv, icw, iz, ib, ia, idtb, ialog, inw, iout;
  if (n_in >= 10 && in_sizes[0] == 8388608) {
    ih = 0; iqkv = 1; icw = 2; iz = 3; ib = 4; ia = 5;
    idtb = 6; ialog = 7; inw = 8; iout = 9;
  } else {
    ih = iqkv = icw = iz = ib = ia = idtb = ialog = inw = iout = -1;
    for (int i = 0; i < n_in; ++i) {
      switch (in_sizes[i]) {
        case 8388608: ih = i; break;
        case 2097152: iqkv = i; break;
        case 8192:    icw = i; break;
        case 64:      inw = i; break;
        case 1048576: if (iz < 0) iz = i; else iout = i; break;
        case 16384:   if (ib < 0) ib = i; else ia = i; break;
        case 16:      if (idtb < 0) idtb = i; else ialog = i; break;
        default: break;
      }
    }
  }
  const float* hs   = (const float*)d_in[ih];
  const float* Wqkv = (const float*)d_in[iqkv];
  const float* cw   = (const float*)d_in[icw];
  const float* Wz   = (const float*)d_in[iz];
  const float* Wb   = (const float*)d_in[ib];
  const float* Wa   = (const float*)d_in[ia];
  const float* dtb  = (const float*)d_in[idtb];
  const float* Alog = (const float*)d_in[ialog];
  const float* nwv  = (const float*)d_in[inw];
  const float* Wout = (const float*)d_in[iout];

  // workspace (~122 MiB): r2 layout; Mc/Bc alias region1 (mixed dead after
  // conv2; of not written until chunk_out).
  char* p = (char*)d_ws;
  bf16*  mixed = (bf16*)p;                                 // region1: 32 MiB
  float* of    = (float*)p;                                //   of aliases mixed
  bf16*  McTw  = (bf16*)p;                                 //   McT: first 16 MiB
  bf16*  Bcw   = (bf16*)(p + (size_t)2048 * 4096 * 2);     //   Bc: second 16 MiB
  p += (size_t)M * CDIM_ * 2;
  bf16*  hs_b  = (bf16*)p;                                 // region2 (16 MiB; dead after z-gemm)
  bf16*  qkvb  = (bf16*)p;                                 //   full region2
  bf16*  hn    = (bf16*)p; p += (size_t)M * CDIM_ * 2;     //   hn aliases qkvb
  bf16*  Wqkv_b= (bf16*)p; p += (size_t)CDIM_ * H_ * 2;    // 4 MiB
  bf16*  Wz_b  = (bf16*)p; p += (size_t)H_ * H_ * 2;       // 2 MiB
  bf16*  Wout_b= (bf16*)p; p += (size_t)H_ * H_ * 2;       // 2 MiB
  float* betaf = (float*)p; p += (size_t)M * NVH_ * 4;     // 512 KiB
  float* gf    = (float*)p; p += (size_t)M * NVH_ * 4;     // 512 KiB
  bf16*  Wws   = (bf16*)p; p += (size_t)2048 * 4096 * 2;   // 16 MiB
  bf16*  U0ws  = (bf16*)p; p += (size_t)2048 * 4096 * 2;   // 16 MiB
  float* lgws  = (float*)p; p += (size_t)2048 * 64 * 4;    // 512 KiB
  bf16*  Sbw   = (bf16*)p; p += (size_t)2048 * 4096 * 2;   // 16 MiB (boundary states)
  float* zb    = out;   // z fp32 staged in d_out, consumed by gnorm2

  // 0) casts fp32 -> bf16 for MFMA operands
  {
    long n;
    n = (long)M * H_;     castf2b<<<(int)(n / 4 / 256), 256, 0, stream>>>(hs,   hs_b,   n);
    n = (long)CDIM_ * H_; castf2b<<<(int)(n / 4 / 256), 256, 0, stream>>>(Wqkv, Wqkv_b, n);
    n = (long)H_ * H_;    castf2b<<<(int)(n / 4 / 256), 256, 0, stream>>>(Wz,   Wz_b,   n);
    n = (long)H_ * H_;    castf2b<<<(int)(n / 4 / 256), 256, 0, stream>>>(Wout, Wout_b, n);
  }
  // 1) mixed = hs @ Wqkv^T  [8192 x 2048] -> bf16 (MFMA)
  gemm_bt<bf16><<<(M / 128) * (CDIM_ / 128), 256, 0, stream>>>(hs_b, Wqkv_b, mixed, M, CDIM_, H_);
  // 2) z = hs @ Wz^T  [8192 x 1024] -> fp32 in d_out (MFMA)
  gemm_bt<float><<<(M / 128) * (H_ / 128), 256, 0, stream>>>(hs_b, Wz_b, zb, M, H_, H_);
  // 3) beta, g (8 rows per block)
  proj_ba2<<<M / 8, 256, 0, stream>>>(hs, Wb, Wa, dtb, Alog, betaf, gf);
  // 4) causal depthwise conv + silu + q-scale -> bf16
  conv2<<<(int)(((long)M * CDIM_) / 256), 256, 0, stream>>>(mixed, cw, qkvb);
  // 5) chunked delta-rule, decoupled:
  //    a) UT-transform precompute + affine transition pieces (fused; 2048 WGs)
  chunk_pre<<<2048, 256, 0, stream>>>(qkvb, betaf, gf, Wws, U0ws, lgws, McTw, Bcw);
  //    b) serial-but-light boundary-state recurrence (32 WGs, prefetch depth 2)
  chunk_state<<<32, 256, 0, stream>>>(McTw, Bcw, lgws, Sbw);
  //    c) per-chunk outputs (parallel 2048)
  chunk_out<<<2048, 256, 0, stream>>>(qkvb, Wws, U0ws, lgws, Sbw, of);
  // 6) gated RMSNorm -> hn bf16
  gnorm2<<<(M * NVH_) / 256, 256, 0, stream>>>(of, zb, nwv, hn);
  // 7) out = hn @ Wout^T -> d_out fp32 (MFMA)
  gemm_bt<float><<<(M / 128) * (H_ / 128), 256, 0, stream>>>(hn, Wout_b, out, M, H_, H_);
}

// Round 4
// 534.421 us; speedup vs baseline: 2.3050x; 1.0340x over previous
//
#include <hip/hip_runtime.h>
#include <hip/hip_bf16.h>
#include <stdint.h>

// Problem constants
#define B_    2
#define S_    4096
#define H_    1024
#define NKH_  8
#define NVH_  16
#define DK_   64
#define DV_   64
#define KEYD_ 512          // NKH*DK
#define CDIM_ 2048         // 2*KEYD + VAL_DIM
#define VALD_ 1024         // NVH*DV
#define NCHUNK_ 64         // S_/64
#define CS_   64           // chunk size

using bf16 = __hip_bfloat16;
using bf16x8 = __attribute__((ext_vector_type(8))) short;  // 8 bf16 = 4 VGPRs
using f32x4  = __attribute__((ext_vector_type(4))) float;

__device__ inline float bsh2f(short s) {
  union { ushort u; bf16 h; } c; c.u = (ushort)s; return __bfloat162float(c.h);
}
__device__ inline short f2bsh(float f) {
  union { ushort u; bf16 h; } c; c.h = __float2bfloat16(f); return (short)c.u;
}

// async global->LDS, 16B per lane; dest = uniform base + lane*16 (HW rule).
__device__ __forceinline__ void gload16(const bf16* g, short* lds) {
  __builtin_amdgcn_global_load_lds(
      (const __attribute__((address_space(1))) void*)g,
      (__attribute__((address_space(3))) void*)lds, 16, 0, 0);
}

// ---------------------------------------------------------------------------
// fp32 -> bf16 cast, 4 elems/thread (n % 4 == 0). (r2-validated structure)
// ---------------------------------------------------------------------------
__global__ __launch_bounds__(256) void castf2b(const float* __restrict__ x,
                                               bf16* __restrict__ y, long n) {
  const long i = ((long)blockIdx.x * 256 + threadIdx.x) * 4;
  if (i >= n) return;
  float4 v = *(const float4*)(x + i);
  union { ushort4 u; bf16 h[4]; } o;
  o.h[0] = __float2bfloat16(v.x);
  o.h[1] = __float2bfloat16(v.y);
  o.h[2] = __float2bfloat16(v.z);
  o.h[3] = __float2bfloat16(v.w);
  *(ushort4*)(y + i) = o.u;
}

// ---------------------------------------------------------------------------
// MFMA GEMM: C[m,n] = sum_k A[m,k]*B[n,k]; A,B bf16; C bf16 or fp32.
// 128x128 tile, 4 waves 2x2, 4x4 of 16x16x32 MFMA, BK=32.
// r4: staging via global_load_lds width=16 (m97 ladder step-3): wave w stages
// 16-row slabs s=w*2+j; lane l -> row s*16+(l>>2), col8 (l&3)*8; LDS linear.
// ---------------------------------------------------------------------------
template <typename OT>
__global__ __launch_bounds__(256) void gemm_bt(const bf16* __restrict__ A,
                                               const bf16* __restrict__ Bm,
                                               OT* __restrict__ C,
                                               int M, int N, int K) {
  __shared__ short Asm[128 * 32];
  __shared__ short Bsm[128 * 32];
  const int t = threadIdx.x;
  const int w = t >> 6, l = t & 63;
  const int ntn = N >> 7;
  const int bm = blockIdx.x / ntn, bn = blockIdx.x % ntn;
  const int m0 = bm << 7, n0 = bn << 7;
  const int wm = (w >> 1) << 6, wn = (w & 1) << 6;

  f32x4 acc[4][4] = {};

  const int grow = l >> 2;            // 0..15 within slab
  const int gc8 = (l & 3) << 3;       // 0,8,16,24
  const bf16* Agl = A + (long)m0 * K + gc8;
  const bf16* Bgl = Bm + (long)n0 * K + gc8;

  const int lm = l & 15;
  const int kk = (l >> 4) << 3;
  const short* ar0 = &Asm[(wm + lm) * 32 + kk];
  const short* br0 = &Bsm[(wn + lm) * 32 + kk];

  for (int k0 = 0; k0 < K; k0 += 32) {
    __syncthreads();   // prev-iter LDS reads done
#pragma unroll
    for (int j = 0; j < 2; ++j) {
      const int s = w * 2 + j;        // slab 0..7 (wave-uniform)
      gload16(Agl + (long)(s * 16 + grow) * K + k0, &Asm[s * 16 * 32]);
      gload16(Bgl + (long)(s * 16 + grow) * K + k0, &Bsm[s * 16 * 32]);
    }
    __syncthreads();   // compiler drains vmcnt before barrier -> LDS ready
    bf16x8 af[4], bfr[4];
#pragma unroll
    for (int mi = 0; mi < 4; ++mi) af[mi] = *(const bf16x8*)(ar0 + mi * 16 * 32);
#pragma unroll
    for (int ni = 0; ni < 4; ++ni) bfr[ni] = *(const bf16x8*)(br0 + ni * 16 * 32);
#pragma unroll
    for (int mi = 0; mi < 4; ++mi)
#pragma unroll
      for (int ni = 0; ni < 4; ++ni)
        acc[mi][ni] = __builtin_amdgcn_mfma_f32_16x16x32_bf16(af[mi], bfr[ni],
                                                              acc[mi][ni], 0, 0, 0);
  }

  // C/D layout: col = l&15, row = (l>>4)*4 + reg
  const int r0 = (l >> 4) << 2;
  const int cn = l & 15;
#pragma unroll
  for (int mi = 0; mi < 4; ++mi)
#pragma unroll
    for (int ni = 0; ni < 4; ++ni) {
      long base = (long)(m0 + wm + mi * 16 + r0) * N + (n0 + wn + ni * 16 + cn);
#pragma unroll
      for (int r = 0; r < 4; ++r) {
        if constexpr (sizeof(OT) == 2)
          C[base + (long)r * N] = __float2bfloat16(acc[mi][ni][r]);
        else
          C[base + (long)r * N] = acc[mi][ni][r];
      }
    }
}

// ---------------------------------------------------------------------------
// conv2 (r8/r9-validated): causal depthwise k=4 cross-corr, silu, q-scale.
// ---------------------------------------------------------------------------
__global__ __launch_bounds__(256) void conv2(const bf16* __restrict__ mixed,
                                             const float* __restrict__ cw,
                                             bf16* __restrict__ qkv) {
  const long idx = (long)blockIdx.x * 256 + threadIdx.x;  // M*2048
  const int c = (int)(idx & (CDIM_ - 1));
  const long row = idx >> 11;
  const int s = (int)(row & (S_ - 1));
  float acc = 0.f;
#pragma unroll
  for (int j = 0; j < 4; ++j) {
    const int ss = s - 3 + j;
    if (ss >= 0)
      acc = fmaf(cw[c * 4 + j], (float)mixed[(row + j - 3) * CDIM_ + c], acc);
  }
  float y = acc / (1.f + __expf(-acc));        // silu
  if (c < KEYD_) y *= 0.125f;                  // q * DK^-0.5
  union { uint16_t u; bf16 h; } o; o.h = __float2bfloat16(y);
  ((uint16_t*)qkv)[row * CDIM_ + c] = o.u;
}

// ---------------------------------------------------------------------------
// proj_ba2 (r3-validated): 8 rows per block; W traffic cut 8x.
// ---------------------------------------------------------------------------
__global__ __launch_bounds__(256) void proj_ba2(const float* __restrict__ hs,
                                                const float* __restrict__ Wb,
                                                const float* __restrict__ Wa,
                                                const float* __restrict__ dtb,
                                                const float* __restrict__ Alog,
                                                float* __restrict__ beta,
                                                float* __restrict__ g) {
  __shared__ float4 hrow[8][257];   // +1 float4 pad
  const long row0 = (long)blockIdx.x * 8;
  const int tid = threadIdx.x;
  for (int i = tid; i < 2048; i += 256) {
    const int r = i >> 8, c4 = i & 255;
    hrow[r][c4] = *(const float4*)(hs + (row0 + r) * H_ + (long)c4 * 4);
  }
  __syncthreads();
  const int j = tid >> 3, r = tid & 7;
  const float4* Wp = (const float4*)(j < 16 ? Wb + (long)j * H_
                                            : Wa + (long)(j - 16) * H_);
  float4 a4 = {0.f, 0.f, 0.f, 0.f};
#pragma unroll 4
  for (int i = 0; i < 256; ++i) {
    const float4 w = Wp[i];
    const float4 hv = hrow[r][i];
    a4.x = fmaf(w.x, hv.x, a4.x);
    a4.y = fmaf(w.y, hv.y, a4.y);
    a4.z = fmaf(w.z, hv.z, a4.z);
    a4.w = fmaf(w.w, hv.w, a4.w);
  }
  const float acc = (a4.x + a4.y) + (a4.z + a4.w);
  const long row = row0 + r;
  if (j < 16) {
    beta[row * NVH_ + j] = 1.f / (1.f + __expf(-acc));
  } else {
    const int hh = j - 16;
    const float x = acc + dtb[hh];
    const float sp = (x > 20.f) ? x : log1pf(__expf(x));
    g[row * NVH_ + hh] = -__expf(Alog[hh]) * sp;
  }
}

// ---------------------------------------------------------------------------
// chunk_pre (r4): per (b,h,chunk) task:
//   lg = cumsum(g); T[t,i] = beta_t e^{lg_t-lg_i}(k_t.k_i), i<t
//   solve (I+T)X = [diag(beta e^lg)K | diag(beta)V] -> W,U0
//   K' = e^{lg63-lg_t} k; McT = -K'^T W; Bc = U0^T K' (MFMA)
// r4 solve: TWO-LEVEL. Upper 32x32 fp32 forward-sub (thread-private) ->
// rank-32 cross-update via 16 MFMAs (bf16 ops, fp32 accum; TloB/XB alias
// dead Ksm/Vsm -> no LDS growth) -> lower 32x32 fp32 forward-sub.
// Serial VALU path halved vs r3; bulk update on matrix pipe.
// ---------------------------------------------------------------------------
__global__ __launch_bounds__(256) void chunk_pre(const bf16* __restrict__ qkv,
                                                 const float* __restrict__ beta,
                                                 const float* __restrict__ g,
                                                 bf16* __restrict__ Wws,
                                                 bf16* __restrict__ U0ws,
                                                 float* __restrict__ lgws,
                                                 bf16* __restrict__ McT,
                                                 bf16* __restrict__ Bc) {
  __shared__ short Ksm[64][72];
  __shared__ short Vsm[64][72];       // aliased: XB (phase2-3), U0T (post-solve)
  __shared__ float Tsm[64][64];       // aliased: WT (post-solve)
  __shared__ short KpT[64][72];       // K'^T rows [k][t]
  __shared__ float Xl[128][67];       // per-thread solution column
  __shared__ float lgs[64];
  __shared__ float bts[64];
  __shared__ float belg[64];

  // aliases (live ranges disjoint)
  short (*XB)[36]   = (short (*)[36]) & Vsm[0][0];   // bf16 Xu, [col][u] (4608 sh, exact fit)
  short (*TloB)[40] = (short (*)[40]) & Ksm[0][0];   // bf16 T[32+m][u] (1280 sh)
  short (*WT)[72]   = (short (*)[72]) & Tsm[0][0];
  short (*U0T)[72]  = Vsm;

  const int blk = blockIdx.x;
  const int hb = blk & 31, c = blk >> 5;   // hb fast: qkv-row L2 reuse
  const long task = (long)hb * 64 + c;
  const int h = hb & 15, b = hb >> 4, kh = h >> 1;
  const long t0 = (long)b * S_ + (long)c * CS_;
  const int tid = threadIdx.x;
  const int wv = tid >> 6, l = tid & 63;
  const int lm = l & 15, lk8 = (l >> 4) << 3;
  const int r0 = (l >> 4) << 2, cn = l & 15;
  const int srow = tid >> 2, scol = (tid & 3) * 16;

  // stage K,V
  {
    const bf16* kp = qkv + (t0 + srow) * CDIM_ + KEYD_ + kh * 64 + scol;
    const bf16* vp = qkv + (t0 + srow) * CDIM_ + 2 * KEYD_ + h * 64 + scol;
    *(bf16x8*)&Ksm[srow][scol]     = *(const bf16x8*)(kp);
    *(bf16x8*)&Ksm[srow][scol + 8] = *(const bf16x8*)(kp + 8);
    *(bf16x8*)&Vsm[srow][scol]     = *(const bf16x8*)(vp);
    *(bf16x8*)&Vsm[srow][scol + 8] = *(const bf16x8*)(vp + 8);
  }
  if (tid < 64) {
    bts[tid] = beta[(t0 + tid) * NVH_ + h];
    lgs[tid] = g[(t0 + tid) * NVH_ + h];
  }
  __syncthreads();

  // wave-parallel inclusive prefix sum of g (wave 0)
  if (tid < 64) {
    float x = lgs[tid];
#pragma unroll
    for (int d = 1; d < 64; d <<= 1) {
      const float y = __shfl_up(x, d);
      if (tid >= d) x += y;
    }
    lgs[tid] = x;
    belg[tid] = bts[tid] * __expf(x);
  }
  __syncthreads();

  if (tid < 128) {
    // KK^T -> T (masked, decayed). 2 waves x 2 m-tiles x 4 n-tiles.
    f32x4 acc[2][4] = {};
#pragma unroll
    for (int ks = 0; ks < 2; ++ks) {
      bf16x8 bfr[4];
#pragma unroll
      for (int ni = 0; ni < 4; ++ni)
        bfr[ni] = *(const bf16x8*)&Ksm[ni * 16 + lm][lk8 + ks * 32];
#pragma unroll
      for (int mi = 0; mi < 2; ++mi) {
        bf16x8 afr = *(const bf16x8*)&Ksm[(wv * 2 + mi) * 16 + lm][lk8 + ks * 32];
#pragma unroll
        for (int ni = 0; ni < 4; ++ni)
          acc[mi][ni] = __builtin_amdgcn_mfma_f32_16x16x32_bf16(afr, bfr[ni],
                                                                acc[mi][ni], 0, 0, 0);
      }
    }
#pragma unroll
    for (int mi = 0; mi < 2; ++mi)
#pragma unroll
      for (int ni = 0; ni < 4; ++ni)
#pragma unroll
        for (int r = 0; r < 4; ++r) {
          const int t = (wv * 2 + mi) * 16 + r0 + r;
          const int i = ni * 16 + cn;
          Tsm[t][i] = (i < t) ? bts[t] * __expf(lgs[t] - lgs[i]) * acc[mi][ni][r]
                              : 0.f;
        }
  } else {
    // waves 2-3: build K'^T (transpose + decay) in parallel with T-build
    const int idx = tid - 128;
    const int tt = idx >> 1;
    const int o2 = (idx & 1) * 32;
    const float dec = __expf(lgs[63] - lgs[tt]);
#pragma unroll 8
    for (int k = 0; k < 32; ++k)
      KpT[o2 + k][tt] = f2bsh(dec * bsh2f(Ksm[tt][o2 + k]));
  }
  __syncthreads();   // Tsm, KpT, belg ready

  // 32x32 fp32 forward-sub on rows [base, base+32), thread-private column.
  auto solve32 = [&](int base) {
    for (int j = base; j < base + 32; j += 8) {
      float xs[8];
#pragma unroll
      for (int a = 0; a < 8; ++a) xs[a] = Xl[tid][j + a];
#pragma unroll
      for (int a = 1; a < 8; ++a)
#pragma unroll
        for (int bb = 0; bb < a; ++bb)
          xs[a] = fmaf(-Tsm[j + a][j + bb], xs[bb], xs[a]);
#pragma unroll
      for (int a = 1; a < 8; ++a) Xl[tid][j + a] = xs[a];
      const int tend = base + 32;
#pragma unroll 2
      for (int tt = j + 8; tt < tend; ++tt) {
        const float4 ta = *(const float4*)&Tsm[tt][j];
        const float4 tb = *(const float4*)&Tsm[tt][j + 4];
        float v = Xl[tid][tt];
        v = fmaf(-ta.x, xs[0], v); v = fmaf(-ta.y, xs[1], v);
        v = fmaf(-ta.z, xs[2], v); v = fmaf(-ta.w, xs[3], v);
        v = fmaf(-tb.x, xs[4], v); v = fmaf(-tb.y, xs[5], v);
        v = fmaf(-tb.z, xs[6], v); v = fmaf(-tb.w, xs[7], v);
        Xl[tid][tt] = v;
      }
    }
  };

  // phase1: rhs init (full column) + upper 32x32 solve (threads 0-127)
  if (tid < 128) {
    const int colW = tid & 63;
    const bool isW = tid < 64;
#pragma unroll 8
    for (int t = 0; t < CS_; ++t)
      Xl[tid][t] = isW ? belg[t] * bsh2f(Ksm[t][colW])
                       : bts[t] * bsh2f(Vsm[t][colW]);
    solve32(0);
  }
  if (tid < 64) lgws[task * 64 + tid] = lgs[tid];
  __syncthreads();   // Xu final; Ksm/Vsm dead -> TloB/XB may be written

  // phase2: bf16 conversions for the cross-update MFMA
  {
    const int col = tid & 127, uh = (tid >> 7) * 16;
#pragma unroll
    for (int u = 0; u < 16; ++u)
      XB[col][uh + u] = f2bsh(Xl[col][uh + u]);
  }
  if (tid < 128) {
    const int m = tid >> 2, u0 = (tid & 3) * 8;
#pragma unroll
    for (int u = 0; u < 8; ++u)
      TloB[m][u0 + u] = f2bsh(Tsm[32 + m][u0 + u]);
  }
  __syncthreads();

  // phase3: rank-32 cross-update via MFMA:
  //   Xl[c][32+t] -= sum_u T[32+t][u] * Xu[u][c]   (16 MFMAs over 4 waves)
  {
#pragma unroll
    for (int ni2 = 0; ni2 < 2; ++ni2) {
      const int ni = wv * 2 + ni2;
      bf16x8 bfr = *(const bf16x8*)&XB[ni * 16 + lm][lk8];
#pragma unroll
      for (int mi = 0; mi < 2; ++mi) {
        bf16x8 afr = *(const bf16x8*)&TloB[mi * 16 + lm][lk8];
        f32x4 uacc = {};
        uacc = __builtin_amdgcn_mfma_f32_16x16x32_bf16(afr, bfr, uacc, 0, 0, 0);
#pragma unroll
        for (int r = 0; r < 4; ++r)
          Xl[ni * 16 + cn][32 + mi * 16 + r0 + r] -= uacc[r];
      }
    }
  }
  __syncthreads();

  // phase4: lower 32x32 solve
  if (tid < 128) solve32(32);
  __syncthreads();   // solve done; Tsm/Vsm regions free for WT/U0T

  // write W/U0 to global (coalesced per row) + transposed bf16 into LDS
  if (tid < 128) {
    const int colW = tid & 63;
    const bool isW = tid < 64;
    bf16* dst = (isW ? Wws : U0ws) + task * 4096 + colW;
    short (*XT)[72] = isW ? WT : U0T;
#pragma unroll 4
    for (int t = 0; t < CS_; t += 2) {
      const float v0 = Xl[tid][t], v1 = Xl[tid][t + 1];
      dst[(long)t * 64] = __float2bfloat16(v0);
      dst[(long)(t + 1) * 64] = __float2bfloat16(v1);
      short2 pk; pk.x = f2bsh(v0); pk.y = f2bsh(v1);
      *(short2*)&XT[colW][t] = pk;
    }
  }
  __syncthreads();   // WT/U0T ready

  // McT = -(K'^T)(W^T)^T : C[m=k'][n=k] = sum_t KpT[k'][t] WT[k][t]
  {
    f32x4 macc[4] = {};
#pragma unroll
    for (int ks = 0; ks < 2; ++ks) {
      bf16x8 afr = *(const bf16x8*)&KpT[wv * 16 + lm][lk8 + ks * 32];
#pragma unroll
      for (int ni = 0; ni < 4; ++ni) {
        bf16x8 bfr = *(const bf16x8*)&WT[ni * 16 + lm][lk8 + ks * 32];
        macc[ni] = __builtin_amdgcn_mfma_f32_16x16x32_bf16(afr, bfr, macc[ni], 0, 0, 0);
      }
    }
#pragma unroll
    for (int ni = 0; ni < 4; ++ni)
#pragma unroll
      for (int r = 0; r < 4; ++r)
        McT[task * 4096 + (wv * 16 + r0 + r) * 64 + ni * 16 + cn] =
            __float2bfloat16(-macc[ni][r]);
  }
  // Bc : C[m=v][n=k'] = sum_t U0T[v][t] KpT[k'][t]
  {
    f32x4 bacc[4] = {};
#pragma unroll
    for (int ks = 0; ks < 2; ++ks) {
      bf16x8 afr = *(const bf16x8*)&U0T[wv * 16 + lm][lk8 + ks * 32];
#pragma unroll
      for (int ni = 0; ni < 4; ++ni) {
        bf16x8 bfr = *(const bf16x8*)&KpT[ni * 16 + lm][lk8 + ks * 32];
        bacc[ni] = __builtin_amdgcn_mfma_f32_16x16x32_bf16(afr, bfr, bacc[ni], 0, 0, 0);
      }
    }
#pragma unroll
    for (int ni = 0; ni < 4; ++ni)
#pragma unroll
      for (int r = 0; r < 4; ++r)
        Bc[task * 4096 + (wv * 16 + r0 + r) * 64 + ni * 16 + cn] =
            __float2bfloat16(bacc[ni][r]);
  }
}

// ---------------------------------------------------------------------------
// chunk_state (r2-validated): serial over 64 chunks, one WG per (b,h):
//   store Sbound[c] = S_c; S_{c+1} = e^{lg63} S_c (fp32) + S_c.McT (MFMA) + Bc
// ---------------------------------------------------------------------------
__global__ __launch_bounds__(256) void chunk_state(const bf16* __restrict__ McT,
                                                   const bf16* __restrict__ Bc,
                                                   const float* __restrict__ lgws,
                                                   bf16* __restrict__ Sb) {
  __shared__ short Msm[3][64][72];
  __shared__ short Bsm[3][64][72];
  __shared__ short Ssm[64][72];   // bf16 state rows [v][k] (wave-private bands)
  __shared__ float lgb[3];

  const int hb = blockIdx.x;      // b*16+h
  const int tid = threadIdx.x, wv = tid >> 6, l = tid & 63;
  const int lm = l & 15, lk8 = (l >> 4) << 3;
  const int r0 = (l >> 4) << 2, cn = l & 15;
  const int srow = tid >> 2, scol = (tid & 3) * 16;

  for (int i = tid; i < 64 * 72; i += 256) ((short*)Ssm)[i] = 0;
  f32x4 Sreg[4] = {};   // fp32 master: S[v = wv*16+r0+r][k = ni*16+cn]

  auto stage = [&](int cc, int bu) {
    const long tt = (long)hb * 64 + cc;
    const bf16* mp = McT + tt * 4096 + srow * 64 + scol;
    const bf16* bp = Bc + tt * 4096 + srow * 64 + scol;
    *(bf16x8*)&Msm[bu][srow][scol]     = *(const bf16x8*)(mp);
    *(bf16x8*)&Msm[bu][srow][scol + 8] = *(const bf16x8*)(mp + 8);
    *(bf16x8*)&Bsm[bu][srow][scol]     = *(const bf16x8*)(bp);
    *(bf16x8*)&Bsm[bu][srow][scol + 8] = *(const bf16x8*)(bp + 8);
    if (tid == 0) lgb[bu] = lgws[tt * 64 + 63];
  };
  stage(0, 0);
  stage(1, 1);

  for (int c = 0; c < NCHUNK_; ++c) {
    __syncthreads();   // buf[c%3] staging complete; prev-step reads done
    if (c + 2 < NCHUNK_) stage(c + 2, (c + 2) % 3);
    const int bu = c % 3;

    // store boundary state S_c (start of chunk c); off critical path
    {
      bf16* sp = Sb + ((long)hb * 64 + c) * 4096;
#pragma unroll
      for (int ni = 0; ni < 4; ++ni)
#pragma unroll
        for (int r = 0; r < 4; ++r)
          sp[(wv * 16 + r0 + r) * 64 + ni * 16 + cn] = __float2bfloat16(Sreg[ni][r]);
    }

    bf16x8 sfr0 = *(const bf16x8*)&Ssm[wv * 16 + lm][lk8];
    bf16x8 sfr1 = *(const bf16x8*)&Ssm[wv * 16 + lm][lk8 + 32];
    f32x4 kacc[4] = {};
#pragma unroll
    for (int ni = 0; ni < 4; ++ni) {
      bf16x8 b0 = *(const bf16x8*)&Msm[bu][ni * 16 + lm][lk8];
      kacc[ni] = __builtin_amdgcn_mfma_f32_16x16x32_bf16(sfr0, b0, kacc[ni], 0, 0, 0);
      bf16x8 b1 = *(const bf16x8*)&Msm[bu][ni * 16 + lm][lk8 + 32];
      kacc[ni] = __builtin_amdgcn_mfma_f32_16x16x32_bf16(sfr1, b1, kacc[ni], 0, 0, 0);
    }
    const float eend = __expf(lgb[bu]);
#pragma unroll
    for (int ni = 0; ni < 4; ++ni)
#pragma unroll
      for (int r = 0; r < 4; ++r) {
        const float bv = bsh2f(Bsm[bu][wv * 16 + r0 + r][ni * 16 + cn]);
        Sreg[ni][r] = eend * Sreg[ni][r] + kacc[ni][r] + bv;
        Ssm[wv * 16 + r0 + r][ni * 16 + cn] = f2bsh(Sreg[ni][r]);
      }
  }
}

// ---------------------------------------------------------------------------
// chunk_out (r2-validated): fully parallel over 2048 (b,h,chunk) tasks.
//   A[t,i]  = (q_t.k_i) * exp(lg_t - lg_i), i<=t
//   Dt[v,t] = U0[t,v] - (S0v . W^T)[v,t]
//   O[t,v]  = (e^{lg} q)_t . S0v  +  A . Dt
// ---------------------------------------------------------------------------
__global__ __launch_bounds__(256) void chunk_out(const bf16* __restrict__ qkv,
                                                 const bf16* __restrict__ Wws,
                                                 const bf16* __restrict__ U0ws,
                                                 const float* __restrict__ lgws,
                                                 const bf16* __restrict__ Sb,
                                                 float* __restrict__ o) {
  __shared__ short Qsm[64][72];   // q rows (later scaled in place by exp(lg_t))
  __shared__ short Ksm[64][72];   // k rows
  __shared__ short Wsm[64][72];   // W rows [t][dk]
  __shared__ short Usm[64][72];   // U0 rows [t][v]
  __shared__ short Amm[64][72];   // A rows [t][i]
  __shared__ short Dsm[64][72];   // Dt rows [v][t] (wave-private 16-row bands)
  __shared__ float lgs[64];

  const int blk = blockIdx.x;
  const int hb = blk & 31, c = blk >> 5;      // hb fast: qkv-row L2 reuse
  const long task = (long)hb * 64 + c;
  const int h = hb & 15, b = hb >> 4, kh = h >> 1;
  const long sb = (long)b * S_ + (long)c * CS_;
  const int tid = threadIdx.x, wv = tid >> 6, l = tid & 63;
  const int lm = l & 15, lk8 = (l >> 4) << 3;
  const int r0 = (l >> 4) << 2, cn = l & 15;
  const int srow = tid >> 2, scol = (tid & 3) * 16;

  // S0 fragments straight from global (L2-resident after chunk_state).
  const bf16* sp = Sb + task * 4096 + (wv * 16 + lm) * 64 + lk8;
  bf16x8 sfr0 = *(const bf16x8*)(sp);
  bf16x8 sfr1 = *(const bf16x8*)(sp + 32);

  {
    const bf16* qp = qkv + (sb + srow) * CDIM_ + kh * 64 + scol;
    const bf16* kp = qkv + (sb + srow) * CDIM_ + KEYD_ + kh * 64 + scol;
    const bf16* wp = Wws + task * 4096 + srow * 64 + scol;
    const bf16* up = U0ws + task * 4096 + srow * 64 + scol;
    *(bf16x8*)&Qsm[srow][scol]     = *(const bf16x8*)(qp);
    *(bf16x8*)&Qsm[srow][scol + 8] = *(const bf16x8*)(qp + 8);
    *(bf16x8*)&Ksm[srow][scol]     = *(const bf16x8*)(kp);
    *(bf16x8*)&Ksm[srow][scol + 8] = *(const bf16x8*)(kp + 8);
    *(bf16x8*)&Wsm[srow][scol]     = *(const bf16x8*)(wp);
    *(bf16x8*)&Wsm[srow][scol + 8] = *(const bf16x8*)(wp + 8);
    *(bf16x8*)&Usm[srow][scol]     = *(const bf16x8*)(up);
    *(bf16x8*)&Usm[srow][scol + 8] = *(const bf16x8*)(up + 8);
    if (tid < 64) lgs[tid] = lgws[task * 64 + tid];
  }
  __syncthreads();

  // A matrix: wave computes its 16 t-rows x all i.
  {
    f32x4 aacc[4] = {};
#pragma unroll
    for (int ks = 0; ks < 2; ++ks) {
      bf16x8 qa = *(const bf16x8*)&Qsm[wv * 16 + lm][lk8 + ks * 32];
#pragma unroll
      for (int ni = 0; ni < 4; ++ni) {
        bf16x8 kb = *(const bf16x8*)&Ksm[ni * 16 + lm][lk8 + ks * 32];
        aacc[ni] = __builtin_amdgcn_mfma_f32_16x16x32_bf16(qa, kb, aacc[ni], 0, 0, 0);
      }
    }
#pragma unroll
    for (int ni = 0; ni < 4; ++ni)
#pragma unroll
      for (int r = 0; r < 4; ++r) {
        const int t = wv * 16 + r0 + r, i = ni * 16 + cn;
        Amm[t][i] = f2bsh((i <= t) ? aacc[ni][r] * __expf(lgs[t] - lgs[i]) : 0.f);
      }
  }
  __syncthreads();  // all A-reads of Qsm done; now safe to scale Q in place

  {
    const float sc = __expf(lgs[srow]);       // Lambda_t
#pragma unroll
    for (int j = 0; j < 16; ++j)
      Qsm[srow][scol + j] = f2bsh(sc * bsh2f(Qsm[srow][scol + j]));
  }
  __syncthreads();

  // M1: Dt[v,t] = U0[t,v] - sum_k S0v[v,k] W[t,k]
  {
    f32x4 dacc[4] = {};
#pragma unroll
    for (int ni = 0; ni < 4; ++ni) {
      bf16x8 w0 = *(const bf16x8*)&Wsm[ni * 16 + lm][lk8];
      dacc[ni] = __builtin_amdgcn_mfma_f32_16x16x32_bf16(sfr0, w0, dacc[ni], 0, 0, 0);
      bf16x8 w1 = *(const bf16x8*)&Wsm[ni * 16 + lm][lk8 + 32];
      dacc[ni] = __builtin_amdgcn_mfma_f32_16x16x32_bf16(sfr1, w1, dacc[ni], 0, 0, 0);
    }
#pragma unroll
    for (int ni = 0; ni < 4; ++ni)
#pragma unroll
      for (int r = 0; r < 4; ++r) {
        const int t = ni * 16 + cn, v = r0 + r;
        Dsm[wv * 16 + v][t] = f2bsh(bsh2f(Usm[t][wv * 16 + v]) - dacc[ni][r]);
      }
  }
  // wave-private Dsm: in-wave ds ordering + compiler lgkmcnt suffice (no barrier)
  bf16x8 dfr0 = *(const bf16x8*)&Dsm[wv * 16 + lm][lk8];
  bf16x8 dfr1 = *(const bf16x8*)&Dsm[wv * 16 + lm][lk8 + 32];

  // M2+M3: O[t, v16] = LambdaQ . S0v + A . Dt
  {
    f32x4 oacc[4] = {};
#pragma unroll
    for (int mi = 0; mi < 4; ++mi) {
      bf16x8 q0 = *(const bf16x8*)&Qsm[mi * 16 + lm][lk8];
      oacc[mi] = __builtin_amdgcn_mfma_f32_16x16x32_bf16(q0, sfr0, oacc[mi], 0, 0, 0);
      bf16x8 q1 = *(const bf16x8*)&Qsm[mi * 16 + lm][lk8 + 32];
      oacc[mi] = __builtin_amdgcn_mfma_f32_16x16x32_bf16(q1, sfr1, oacc[mi], 0, 0, 0);
    }
#pragma unroll
    for (int mi = 0; mi < 4; ++mi) {
      bf16x8 a0 = *(const bf16x8*)&Amm[mi * 16 + lm][lk8];
      oacc[mi] = __builtin_amdgcn_mfma_f32_16x16x32_bf16(a0, dfr0, oacc[mi], 0, 0, 0);
      bf16x8 a1 = *(const bf16x8*)&Amm[mi * 16 + lm][lk8 + 32];
      oacc[mi] = __builtin_amdgcn_mfma_f32_16x16x32_bf16(a1, dfr1, oacc[mi], 0, 0, 0);
    }
#pragma unroll
    for (int mi = 0; mi < 4; ++mi)
#pragma unroll
      for (int r = 0; r < 4; ++r) {
        const int t = mi * 16 + r0 + r;
        o[(sb + t) * VALD_ + h * 64 + wv * 16 + cn] = oacc[mi][r];
      }
  }
}

// ---------------------------------------------------------------------------
// gnorm2 (r9-validated): h = o*silu(z); rmsnorm; *w -> bf16 hn.
// ---------------------------------------------------------------------------
__global__ __launch_bounds__(256) void gnorm2(const float* __restrict__ o,
                                              const float* __restrict__ z,
                                              const float* __restrict__ nw,
                                              bf16* __restrict__ hn) {
  const long idx = (long)blockIdx.x * 256 + threadIdx.x;  // M*16
  const float* op = o + idx * 64;
  const float* zp = z + idx * 64;
  float hv[64];
  float ss = 0.f;
#pragma unroll
  for (int i = 0; i < 64; ++i) {
    const float zz = zp[i];
    const float hh = op[i] * (zz / (1.f + __expf(-zz)));
    hv[i] = hh;
    ss = fmaf(hh, hh, ss);
  }
  const float r = rsqrtf(ss * (1.f / 64.f) + 1e-6f);
#pragma unroll
  for (int i = 0; i < 64; ++i)
    hn[idx * 64 + i] = __float2bfloat16(hv[i] * r * nw[i]);
}

// ---------------------------------------------------------------------------
extern "C" void kernel_launch(void* const* d_in, const int* in_sizes, int n_in,
                              void* d_out, int out_size, void* d_ws, size_t ws_size,
                              hipStream_t stream) {
  float* out = (float*)d_out;   // fp32 output (r8-confirmed)
  const int M = B_ * S_;        // 8192

  // input mapping (dict order confirmed; size-based fallback kept)
  int ih, iqkv, icw, iz, ib, ia, idtb, ialog, inw, iout;
  if (n_in >= 10 && in_sizes[0] == 8388608) {
    ih = 0; iqkv = 1; icw = 2; iz = 3; ib = 4; ia = 5;
    idtb = 6; ialog = 7; inw = 8; iout = 9;
  } else {
    ih = iqkv = icw = iz = ib = ia = idtb = ialog = inw = iout = -1;
    for (int i = 0; i < n_in; ++i) {
      switch (in_sizes[i]) {
        case 8388608: ih = i; break;
        case 2097152: iqkv = i; break;
        case 8192:    icw = i; break;
        case 64:      inw = i; break;
        case 1048576: if (iz < 0) iz = i; else iout = i; break;
        case 16384:   if (ib < 0) ib = i; else ia = i; break;
        case 16:      if (idtb < 0) idtb = i; else ialog = i; break;
        default: break;
      }
    }
  }
  const float* hs   = (const float*)d_in[ih];
  const float* Wqkv = (const float*)d_in[iqkv];
  const float* cw   = (const float*)d_in[icw];
  const float* Wz   = (const float*)d_in[iz];
  const float* Wb   = (const float*)d_in[ib];
  const float* Wa   = (const float*)d_in[ia];
  const float* dtb  = (const float*)d_in[idtb];
  const float* Alog = (const float*)d_in[ialog];
  const float* nwv  = (const float*)d_in[inw];
  const float* Wout = (const float*)d_in[iout];

  // workspace (~122 MiB): r2 layout; Mc/Bc alias region1 (mixed dead after
  // conv2; of not written until chunk_out).
  char* p = (char*)d_ws;
  bf16*  mixed = (bf16*)p;                                 // region1: 32 MiB
  float* of    = (float*)p;                                //   of aliases mixed
  bf16*  McTw  = (bf16*)p;                                 //   McT: first 16 MiB
  bf16*  Bcw   = (bf16*)(p + (size_t)2048 * 4096 * 2);     //   Bc: second 16 MiB
  p += (size_t)M * CDIM_ * 2;
  bf16*  hs_b  = (bf16*)p;                                 // region2 (16 MiB; dead after z-gemm)
  bf16*  qkvb  = (bf16*)p;                                 //   full region2
  bf16*  hn    = (bf16*)p; p += (size_t)M * CDIM_ * 2;     //   hn aliases qkvb
  bf16*  Wqkv_b= (bf16*)p; p += (size_t)CDIM_ * H_ * 2;    // 4 MiB
  bf16*  Wz_b  = (bf16*)p; p += (size_t)H_ * H_ * 2;       // 2 MiB
  bf16*  Wout_b= (bf16*)p; p += (size_t)H_ * H_ * 2;       // 2 MiB
  float* betaf = (float*)p; p += (size_t)M * NVH_ * 4;     // 512 KiB
  float* gf    = (float*)p; p += (size_t)M * NVH_ * 4;     // 512 KiB
  bf16*  Wws   = (bf16*)p; p += (size_t)2048 * 4096 * 2;   // 16 MiB
  bf16*  U0ws  = (bf16*)p; p += (size_t)2048 * 4096 * 2;   // 16 MiB
  float* lgws  = (float*)p; p += (size_t)2048 * 64 * 4;    // 512 KiB
  bf16*  Sbw   = (bf16*)p; p += (size_t)2048 * 4096 * 2;   // 16 MiB (boundary states)
  float* zb    = out;   // z fp32 staged in d_out, consumed by gnorm2

  // 0) casts fp32 -> bf16 for MFMA operands
  {
    long n;
    n = (long)M * H_;     castf2b<<<(int)(n / 4 / 256), 256, 0, stream>>>(hs,   hs_b,   n);
    n = (long)CDIM_ * H_; castf2b<<<(int)(n / 4 / 256), 256, 0, stream>>>(Wqkv, Wqkv_b, n);
    n = (long)H_ * H_;    castf2b<<<(int)(n / 4 / 256), 256, 0, stream>>>(Wz,   Wz_b,   n);
    n = (long)H_ * H_;    castf2b<<<(int)(n / 4 / 256), 256, 0, stream>>>(Wout, Wout_b, n);
  }
  // 1) mixed = hs @ Wqkv^T  [8192 x 2048] -> bf16 (MFMA)
  gemm_bt<bf16><<<(M / 128) * (CDIM_ / 128), 256, 0, stream>>>(hs_b, Wqkv_b, mixed, M, CDIM_, H_);
  // 2) z = hs @ Wz^T  [8192 x 1024] -> fp32 in d_out (MFMA)
  gemm_bt<float><<<(M / 128) * (H_ / 128), 256, 0, stream>>>(hs_b, Wz_b, zb, M, H_, H_);
  // 3) beta, g (8 rows per block)
  proj_ba2<<<M / 8, 256, 0, stream>>>(hs, Wb, Wa, dtb, Alog, betaf, gf);
  // 4) causal depthwise conv + silu + q-scale -> bf16
  conv2<<<(int)(((long)M * CDIM_) / 256), 256, 0, stream>>>(mixed, cw, qkvb);
  // 5) chunked delta-rule, decoupled:
  //    a) UT-transform precompute + affine transition pieces (fused; 2048 WGs)
  chunk_pre<<<2048, 256, 0, stream>>>(qkvb, betaf, gf, Wws, U0ws, lgws, McTw, Bcw);
  //    b) serial-but-light boundary-state recurrence (32 WGs, prefetch depth 2)
  chunk_state<<<32, 256, 0, stream>>>(McTw, Bcw, lgws, Sbw);
  //    c) per-chunk outputs (parallel 2048)
  chunk_out<<<2048, 256, 0, stream>>>(qkvb, Wws, U0ws, lgws, Sbw, of);
  // 6) gated RMSNorm -> hn bf16
  gnorm2<<<(M * NVH_) / 256, 256, 0, stream>>>(of, zb, nwv, hn);
  // 7) out = hn @ Wout^T -> d_out fp32 (MFMA)
  gemm_bt<float><<<(M / 128) * (H_ / 128), 256, 0, stream>>>(hn, Wout_b, out, M, H_, H_);
}

// Round 5
// 502.315 us; speedup vs baseline: 2.4523x; 1.0639x over previous
//
#include <hip/hip_runtime.h>
#include <hip/hip_bf16.h>
#include <stdint.h>

// Problem constants
#define B_    2
#define S_    4096
#define H_    1024
#define NKH_  8
#define NVH_  16
#define DK_   64
#define DV_   64
#define KEYD_ 512          // NKH*DK
#define CDIM_ 2048         // 2*KEYD + VAL_DIM
#define VALD_ 1024         // NVH*DV
#define NCHUNK_ 64         // S_/64
#define CS_   64           // chunk size

using bf16 = __hip_bfloat16;
using bf16x8 = __attribute__((ext_vector_type(8))) short;  // 8 bf16 = 4 VGPRs
using f32x4  = __attribute__((ext_vector_type(4))) float;

__device__ inline float bsh2f(short s) {
  union { ushort u; bf16 h; } c; c.u = (ushort)s; return __bfloat162float(c.h);
}
__device__ inline short f2bsh(float f) {
  union { ushort u; bf16 h; } c; c.h = __float2bfloat16(f); return (short)c.u;
}

// async global->LDS, 16B per lane; dest = uniform base + lane*16 (HW rule).
__device__ __forceinline__ void gload16(const bf16* g, short* lds) {
  __builtin_amdgcn_global_load_lds(
      (const __attribute__((address_space(1))) void*)g,
      (__attribute__((address_space(3))) void*)lds, 16, 0, 0);
}

// ---------------------------------------------------------------------------
// fp32 -> bf16 cast, 4 elems/thread (n % 4 == 0). (r2-validated structure)
// ---------------------------------------------------------------------------
__global__ __launch_bounds__(256) void castf2b(const float* __restrict__ x,
                                               bf16* __restrict__ y, long n) {
  const long i = ((long)blockIdx.x * 256 + threadIdx.x) * 4;
  if (i >= n) return;
  float4 v = *(const float4*)(x + i);
  union { ushort4 u; bf16 h[4]; } o;
  o.h[0] = __float2bfloat16(v.x);
  o.h[1] = __float2bfloat16(v.y);
  o.h[2] = __float2bfloat16(v.z);
  o.h[3] = __float2bfloat16(v.w);
  *(ushort4*)(y + i) = o.u;
}

// ---------------------------------------------------------------------------
// MFMA GEMM (r4-validated): C[m,n] = sum_k A[m,k]*B[n,k]; A,B bf16;
// C bf16 or fp32. 128x128 tile, 4 waves 2x2, 4x4 of 16x16x32 MFMA, BK=32.
// Staging via global_load_lds width=16 (m97 ladder step-3).
// ---------------------------------------------------------------------------
template <typename OT>
__global__ __launch_bounds__(256) void gemm_bt(const bf16* __restrict__ A,
                                               const bf16* __restrict__ Bm,
                                               OT* __restrict__ C,
                                               int M, int N, int K) {
  __shared__ short Asm[128 * 32];
  __shared__ short Bsm[128 * 32];
  const int t = threadIdx.x;
  const int w = t >> 6, l = t & 63;
  const int ntn = N >> 7;
  const int bm = blockIdx.x / ntn, bn = blockIdx.x % ntn;
  const int m0 = bm << 7, n0 = bn << 7;
  const int wm = (w >> 1) << 6, wn = (w & 1) << 6;

  f32x4 acc[4][4] = {};

  const int grow = l >> 2;            // 0..15 within slab
  const int gc8 = (l & 3) << 3;       // 0,8,16,24
  const bf16* Agl = A + (long)m0 * K + gc8;
  const bf16* Bgl = Bm + (long)n0 * K + gc8;

  const int lm = l & 15;
  const int kk = (l >> 4) << 3;
  const short* ar0 = &Asm[(wm + lm) * 32 + kk];
  const short* br0 = &Bsm[(wn + lm) * 32 + kk];

  for (int k0 = 0; k0 < K; k0 += 32) {
    __syncthreads();   // prev-iter LDS reads done
#pragma unroll
    for (int j = 0; j < 2; ++j) {
      const int s = w * 2 + j;        // slab 0..7 (wave-uniform)
      gload16(Agl + (long)(s * 16 + grow) * K + k0, &Asm[s * 16 * 32]);
      gload16(Bgl + (long)(s * 16 + grow) * K + k0, &Bsm[s * 16 * 32]);
    }
    __syncthreads();   // compiler drains vmcnt before barrier -> LDS ready
    bf16x8 af[4], bfr[4];
#pragma unroll
    for (int mi = 0; mi < 4; ++mi) af[mi] = *(const bf16x8*)(ar0 + mi * 16 * 32);
#pragma unroll
    for (int ni = 0; ni < 4; ++ni) bfr[ni] = *(const bf16x8*)(br0 + ni * 16 * 32);
#pragma unroll
    for (int mi = 0; mi < 4; ++mi)
#pragma unroll
      for (int ni = 0; ni < 4; ++ni)
        acc[mi][ni] = __builtin_amdgcn_mfma_f32_16x16x32_bf16(af[mi], bfr[ni],
                                                              acc[mi][ni], 0, 0, 0);
  }

  // C/D layout: col = l&15, row = (l>>4)*4 + reg
  const int r0 = (l >> 4) << 2;
  const int cn = l & 15;
#pragma unroll
  for (int mi = 0; mi < 4; ++mi)
#pragma unroll
    for (int ni = 0; ni < 4; ++ni) {
      long base = (long)(m0 + wm + mi * 16 + r0) * N + (n0 + wn + ni * 16 + cn);
#pragma unroll
      for (int r = 0; r < 4; ++r) {
        if constexpr (sizeof(OT) == 2)
          C[base + (long)r * N] = __float2bfloat16(acc[mi][ni][r]);
        else
          C[base + (long)r * N] = acc[mi][ni][r];
      }
    }
}

// ---------------------------------------------------------------------------
// conv3 (r5): causal depthwise k=4 conv + silu + q-scale, 8 channels/thread.
// 4 x bf16x8 row loads (guards thread-uniform) + 8 x float4 weight loads
// (L2-resident) + 1 x 16B store: 13 VMEM per 8 outputs vs 72 scalar in r4.
// Same fmaf order per element -> bitwise-identical results.
// ---------------------------------------------------------------------------
__global__ __launch_bounds__(256) void conv3(const bf16* __restrict__ mixed,
                                             const float* __restrict__ cw,
                                             bf16* __restrict__ qkv) {
  const long idx = (long)blockIdx.x * 256 + threadIdx.x;  // over M*256 groups
  const int c0 = (int)(idx & 255) << 3;                   // channel group base
  const long row = idx >> 8;
  const int s = (int)(row & (S_ - 1));

  bf16x8 mv[4];
#pragma unroll
  for (int j = 0; j < 4; ++j) {
    if (s - 3 + j >= 0)
      mv[j] = *(const bf16x8*)(mixed + (row + j - 3) * CDIM_ + c0);
    else
      mv[j] = (bf16x8){0, 0, 0, 0, 0, 0, 0, 0};
  }

  const float qs = (c0 < KEYD_) ? 0.125f : 1.f;
  union { ushort4 u4[2]; short h[8]; } o;
#pragma unroll
  for (int e = 0; e < 8; ++e) {
    const float4 w = *(const float4*)(cw + (c0 + e) * 4);
    float acc = 0.f;
    acc = fmaf(w.x, bsh2f(mv[0][e]), acc);
    acc = fmaf(w.y, bsh2f(mv[1][e]), acc);
    acc = fmaf(w.z, bsh2f(mv[2][e]), acc);
    acc = fmaf(w.w, bsh2f(mv[3][e]), acc);
    const float y = qs * (acc / (1.f + __expf(-acc)));    // silu (+ q-scale)
    o.h[e] = f2bsh(y);
  }
  *(bf16x8*)((uint16_t*)qkv + row * CDIM_ + c0) = *(bf16x8*)&o.h[0];
}

// ---------------------------------------------------------------------------
// proj_ba2 (r3-validated): 8 rows per block; W traffic cut 8x.
// ---------------------------------------------------------------------------
__global__ __launch_bounds__(256) void proj_ba2(const float* __restrict__ hs,
                                                const float* __restrict__ Wb,
                                                const float* __restrict__ Wa,
                                                const float* __restrict__ dtb,
                                                const float* __restrict__ Alog,
                                                float* __restrict__ beta,
                                                float* __restrict__ g) {
  __shared__ float4 hrow[8][257];   // +1 float4 pad
  const long row0 = (long)blockIdx.x * 8;
  const int tid = threadIdx.x;
  for (int i = tid; i < 2048; i += 256) {
    const int r = i >> 8, c4 = i & 255;
    hrow[r][c4] = *(const float4*)(hs + (row0 + r) * H_ + (long)c4 * 4);
  }
  __syncthreads();
  const int j = tid >> 3, r = tid & 7;
  const float4* Wp = (const float4*)(j < 16 ? Wb + (long)j * H_
                                            : Wa + (long)(j - 16) * H_);
  float4 a4 = {0.f, 0.f, 0.f, 0.f};
#pragma unroll 4
  for (int i = 0; i < 256; ++i) {
    const float4 w = Wp[i];
    const float4 hv = hrow[r][i];
    a4.x = fmaf(w.x, hv.x, a4.x);
    a4.y = fmaf(w.y, hv.y, a4.y);
    a4.z = fmaf(w.z, hv.z, a4.z);
    a4.w = fmaf(w.w, hv.w, a4.w);
  }
  const float acc = (a4.x + a4.y) + (a4.z + a4.w);
  const long row = row0 + r;
  if (j < 16) {
    beta[row * NVH_ + j] = 1.f / (1.f + __expf(-acc));
  } else {
    const int hh = j - 16;
    const float x = acc + dtb[hh];
    const float sp = (x > 20.f) ? x : log1pf(__expf(x));
    g[row * NVH_ + hh] = -__expf(Alog[hh]) * sp;
  }
}

// ---------------------------------------------------------------------------
// chunk_pre (r4-validated): per (b,h,chunk) task:
//   lg = cumsum(g); T[t,i] = beta_t e^{lg_t-lg_i}(k_t.k_i), i<t
//   solve (I+T)X = [diag(beta e^lg)K | diag(beta)V] -> W,U0
//   K' = e^{lg63-lg_t} k; McT = -K'^T W; Bc = U0^T K' (MFMA)
// Two-level solve: upper 32x32 fp32 -> rank-32 MFMA cross-update -> lower
// 32x32 fp32. TloB/XB alias dead Ksm/Vsm (no LDS growth).
// ---------------------------------------------------------------------------
__global__ __launch_bounds__(256) void chunk_pre(const bf16* __restrict__ qkv,
                                                 const float* __restrict__ beta,
                                                 const float* __restrict__ g,
                                                 bf16* __restrict__ Wws,
                                                 bf16* __restrict__ U0ws,
                                                 float* __restrict__ lgws,
                                                 bf16* __restrict__ McT,
                                                 bf16* __restrict__ Bc) {
  __shared__ short Ksm[64][72];
  __shared__ short Vsm[64][72];       // aliased: XB (phase2-3), U0T (post-solve)
  __shared__ float Tsm[64][64];       // aliased: WT (post-solve)
  __shared__ short KpT[64][72];       // K'^T rows [k][t]
  __shared__ float Xl[128][67];       // per-thread solution column
  __shared__ float lgs[64];
  __shared__ float bts[64];
  __shared__ float belg[64];

  // aliases (live ranges disjoint)
  short (*XB)[36]   = (short (*)[36]) & Vsm[0][0];   // bf16 Xu, [col][u]
  short (*TloB)[40] = (short (*)[40]) & Ksm[0][0];   // bf16 T[32+m][u]
  short (*WT)[72]   = (short (*)[72]) & Tsm[0][0];
  short (*U0T)[72]  = Vsm;

  const int blk = blockIdx.x;
  const int hb = blk & 31, c = blk >> 5;   // hb fast: qkv-row L2 reuse
  const long task = (long)hb * 64 + c;
  const int h = hb & 15, b = hb >> 4, kh = h >> 1;
  const long t0 = (long)b * S_ + (long)c * CS_;
  const int tid = threadIdx.x;
  const int wv = tid >> 6, l = tid & 63;
  const int lm = l & 15, lk8 = (l >> 4) << 3;
  const int r0 = (l >> 4) << 2, cn = l & 15;
  const int srow = tid >> 2, scol = (tid & 3) * 16;

  // stage K,V
  {
    const bf16* kp = qkv + (t0 + srow) * CDIM_ + KEYD_ + kh * 64 + scol;
    const bf16* vp = qkv + (t0 + srow) * CDIM_ + 2 * KEYD_ + h * 64 + scol;
    *(bf16x8*)&Ksm[srow][scol]     = *(const bf16x8*)(kp);
    *(bf16x8*)&Ksm[srow][scol + 8] = *(const bf16x8*)(kp + 8);
    *(bf16x8*)&Vsm[srow][scol]     = *(const bf16x8*)(vp);
    *(bf16x8*)&Vsm[srow][scol + 8] = *(const bf16x8*)(vp + 8);
  }
  if (tid < 64) {
    bts[tid] = beta[(t0 + tid) * NVH_ + h];
    lgs[tid] = g[(t0 + tid) * NVH_ + h];
  }
  __syncthreads();

  // wave-parallel inclusive prefix sum of g (wave 0)
  if (tid < 64) {
    float x = lgs[tid];
#pragma unroll
    for (int d = 1; d < 64; d <<= 1) {
      const float y = __shfl_up(x, d);
      if (tid >= d) x += y;
    }
    lgs[tid] = x;
    belg[tid] = bts[tid] * __expf(x);
  }
  __syncthreads();

  if (tid < 128) {
    // KK^T -> T (masked, decayed). 2 waves x 2 m-tiles x 4 n-tiles.
    f32x4 acc[2][4] = {};
#pragma unroll
    for (int ks = 0; ks < 2; ++ks) {
      bf16x8 bfr[4];
#pragma unroll
      for (int ni = 0; ni < 4; ++ni)
        bfr[ni] = *(const bf16x8*)&Ksm[ni * 16 + lm][lk8 + ks * 32];
#pragma unroll
      for (int mi = 0; mi < 2; ++mi) {
        bf16x8 afr = *(const bf16x8*)&Ksm[(wv * 2 + mi) * 16 + lm][lk8 + ks * 32];
#pragma unroll
        for (int ni = 0; ni < 4; ++ni)
          acc[mi][ni] = __builtin_amdgcn_mfma_f32_16x16x32_bf16(afr, bfr[ni],
                                                                acc[mi][ni], 0, 0, 0);
      }
    }
#pragma unroll
    for (int mi = 0; mi < 2; ++mi)
#pragma unroll
      for (int ni = 0; ni < 4; ++ni)
#pragma unroll
        for (int r = 0; r < 4; ++r) {
          const int t = (wv * 2 + mi) * 16 + r0 + r;
          const int i = ni * 16 + cn;
          Tsm[t][i] = (i < t) ? bts[t] * __expf(lgs[t] - lgs[i]) * acc[mi][ni][r]
                              : 0.f;
        }
  } else {
    // waves 2-3: build K'^T (transpose + decay) in parallel with T-build
    const int idx = tid - 128;
    const int tt = idx >> 1;
    const int o2 = (idx & 1) * 32;
    const float dec = __expf(lgs[63] - lgs[tt]);
#pragma unroll 8
    for (int k = 0; k < 32; ++k)
      KpT[o2 + k][tt] = f2bsh(dec * bsh2f(Ksm[tt][o2 + k]));
  }
  __syncthreads();   // Tsm, KpT, belg ready

  // 32x32 fp32 forward-sub on rows [base, base+32), thread-private column.
  auto solve32 = [&](int base) {
    for (int j = base; j < base + 32; j += 8) {
      float xs[8];
#pragma unroll
      for (int a = 0; a < 8; ++a) xs[a] = Xl[tid][j + a];
#pragma unroll
      for (int a = 1; a < 8; ++a)
#pragma unroll
        for (int bb = 0; bb < a; ++bb)
          xs[a] = fmaf(-Tsm[j + a][j + bb], xs[bb], xs[a]);
#pragma unroll
      for (int a = 1; a < 8; ++a) Xl[tid][j + a] = xs[a];
      const int tend = base + 32;
#pragma unroll 2
      for (int tt = j + 8; tt < tend; ++tt) {
        const float4 ta = *(const float4*)&Tsm[tt][j];
        const float4 tb = *(const float4*)&Tsm[tt][j + 4];
        float v = Xl[tid][tt];
        v = fmaf(-ta.x, xs[0], v); v = fmaf(-ta.y, xs[1], v);
        v = fmaf(-ta.z, xs[2], v); v = fmaf(-ta.w, xs[3], v);
        v = fmaf(-tb.x, xs[4], v); v = fmaf(-tb.y, xs[5], v);
        v = fmaf(-tb.z, xs[6], v); v = fmaf(-tb.w, xs[7], v);
        Xl[tid][tt] = v;
      }
    }
  };

  // phase1: rhs init (full column) + upper 32x32 solve (threads 0-127)
  if (tid < 128) {
    const int colW = tid & 63;
    const bool isW = tid < 64;
#pragma unroll 8
    for (int t = 0; t < CS_; ++t)
      Xl[tid][t] = isW ? belg[t] * bsh2f(Ksm[t][colW])
                       : bts[t] * bsh2f(Vsm[t][colW]);
    solve32(0);
  }
  if (tid < 64) lgws[task * 64 + tid] = lgs[tid];
  __syncthreads();   // Xu final; Ksm/Vsm dead -> TloB/XB may be written

  // phase2: bf16 conversions for the cross-update MFMA
  {
    const int col = tid & 127, uh = (tid >> 7) * 16;
#pragma unroll
    for (int u = 0; u < 16; ++u)
      XB[col][uh + u] = f2bsh(Xl[col][uh + u]);
  }
  if (tid < 128) {
    const int m = tid >> 2, u0 = (tid & 3) * 8;
#pragma unroll
    for (int u = 0; u < 8; ++u)
      TloB[m][u0 + u] = f2bsh(Tsm[32 + m][u0 + u]);
  }
  __syncthreads();

  // phase3: rank-32 cross-update via MFMA:
  //   Xl[c][32+t] -= sum_u T[32+t][u] * Xu[u][c]   (16 MFMAs over 4 waves)
  {
#pragma unroll
    for (int ni2 = 0; ni2 < 2; ++ni2) {
      const int ni = wv * 2 + ni2;
      bf16x8 bfr = *(const bf16x8*)&XB[ni * 16 + lm][lk8];
#pragma unroll
      for (int mi = 0; mi < 2; ++mi) {
        bf16x8 afr = *(const bf16x8*)&TloB[mi * 16 + lm][lk8];
        f32x4 uacc = {};
        uacc = __builtin_amdgcn_mfma_f32_16x16x32_bf16(afr, bfr, uacc, 0, 0, 0);
#pragma unroll
        for (int r = 0; r < 4; ++r)
          Xl[ni * 16 + cn][32 + mi * 16 + r0 + r] -= uacc[r];
      }
    }
  }
  __syncthreads();

  // phase4: lower 32x32 solve
  if (tid < 128) solve32(32);
  __syncthreads();   // solve done; Tsm/Vsm regions free for WT/U0T

  // write W/U0 to global (coalesced per row) + transposed bf16 into LDS
  if (tid < 128) {
    const int colW = tid & 63;
    const bool isW = tid < 64;
    bf16* dst = (isW ? Wws : U0ws) + task * 4096 + colW;
    short (*XT)[72] = isW ? WT : U0T;
#pragma unroll 4
    for (int t = 0; t < CS_; t += 2) {
      const float v0 = Xl[tid][t], v1 = Xl[tid][t + 1];
      dst[(long)t * 64] = __float2bfloat16(v0);
      dst[(long)(t + 1) * 64] = __float2bfloat16(v1);
      short2 pk; pk.x = f2bsh(v0); pk.y = f2bsh(v1);
      *(short2*)&XT[colW][t] = pk;
    }
  }
  __syncthreads();   // WT/U0T ready

  // McT = -(K'^T)(W^T)^T : C[m=k'][n=k] = sum_t KpT[k'][t] WT[k][t]
  {
    f32x4 macc[4] = {};
#pragma unroll
    for (int ks = 0; ks < 2; ++ks) {
      bf16x8 afr = *(const bf16x8*)&KpT[wv * 16 + lm][lk8 + ks * 32];
#pragma unroll
      for (int ni = 0; ni < 4; ++ni) {
        bf16x8 bfr = *(const bf16x8*)&WT[ni * 16 + lm][lk8 + ks * 32];
        macc[ni] = __builtin_amdgcn_mfma_f32_16x16x32_bf16(afr, bfr, macc[ni], 0, 0, 0);
      }
    }
#pragma unroll
    for (int ni = 0; ni < 4; ++ni)
#pragma unroll
      for (int r = 0; r < 4; ++r)
        McT[task * 4096 + (wv * 16 + r0 + r) * 64 + ni * 16 + cn] =
            __float2bfloat16(-macc[ni][r]);
  }
  // Bc : C[m=v][n=k'] = sum_t U0T[v][t] KpT[k'][t]
  {
    f32x4 bacc[4] = {};
#pragma unroll
    for (int ks = 0; ks < 2; ++ks) {
      bf16x8 afr = *(const bf16x8*)&U0T[wv * 16 + lm][lk8 + ks * 32];
#pragma unroll
      for (int ni = 0; ni < 4; ++ni) {
        bf16x8 bfr = *(const bf16x8*)&KpT[ni * 16 + lm][lk8 + ks * 32];
        bacc[ni] = __builtin_amdgcn_mfma_f32_16x16x32_bf16(afr, bfr, bacc[ni], 0, 0, 0);
      }
    }
#pragma unroll
    for (int ni = 0; ni < 4; ++ni)
#pragma unroll
      for (int r = 0; r < 4; ++r)
        Bc[task * 4096 + (wv * 16 + r0 + r) * 64 + ni * 16 + cn] =
            __float2bfloat16(bacc[ni][r]);
  }
}

// ---------------------------------------------------------------------------
// chunk_state (r2-validated): serial over 64 chunks, one WG per (b,h):
//   store Sbound[c] = S_c; S_{c+1} = e^{lg63} S_c (fp32) + S_c.McT (MFMA) + Bc
// ---------------------------------------------------------------------------
__global__ __launch_bounds__(256) void chunk_state(const bf16* __restrict__ McT,
                                                   const bf16* __restrict__ Bc,
                                                   const float* __restrict__ lgws,
                                                   bf16* __restrict__ Sb) {
  __shared__ short Msm[3][64][72];
  __shared__ short Bsm[3][64][72];
  __shared__ short Ssm[64][72];   // bf16 state rows [v][k] (wave-private bands)
  __shared__ float lgb[3];

  const int hb = blockIdx.x;      // b*16+h
  const int tid = threadIdx.x, wv = tid >> 6, l = tid & 63;
  const int lm = l & 15, lk8 = (l >> 4) << 3;
  const int r0 = (l >> 4) << 2, cn = l & 15;
  const int srow = tid >> 2, scol = (tid & 3) * 16;

  for (int i = tid; i < 64 * 72; i += 256) ((short*)Ssm)[i] = 0;
  f32x4 Sreg[4] = {};   // fp32 master: S[v = wv*16+r0+r][k = ni*16+cn]

  auto stage = [&](int cc, int bu) {
    const long tt = (long)hb * 64 + cc;
    const bf16* mp = McT + tt * 4096 + srow * 64 + scol;
    const bf16* bp = Bc + tt * 4096 + srow * 64 + scol;
    *(bf16x8*)&Msm[bu][srow][scol]     = *(const bf16x8*)(mp);
    *(bf16x8*)&Msm[bu][srow][scol + 8] = *(const bf16x8*)(mp + 8);
    *(bf16x8*)&Bsm[bu][srow][scol]     = *(const bf16x8*)(bp);
    *(bf16x8*)&Bsm[bu][srow][scol + 8] = *(const bf16x8*)(bp + 8);
    if (tid == 0) lgb[bu] = lgws[tt * 64 + 63];
  };
  stage(0, 0);
  stage(1, 1);

  for (int c = 0; c < NCHUNK_; ++c) {
    __syncthreads();   // buf[c%3] staging complete; prev-step reads done
    if (c + 2 < NCHUNK_) stage(c + 2, (c + 2) % 3);
    const int bu = c % 3;

    // store boundary state S_c (start of chunk c); off critical path
    {
      bf16* sp = Sb + ((long)hb * 64 + c) * 4096;
#pragma unroll
      for (int ni = 0; ni < 4; ++ni)
#pragma unroll
        for (int r = 0; r < 4; ++r)
          sp[(wv * 16 + r0 + r) * 64 + ni * 16 + cn] = __float2bfloat16(Sreg[ni][r]);
    }

    bf16x8 sfr0 = *(const bf16x8*)&Ssm[wv * 16 + lm][lk8];
    bf16x8 sfr1 = *(const bf16x8*)&Ssm[wv * 16 + lm][lk8 + 32];
    f32x4 kacc[4] = {};
#pragma unroll
    for (int ni = 0; ni < 4; ++ni) {
      bf16x8 b0 = *(const bf16x8*)&Msm[bu][ni * 16 + lm][lk8];
      kacc[ni] = __builtin_amdgcn_mfma_f32_16x16x32_bf16(sfr0, b0, kacc[ni], 0, 0, 0);
      bf16x8 b1 = *(const bf16x8*)&Msm[bu][ni * 16 + lm][lk8 + 32];
      kacc[ni] = __builtin_amdgcn_mfma_f32_16x16x32_bf16(sfr1, b1, kacc[ni], 0, 0, 0);
    }
    const float eend = __expf(lgb[bu]);
#pragma unroll
    for (int ni = 0; ni < 4; ++ni)
#pragma unroll
      for (int r = 0; r < 4; ++r) {
        const float bv = bsh2f(Bsm[bu][wv * 16 + r0 + r][ni * 16 + cn]);
        Sreg[ni][r] = eend * Sreg[ni][r] + kacc[ni][r] + bv;
        Ssm[wv * 16 + r0 + r][ni * 16 + cn] = f2bsh(Sreg[ni][r]);
      }
  }
}

// ---------------------------------------------------------------------------
// chunk_out (r2-validated): fully parallel over 2048 (b,h,chunk) tasks.
//   A[t,i]  = (q_t.k_i) * exp(lg_t - lg_i), i<=t
//   Dt[v,t] = U0[t,v] - (S0v . W^T)[v,t]
//   O[t,v]  = (e^{lg} q)_t . S0v  +  A . Dt
// ---------------------------------------------------------------------------
__global__ __launch_bounds__(256) void chunk_out(const bf16* __restrict__ qkv,
                                                 const bf16* __restrict__ Wws,
                                                 const bf16* __restrict__ U0ws,
                                                 const float* __restrict__ lgws,
                                                 const bf16* __restrict__ Sb,
                                                 float* __restrict__ o) {
  __shared__ short Qsm[64][72];   // q rows (later scaled in place by exp(lg_t))
  __shared__ short Ksm[64][72];   // k rows
  __shared__ short Wsm[64][72];   // W rows [t][dk]
  __shared__ short Usm[64][72];   // U0 rows [t][v]
  __shared__ short Amm[64][72];   // A rows [t][i]
  __shared__ short Dsm[64][72];   // Dt rows [v][t] (wave-private 16-row bands)
  __shared__ float lgs[64];

  const int blk = blockIdx.x;
  const int hb = blk & 31, c = blk >> 5;      // hb fast: qkv-row L2 reuse
  const long task = (long)hb * 64 + c;
  const int h = hb & 15, b = hb >> 4, kh = h >> 1;
  const long sb = (long)b * S_ + (long)c * CS_;
  const int tid = threadIdx.x, wv = tid >> 6, l = tid & 63;
  const int lm = l & 15, lk8 = (l >> 4) << 3;
  const int r0 = (l >> 4) << 2, cn = l & 15;
  const int srow = tid >> 2, scol = (tid & 3) * 16;

  // S0 fragments straight from global (L2-resident after chunk_state).
  const bf16* sp = Sb + task * 4096 + (wv * 16 + lm) * 64 + lk8;
  bf16x8 sfr0 = *(const bf16x8*)(sp);
  bf16x8 sfr1 = *(const bf16x8*)(sp + 32);

  {
    const bf16* qp = qkv + (sb + srow) * CDIM_ + kh * 64 + scol;
    const bf16* kp = qkv + (sb + srow) * CDIM_ + KEYD_ + kh * 64 + scol;
    const bf16* wp = Wws + task * 4096 + srow * 64 + scol;
    const bf16* up = U0ws + task * 4096 + srow * 64 + scol;
    *(bf16x8*)&Qsm[srow][scol]     = *(const bf16x8*)(qp);
    *(bf16x8*)&Qsm[srow][scol + 8] = *(const bf16x8*)(qp + 8);
    *(bf16x8*)&Ksm[srow][scol]     = *(const bf16x8*)(kp);
    *(bf16x8*)&Ksm[srow][scol + 8] = *(const bf16x8*)(kp + 8);
    *(bf16x8*)&Wsm[srow][scol]     = *(const bf16x8*)(wp);
    *(bf16x8*)&Wsm[srow][scol + 8] = *(const bf16x8*)(wp + 8);
    *(bf16x8*)&Usm[srow][scol]     = *(const bf16x8*)(up);
    *(bf16x8*)&Usm[srow][scol + 8] = *(const bf16x8*)(up + 8);
    if (tid < 64) lgs[tid] = lgws[task * 64 + tid];
  }
  __syncthreads();

  // A matrix: wave computes its 16 t-rows x all i.
  {
    f32x4 aacc[4] = {};
#pragma unroll
    for (int ks = 0; ks < 2; ++ks) {
      bf16x8 qa = *(const bf16x8*)&Qsm[wv * 16 + lm][lk8 + ks * 32];
#pragma unroll
      for (int ni = 0; ni < 4; ++ni) {
        bf16x8 kb = *(const bf16x8*)&Ksm[ni * 16 + lm][lk8 + ks * 32];
        aacc[ni] = __builtin_amdgcn_mfma_f32_16x16x32_bf16(qa, kb, aacc[ni], 0, 0, 0);
      }
    }
#pragma unroll
    for (int ni = 0; ni < 4; ++ni)
#pragma unroll
      for (int r = 0; r < 4; ++r) {
        const int t = wv * 16 + r0 + r, i = ni * 16 + cn;
        Amm[t][i] = f2bsh((i <= t) ? aacc[ni][r] * __expf(lgs[t] - lgs[i]) : 0.f);
      }
  }
  __syncthreads();  // all A-reads of Qsm done; now safe to scale Q in place

  {
    const float sc = __expf(lgs[srow]);       // Lambda_t
#pragma unroll
    for (int j = 0; j < 16; ++j)
      Qsm[srow][scol + j] = f2bsh(sc * bsh2f(Qsm[srow][scol + j]));
  }
  __syncthreads();

  // M1: Dt[v,t] = U0[t,v] - sum_k S0v[v,k] W[t,k]
  {
    f32x4 dacc[4] = {};
#pragma unroll
    for (int ni = 0; ni < 4; ++ni) {
      bf16x8 w0 = *(const bf16x8*)&Wsm[ni * 16 + lm][lk8];
      dacc[ni] = __builtin_amdgcn_mfma_f32_16x16x32_bf16(sfr0, w0, dacc[ni], 0, 0, 0);
      bf16x8 w1 = *(const bf16x8*)&Wsm[ni * 16 + lm][lk8 + 32];
      dacc[ni] = __builtin_amdgcn_mfma_f32_16x16x32_bf16(sfr1, w1, dacc[ni], 0, 0, 0);
    }
#pragma unroll
    for (int ni = 0; ni < 4; ++ni)
#pragma unroll
      for (int r = 0; r < 4; ++r) {
        const int t = ni * 16 + cn, v = r0 + r;
        Dsm[wv * 16 + v][t] = f2bsh(bsh2f(Usm[t][wv * 16 + v]) - dacc[ni][r]);
      }
  }
  // wave-private Dsm: in-wave ds ordering + compiler lgkmcnt suffice (no barrier)
  bf16x8 dfr0 = *(const bf16x8*)&Dsm[wv * 16 + lm][lk8];
  bf16x8 dfr1 = *(const bf16x8*)&Dsm[wv * 16 + lm][lk8 + 32];

  // M2+M3: O[t, v16] = LambdaQ . S0v + A . Dt
  {
    f32x4 oacc[4] = {};
#pragma unroll
    for (int mi = 0; mi < 4; ++mi) {
      bf16x8 q0 = *(const bf16x8*)&Qsm[mi * 16 + lm][lk8];
      oacc[mi] = __builtin_amdgcn_mfma_f32_16x16x32_bf16(q0, sfr0, oacc[mi], 0, 0, 0);
      bf16x8 q1 = *(const bf16x8*)&Qsm[mi * 16 + lm][lk8 + 32];
      oacc[mi] = __builtin_amdgcn_mfma_f32_16x16x32_bf16(q1, sfr1, oacc[mi], 0, 0, 0);
    }
#pragma unroll
    for (int mi = 0; mi < 4; ++mi) {
      bf16x8 a0 = *(const bf16x8*)&Amm[mi * 16 + lm][lk8];
      oacc[mi] = __builtin_amdgcn_mfma_f32_16x16x32_bf16(a0, dfr0, oacc[mi], 0, 0, 0);
      bf16x8 a1 = *(const bf16x8*)&Amm[mi * 16 + lm][lk8 + 32];
      oacc[mi] = __builtin_amdgcn_mfma_f32_16x16x32_bf16(a1, dfr1, oacc[mi], 0, 0, 0);
    }
#pragma unroll
    for (int mi = 0; mi < 4; ++mi)
#pragma unroll
      for (int r = 0; r < 4; ++r) {
        const int t = mi * 16 + r0 + r;
        o[(sb + t) * VALD_ + h * 64 + wv * 16 + cn] = oacc[mi][r];
      }
  }
}

// ---------------------------------------------------------------------------
// gnorm3 (r5): h = o*silu(z); rmsnorm; *w -> bf16 hn. float4 loads, bf16x8
// stores (40 VMEM/thread vs 192 scalar in r4). Same fp order -> same results.
// ---------------------------------------------------------------------------
__global__ __launch_bounds__(256) void gnorm3(const float* __restrict__ o,
                                              const float* __restrict__ z,
                                              const float* __restrict__ nw,
                                              bf16* __restrict__ hn) {
  const long idx = (long)blockIdx.x * 256 + threadIdx.x;  // M*16
  const float* op = o + idx * 64;
  const float* zp = z + idx * 64;
  float4 hv[16];
  float ss = 0.f;
#pragma unroll
  for (int i = 0; i < 16; ++i) {
    const float4 ov = *(const float4*)(op + i * 4);
    const float4 zv = *(const float4*)(zp + i * 4);
    float4 h;
    h.x = ov.x * (zv.x / (1.f + __expf(-zv.x)));
    h.y = ov.y * (zv.y / (1.f + __expf(-zv.y)));
    h.z = ov.z * (zv.z / (1.f + __expf(-zv.z)));
    h.w = ov.w * (zv.w / (1.f + __expf(-zv.w)));
    hv[i] = h;
    ss = fmaf(h.x, h.x, ss); ss = fmaf(h.y, h.y, ss);
    ss = fmaf(h.z, h.z, ss); ss = fmaf(h.w, h.w, ss);
  }
  const float r = rsqrtf(ss * (1.f / 64.f) + 1e-6f);
#pragma unroll
  for (int i = 0; i < 16; i += 2) {
    const float4 w0 = *(const float4*)(nw + i * 4);
    const float4 w1 = *(const float4*)(nw + i * 4 + 4);
    bf16x8 pk;
    pk[0] = f2bsh(hv[i].x * r * w0.x);     pk[1] = f2bsh(hv[i].y * r * w0.y);
    pk[2] = f2bsh(hv[i].z * r * w0.z);     pk[3] = f2bsh(hv[i].w * r * w0.w);
    pk[4] = f2bsh(hv[i + 1].x * r * w1.x); pk[5] = f2bsh(hv[i + 1].y * r * w1.y);
    pk[6] = f2bsh(hv[i + 1].z * r * w1.z); pk[7] = f2bsh(hv[i + 1].w * r * w1.w);
    *(bf16x8*)((uint16_t*)hn + idx * 64 + i * 4) = pk;
  }
}

// ---------------------------------------------------------------------------
extern "C" void kernel_launch(void* const* d_in, const int* in_sizes, int n_in,
                              void* d_out, int out_size, void* d_ws, size_t ws_size,
                              hipStream_t stream) {
  float* out = (float*)d_out;   // fp32 output (r8-confirmed)
  const int M = B_ * S_;        // 8192

  // input mapping (dict order confirmed; size-based fallback kept)
  int ih, iqkv, icw, iz, ib, ia, idtb, ialog, inw, iout;
  if (n_in >= 10 && in_sizes[0] == 8388608) {
    ih = 0; iqkv = 1; icw = 2; iz = 3; ib = 4; ia = 5;
    idtb = 6; ialog = 7; inw = 8; iout = 9;
  } else {
    ih = iqkv = icw = iz = ib = ia = idtb = ialog = inw = iout = -1;
    for (int i = 0; i < n_in; ++i) {
      switch (in_sizes[i]) {
        case 8388608: ih = i; break;
        case 2097152: iqkv = i; break;
        case 8192:    icw = i; break;
        case 64:      inw = i; break;
        case 1048576: if (iz < 0) iz = i; else iout = i; break;
        case 16384:   if (ib < 0) ib = i; else ia = i; break;
        case 16:      if (idtb < 0) idtb = i; else ialog = i; break;
        default: break;
      }
    }
  }
  const float* hs   = (const float*)d_in[ih];
  const float* Wqkv = (const float*)d_in[iqkv];
  const float* cw   = (const float*)d_in[icw];
  const float* Wz   = (const float*)d_in[iz];
  const float* Wb   = (const float*)d_in[ib];
  const float* Wa   = (const float*)d_in[ia];
  const float* dtb  = (const float*)d_in[idtb];
  const float* Alog = (const float*)d_in[ialog];
  const float* nwv  = (const float*)d_in[inw];
  const float* Wout = (const float*)d_in[iout];

  // workspace (~122 MiB): r2 layout; Mc/Bc alias region1 (mixed dead after
  // conv; of not written until chunk_out).
  char* p = (char*)d_ws;
  bf16*  mixed = (bf16*)p;                                 // region1: 32 MiB
  float* of    = (float*)p;                                //   of aliases mixed
  bf16*  McTw  = (bf16*)p;                                 //   McT: first 16 MiB
  bf16*  Bcw   = (bf16*)(p + (size_t)2048 * 4096 * 2);     //   Bc: second 16 MiB
  p += (size_t)M * CDIM_ * 2;
  bf16*  hs_b  = (bf16*)p;                                 // region2 (16 MiB; dead after z-gemm)
  bf16*  qkvb  = (bf16*)p;                                 //   full region2
  bf16*  hn    = (bf16*)p; p += (size_t)M * CDIM_ * 2;     //   hn aliases qkvb
  bf16*  Wqkv_b= (bf16*)p; p += (size_t)CDIM_ * H_ * 2;    // 4 MiB
  bf16*  Wz_b  = (bf16*)p; p += (size_t)H_ * H_ * 2;       // 2 MiB
  bf16*  Wout_b= (bf16*)p; p += (size_t)H_ * H_ * 2;       // 2 MiB
  float* betaf = (float*)p; p += (size_t)M * NVH_ * 4;     // 512 KiB
  float* gf    = (float*)p; p += (size_t)M * NVH_ * 4;     // 512 KiB
  bf16*  Wws   = (bf16*)p; p += (size_t)2048 * 4096 * 2;   // 16 MiB
  bf16*  U0ws  = (bf16*)p; p += (size_t)2048 * 4096 * 2;   // 16 MiB
  float* lgws  = (float*)p; p += (size_t)2048 * 64 * 4;    // 512 KiB
  bf16*  Sbw   = (bf16*)p; p += (size_t)2048 * 4096 * 2;   // 16 MiB (boundary states)
  float* zb    = out;   // z fp32 staged in d_out, consumed by gnorm3

  // 0) casts fp32 -> bf16 for MFMA operands
  {
    long n;
    n = (long)M * H_;     castf2b<<<(int)(n / 4 / 256), 256, 0, stream>>>(hs,   hs_b,   n);
    n = (long)CDIM_ * H_; castf2b<<<(int)(n / 4 / 256), 256, 0, stream>>>(Wqkv, Wqkv_b, n);
    n = (long)H_ * H_;    castf2b<<<(int)(n / 4 / 256), 256, 0, stream>>>(Wz,   Wz_b,   n);
    n = (long)H_ * H_;    castf2b<<<(int)(n / 4 / 256), 256, 0, stream>>>(Wout, Wout_b, n);
  }
  // 1) mixed = hs @ Wqkv^T  [8192 x 2048] -> bf16 (MFMA)
  gemm_bt<bf16><<<(M / 128) * (CDIM_ / 128), 256, 0, stream>>>(hs_b, Wqkv_b, mixed, M, CDIM_, H_);
  // 2) z = hs @ Wz^T  [8192 x 1024] -> fp32 in d_out (MFMA)
  gemm_bt<float><<<(M / 128) * (H_ / 128), 256, 0, stream>>>(hs_b, Wz_b, zb, M, H_, H_);
  // 3) beta, g (8 rows per block)
  proj_ba2<<<M / 8, 256, 0, stream>>>(hs, Wb, Wa, dtb, Alog, betaf, gf);
  // 4) causal depthwise conv + silu + q-scale -> bf16 (8 ch/thread vectorized)
  conv3<<<(int)(((long)M * CDIM_) / 8 / 256), 256, 0, stream>>>(mixed, cw, qkvb);
  // 5) chunked delta-rule, decoupled:
  //    a) UT-transform precompute + affine transition pieces (fused; 2048 WGs)
  chunk_pre<<<2048, 256, 0, stream>>>(qkvb, betaf, gf, Wws, U0ws, lgws, McTw, Bcw);
  //    b) serial-but-light boundary-state recurrence (32 WGs, prefetch depth 2)
  chunk_state<<<32, 256, 0, stream>>>(McTw, Bcw, lgws, Sbw);
  //    c) per-chunk outputs (parallel 2048)
  chunk_out<<<2048, 256, 0, stream>>>(qkvb, Wws, U0ws, lgws, Sbw, of);
  // 6) gated RMSNorm -> hn bf16 (vectorized)
  gnorm3<<<(M * NVH_) / 256, 256, 0, stream>>>(of, zb, nwv, hn);
  // 7) out = hn @ Wout^T -> d_out fp32 (MFMA)
  gemm_bt<float><<<(M / 128) * (H_ / 128), 256, 0, stream>>>(hn, Wout_b, out, M, H_, H_);
}

// Round 6
// 477.795 us; speedup vs baseline: 2.5781x; 1.0513x over previous
//
#include <hip/hip_runtime.h>
#include <hip/hip_bf16.h>
#include <stdint.h>

// Problem constants
#define B_    2
#define S_    4096
#define H_    1024
#define NKH_  8
#define NVH_  16
#define DK_   64
#define DV_   64
#define KEYD_ 512          // NKH*DK
#define CDIM_ 2048         // 2*KEYD + VAL_DIM
#define VALD_ 1024         // NVH*DV
#define NCHUNK_ 64         // S_/64
#define CS_   64           // chunk size

using bf16 = __hip_bfloat16;
using bf16x8 = __attribute__((ext_vector_type(8))) short;  // 8 bf16 = 4 VGPRs
using f32x4  = __attribute__((ext_vector_type(4))) float;

__device__ inline float bsh2f(short s) {
  union { ushort u; bf16 h; } c; c.u = (ushort)s; return __bfloat162float(c.h);
}
__device__ inline short f2bsh(float f) {
  union { ushort u; bf16 h; } c; c.h = __float2bfloat16(f); return (short)c.u;
}

// async global->LDS, 16B per lane; dest = uniform base + lane*16 (HW rule).
__device__ __forceinline__ void gload16(const bf16* g, short* lds) {
  __builtin_amdgcn_global_load_lds(
      (const __attribute__((address_space(1))) void*)g,
      (__attribute__((address_space(3))) void*)lds, 16, 0, 0);
}

// ---------------------------------------------------------------------------
// fp32 -> bf16 cast, 4 elems/thread (n % 4 == 0). (r2-validated structure)
// ---------------------------------------------------------------------------
__global__ __launch_bounds__(256) void castf2b(const float* __restrict__ x,
                                               bf16* __restrict__ y, long n) {
  const long i = ((long)blockIdx.x * 256 + threadIdx.x) * 4;
  if (i >= n) return;
  float4 v = *(const float4*)(x + i);
  union { ushort4 u; bf16 h[4]; } o;
  o.h[0] = __float2bfloat16(v.x);
  o.h[1] = __float2bfloat16(v.y);
  o.h[2] = __float2bfloat16(v.z);
  o.h[3] = __float2bfloat16(v.w);
  *(ushort4*)(y + i) = o.u;
}

// ---------------------------------------------------------------------------
// MFMA GEMM (r4-validated): C[m,n] = sum_k A[m,k]*B[n,k]; A,B bf16;
// C bf16 or fp32. 128x128 tile, 4 waves 2x2, 4x4 of 16x16x32 MFMA, BK=32.
// Staging via global_load_lds width=16 (m97 ladder step-3).
// ---------------------------------------------------------------------------
template <typename OT>
__global__ __launch_bounds__(256) void gemm_bt(const bf16* __restrict__ A,
                                               const bf16* __restrict__ Bm,
                                               OT* __restrict__ C,
                                               int M, int N, int K) {
  __shared__ short Asm[128 * 32];
  __shared__ short Bsm[128 * 32];
  const int t = threadIdx.x;
  const int w = t >> 6, l = t & 63;
  const int ntn = N >> 7;
  const int bm = blockIdx.x / ntn, bn = blockIdx.x % ntn;
  const int m0 = bm << 7, n0 = bn << 7;
  const int wm = (w >> 1) << 6, wn = (w & 1) << 6;

  f32x4 acc[4][4] = {};

  const int grow = l >> 2;            // 0..15 within slab
  const int gc8 = (l & 3) << 3;       // 0,8,16,24
  const bf16* Agl = A + (long)m0 * K + gc8;
  const bf16* Bgl = Bm + (long)n0 * K + gc8;

  const int lm = l & 15;
  const int kk = (l >> 4) << 3;
  const short* ar0 = &Asm[(wm + lm) * 32 + kk];
  const short* br0 = &Bsm[(wn + lm) * 32 + kk];

  for (int k0 = 0; k0 < K; k0 += 32) {
    __syncthreads();   // prev-iter LDS reads done
#pragma unroll
    for (int j = 0; j < 2; ++j) {
      const int s = w * 2 + j;        // slab 0..7 (wave-uniform)
      gload16(Agl + (long)(s * 16 + grow) * K + k0, &Asm[s * 16 * 32]);
      gload16(Bgl + (long)(s * 16 + grow) * K + k0, &Bsm[s * 16 * 32]);
    }
    __syncthreads();   // compiler drains vmcnt before barrier -> LDS ready
    bf16x8 af[4], bfr[4];
#pragma unroll
    for (int mi = 0; mi < 4; ++mi) af[mi] = *(const bf16x8*)(ar0 + mi * 16 * 32);
#pragma unroll
    for (int ni = 0; ni < 4; ++ni) bfr[ni] = *(const bf16x8*)(br0 + ni * 16 * 32);
#pragma unroll
    for (int mi = 0; mi < 4; ++mi)
#pragma unroll
      for (int ni = 0; ni < 4; ++ni)
        acc[mi][ni] = __builtin_amdgcn_mfma_f32_16x16x32_bf16(af[mi], bfr[ni],
                                                              acc[mi][ni], 0, 0, 0);
  }

  // C/D layout: col = l&15, row = (l>>4)*4 + reg
  const int r0 = (l >> 4) << 2;
  const int cn = l & 15;
#pragma unroll
  for (int mi = 0; mi < 4; ++mi)
#pragma unroll
    for (int ni = 0; ni < 4; ++ni) {
      long base = (long)(m0 + wm + mi * 16 + r0) * N + (n0 + wn + ni * 16 + cn);
#pragma unroll
      for (int r = 0; r < 4; ++r) {
        if constexpr (sizeof(OT) == 2)
          C[base + (long)r * N] = __float2bfloat16(acc[mi][ni][r]);
        else
          C[base + (long)r * N] = acc[mi][ni][r];
      }
    }
}

// ---------------------------------------------------------------------------
// conv3 (r5-validated): causal depthwise k=4 conv + silu + q-scale, 8 ch/thr.
// ---------------------------------------------------------------------------
__global__ __launch_bounds__(256) void conv3(const bf16* __restrict__ mixed,
                                             const float* __restrict__ cw,
                                             bf16* __restrict__ qkv) {
  const long idx = (long)blockIdx.x * 256 + threadIdx.x;  // over M*256 groups
  const int c0 = (int)(idx & 255) << 3;                   // channel group base
  const long row = idx >> 8;
  const int s = (int)(row & (S_ - 1));

  bf16x8 mv[4];
#pragma unroll
  for (int j = 0; j < 4; ++j) {
    if (s - 3 + j >= 0)
      mv[j] = *(const bf16x8*)(mixed + (row + j - 3) * CDIM_ + c0);
    else
      mv[j] = (bf16x8){0, 0, 0, 0, 0, 0, 0, 0};
  }

  const float qs = (c0 < KEYD_) ? 0.125f : 1.f;
  union { ushort4 u4[2]; short h[8]; } o;
#pragma unroll
  for (int e = 0; e < 8; ++e) {
    const float4 w = *(const float4*)(cw + (c0 + e) * 4);
    float acc = 0.f;
    acc = fmaf(w.x, bsh2f(mv[0][e]), acc);
    acc = fmaf(w.y, bsh2f(mv[1][e]), acc);
    acc = fmaf(w.z, bsh2f(mv[2][e]), acc);
    acc = fmaf(w.w, bsh2f(mv[3][e]), acc);
    const float y = qs * (acc / (1.f + __expf(-acc)));    // silu (+ q-scale)
    o.h[e] = f2bsh(y);
  }
  *(bf16x8*)((uint16_t*)qkv + row * CDIM_ + c0) = *(bf16x8*)&o.h[0];
}

// ---------------------------------------------------------------------------
// proj_ba2 (r3-validated): 8 rows per block; W traffic cut 8x.
// ---------------------------------------------------------------------------
__global__ __launch_bounds__(256) void proj_ba2(const float* __restrict__ hs,
                                                const float* __restrict__ Wb,
                                                const float* __restrict__ Wa,
                                                const float* __restrict__ dtb,
                                                const float* __restrict__ Alog,
                                                float* __restrict__ beta,
                                                float* __restrict__ g) {
  __shared__ float4 hrow[8][257];   // +1 float4 pad
  const long row0 = (long)blockIdx.x * 8;
  const int tid = threadIdx.x;
  for (int i = tid; i < 2048; i += 256) {
    const int r = i >> 8, c4 = i & 255;
    hrow[r][c4] = *(const float4*)(hs + (row0 + r) * H_ + (long)c4 * 4);
  }
  __syncthreads();
  const int j = tid >> 3, r = tid & 7;
  const float4* Wp = (const float4*)(j < 16 ? Wb + (long)j * H_
                                            : Wa + (long)(j - 16) * H_);
  float4 a4 = {0.f, 0.f, 0.f, 0.f};
#pragma unroll 4
  for (int i = 0; i < 256; ++i) {
    const float4 w = Wp[i];
    const float4 hv = hrow[r][i];
    a4.x = fmaf(w.x, hv.x, a4.x);
    a4.y = fmaf(w.y, hv.y, a4.y);
    a4.z = fmaf(w.z, hv.z, a4.z);
    a4.w = fmaf(w.w, hv.w, a4.w);
  }
  const float acc = (a4.x + a4.y) + (a4.z + a4.w);
  const long row = row0 + r;
  if (j < 16) {
    beta[row * NVH_ + j] = 1.f / (1.f + __expf(-acc));
  } else {
    const int hh = j - 16;
    const float x = acc + dtb[hh];
    const float sp = (x > 20.f) ? x : log1pf(__expf(x));
    g[row * NVH_ + hh] = -__expf(Alog[hh]) * sp;
  }
}

// ---------------------------------------------------------------------------
// chunk_pre (r4-validated): per (b,h,chunk) task:
//   lg = cumsum(g); T[t,i] = beta_t e^{lg_t-lg_i}(k_t.k_i), i<t
//   solve (I+T)X = [diag(beta e^lg)K | diag(beta)V] -> W,U0
//   K' = e^{lg63-lg_t} k; McT = -K'^T W; Bc = U0^T K' (MFMA)
// Two-level solve: upper 32x32 fp32 -> rank-32 MFMA cross-update -> lower
// 32x32 fp32. TloB/XB alias dead Ksm/Vsm (no LDS growth).
// ---------------------------------------------------------------------------
__global__ __launch_bounds__(256) void chunk_pre(const bf16* __restrict__ qkv,
                                                 const float* __restrict__ beta,
                                                 const float* __restrict__ g,
                                                 bf16* __restrict__ Wws,
                                                 bf16* __restrict__ U0ws,
                                                 float* __restrict__ lgws,
                                                 bf16* __restrict__ McT,
                                                 bf16* __restrict__ Bc) {
  __shared__ short Ksm[64][72];
  __shared__ short Vsm[64][72];       // aliased: XB (phase2-3), U0T (post-solve)
  __shared__ float Tsm[64][64];       // aliased: WT (post-solve)
  __shared__ short KpT[64][72];       // K'^T rows [k][t]
  __shared__ float Xl[128][67];       // per-thread solution column
  __shared__ float lgs[64];
  __shared__ float bts[64];
  __shared__ float belg[64];

  // aliases (live ranges disjoint)
  short (*XB)[36]   = (short (*)[36]) & Vsm[0][0];   // bf16 Xu, [col][u]
  short (*TloB)[40] = (short (*)[40]) & Ksm[0][0];   // bf16 T[32+m][u]
  short (*WT)[72]   = (short (*)[72]) & Tsm[0][0];
  short (*U0T)[72]  = Vsm;

  const int blk = blockIdx.x;
  const int hb = blk & 31, c = blk >> 5;   // hb fast: qkv-row L2 reuse
  const long task = (long)hb * 64 + c;
  const int h = hb & 15, b = hb >> 4, kh = h >> 1;
  const long t0 = (long)b * S_ + (long)c * CS_;
  const int tid = threadIdx.x;
  const int wv = tid >> 6, l = tid & 63;
  const int lm = l & 15, lk8 = (l >> 4) << 3;
  const int r0 = (l >> 4) << 2, cn = l & 15;
  const int srow = tid >> 2, scol = (tid & 3) * 16;

  // stage K,V
  {
    const bf16* kp = qkv + (t0 + srow) * CDIM_ + KEYD_ + kh * 64 + scol;
    const bf16* vp = qkv + (t0 + srow) * CDIM_ + 2 * KEYD_ + h * 64 + scol;
    *(bf16x8*)&Ksm[srow][scol]     = *(const bf16x8*)(kp);
    *(bf16x8*)&Ksm[srow][scol + 8] = *(const bf16x8*)(kp + 8);
    *(bf16x8*)&Vsm[srow][scol]     = *(const bf16x8*)(vp);
    *(bf16x8*)&Vsm[srow][scol + 8] = *(const bf16x8*)(vp + 8);
  }
  if (tid < 64) {
    bts[tid] = beta[(t0 + tid) * NVH_ + h];
    lgs[tid] = g[(t0 + tid) * NVH_ + h];
  }
  __syncthreads();

  // wave-parallel inclusive prefix sum of g (wave 0)
  if (tid < 64) {
    float x = lgs[tid];
#pragma unroll
    for (int d = 1; d < 64; d <<= 1) {
      const float y = __shfl_up(x, d);
      if (tid >= d) x += y;
    }
    lgs[tid] = x;
    belg[tid] = bts[tid] * __expf(x);
  }
  __syncthreads();

  if (tid < 128) {
    // KK^T -> T (masked, decayed). 2 waves x 2 m-tiles x 4 n-tiles.
    f32x4 acc[2][4] = {};
#pragma unroll
    for (int ks = 0; ks < 2; ++ks) {
      bf16x8 bfr[4];
#pragma unroll
      for (int ni = 0; ni < 4; ++ni)
        bfr[ni] = *(const bf16x8*)&Ksm[ni * 16 + lm][lk8 + ks * 32];
#pragma unroll
      for (int mi = 0; mi < 2; ++mi) {
        bf16x8 afr = *(const bf16x8*)&Ksm[(wv * 2 + mi) * 16 + lm][lk8 + ks * 32];
#pragma unroll
        for (int ni = 0; ni < 4; ++ni)
          acc[mi][ni] = __builtin_amdgcn_mfma_f32_16x16x32_bf16(afr, bfr[ni],
                                                                acc[mi][ni], 0, 0, 0);
      }
    }
#pragma unroll
    for (int mi = 0; mi < 2; ++mi)
#pragma unroll
      for (int ni = 0; ni < 4; ++ni)
#pragma unroll
        for (int r = 0; r < 4; ++r) {
          const int t = (wv * 2 + mi) * 16 + r0 + r;
          const int i = ni * 16 + cn;
          Tsm[t][i] = (i < t) ? bts[t] * __expf(lgs[t] - lgs[i]) * acc[mi][ni][r]
                              : 0.f;
        }
  } else {
    // waves 2-3: build K'^T (transpose + decay) in parallel with T-build
    const int idx = tid - 128;
    const int tt = idx >> 1;
    const int o2 = (idx & 1) * 32;
    const float dec = __expf(lgs[63] - lgs[tt]);
#pragma unroll 8
    for (int k = 0; k < 32; ++k)
      KpT[o2 + k][tt] = f2bsh(dec * bsh2f(Ksm[tt][o2 + k]));
  }
  __syncthreads();   // Tsm, KpT, belg ready

  // 32x32 fp32 forward-sub on rows [base, base+32), thread-private column.
  auto solve32 = [&](int base) {
    for (int j = base; j < base + 32; j += 8) {
      float xs[8];
#pragma unroll
      for (int a = 0; a < 8; ++a) xs[a] = Xl[tid][j + a];
#pragma unroll
      for (int a = 1; a < 8; ++a)
#pragma unroll
        for (int bb = 0; bb < a; ++bb)
          xs[a] = fmaf(-Tsm[j + a][j + bb], xs[bb], xs[a]);
#pragma unroll
      for (int a = 1; a < 8; ++a) Xl[tid][j + a] = xs[a];
      const int tend = base + 32;
#pragma unroll 2
      for (int tt = j + 8; tt < tend; ++tt) {
        const float4 ta = *(const float4*)&Tsm[tt][j];
        const float4 tb = *(const float4*)&Tsm[tt][j + 4];
        float v = Xl[tid][tt];
        v = fmaf(-ta.x, xs[0], v); v = fmaf(-ta.y, xs[1], v);
        v = fmaf(-ta.z, xs[2], v); v = fmaf(-ta.w, xs[3], v);
        v = fmaf(-tb.x, xs[4], v); v = fmaf(-tb.y, xs[5], v);
        v = fmaf(-tb.z, xs[6], v); v = fmaf(-tb.w, xs[7], v);
        Xl[tid][tt] = v;
      }
    }
  };

  // phase1: rhs init (full column) + upper 32x32 solve (threads 0-127)
  if (tid < 128) {
    const int colW = tid & 63;
    const bool isW = tid < 64;
#pragma unroll 8
    for (int t = 0; t < CS_; ++t)
      Xl[tid][t] = isW ? belg[t] * bsh2f(Ksm[t][colW])
                       : bts[t] * bsh2f(Vsm[t][colW]);
    solve32(0);
  }
  if (tid < 64) lgws[task * 64 + tid] = lgs[tid];
  __syncthreads();   // Xu final; Ksm/Vsm dead -> TloB/XB may be written

  // phase2: bf16 conversions for the cross-update MFMA
  {
    const int col = tid & 127, uh = (tid >> 7) * 16;
#pragma unroll
    for (int u = 0; u < 16; ++u)
      XB[col][uh + u] = f2bsh(Xl[col][uh + u]);
  }
  if (tid < 128) {
    const int m = tid >> 2, u0 = (tid & 3) * 8;
#pragma unroll
    for (int u = 0; u < 8; ++u)
      TloB[m][u0 + u] = f2bsh(Tsm[32 + m][u0 + u]);
  }
  __syncthreads();

  // phase3: rank-32 cross-update via MFMA:
  //   Xl[c][32+t] -= sum_u T[32+t][u] * Xu[u][c]   (16 MFMAs over 4 waves)
  {
#pragma unroll
    for (int ni2 = 0; ni2 < 2; ++ni2) {
      const int ni = wv * 2 + ni2;
      bf16x8 bfr = *(const bf16x8*)&XB[ni * 16 + lm][lk8];
#pragma unroll
      for (int mi = 0; mi < 2; ++mi) {
        bf16x8 afr = *(const bf16x8*)&TloB[mi * 16 + lm][lk8];
        f32x4 uacc = {};
        uacc = __builtin_amdgcn_mfma_f32_16x16x32_bf16(afr, bfr, uacc, 0, 0, 0);
#pragma unroll
        for (int r = 0; r < 4; ++r)
          Xl[ni * 16 + cn][32 + mi * 16 + r0 + r] -= uacc[r];
      }
    }
  }
  __syncthreads();

  // phase4: lower 32x32 solve
  if (tid < 128) solve32(32);
  __syncthreads();   // solve done; Tsm/Vsm regions free for WT/U0T

  // write W/U0 to global (coalesced per row) + transposed bf16 into LDS
  if (tid < 128) {
    const int colW = tid & 63;
    const bool isW = tid < 64;
    bf16* dst = (isW ? Wws : U0ws) + task * 4096 + colW;
    short (*XT)[72] = isW ? WT : U0T;
#pragma unroll 4
    for (int t = 0; t < CS_; t += 2) {
      const float v0 = Xl[tid][t], v1 = Xl[tid][t + 1];
      dst[(long)t * 64] = __float2bfloat16(v0);
      dst[(long)(t + 1) * 64] = __float2bfloat16(v1);
      short2 pk; pk.x = f2bsh(v0); pk.y = f2bsh(v1);
      *(short2*)&XT[colW][t] = pk;
    }
  }
  __syncthreads();   // WT/U0T ready

  // McT = -(K'^T)(W^T)^T : C[m=k'][n=k] = sum_t KpT[k'][t] WT[k][t]
  {
    f32x4 macc[4] = {};
#pragma unroll
    for (int ks = 0; ks < 2; ++ks) {
      bf16x8 afr = *(const bf16x8*)&KpT[wv * 16 + lm][lk8 + ks * 32];
#pragma unroll
      for (int ni = 0; ni < 4; ++ni) {
        bf16x8 bfr = *(const bf16x8*)&WT[ni * 16 + lm][lk8 + ks * 32];
        macc[ni] = __builtin_amdgcn_mfma_f32_16x16x32_bf16(afr, bfr, macc[ni], 0, 0, 0);
      }
    }
#pragma unroll
    for (int ni = 0; ni < 4; ++ni)
#pragma unroll
      for (int r = 0; r < 4; ++r)
        McT[task * 4096 + (wv * 16 + r0 + r) * 64 + ni * 16 + cn] =
            __float2bfloat16(-macc[ni][r]);
  }
  // Bc : C[m=v][n=k'] = sum_t U0T[v][t] KpT[k'][t]
  {
    f32x4 bacc[4] = {};
#pragma unroll
    for (int ks = 0; ks < 2; ++ks) {
      bf16x8 afr = *(const bf16x8*)&U0T[wv * 16 + lm][lk8 + ks * 32];
#pragma unroll
      for (int ni = 0; ni < 4; ++ni) {
        bf16x8 bfr = *(const bf16x8*)&KpT[ni * 16 + lm][lk8 + ks * 32];
        bacc[ni] = __builtin_amdgcn_mfma_f32_16x16x32_bf16(afr, bfr, bacc[ni], 0, 0, 0);
      }
    }
#pragma unroll
    for (int ni = 0; ni < 4; ++ni)
#pragma unroll
      for (int r = 0; r < 4; ++r)
        Bc[task * 4096 + (wv * 16 + r0 + r) * 64 + ni * 16 + cn] =
            __float2bfloat16(bacc[ni][r]);
  }
}

// ---------------------------------------------------------------------------
// chunk_state (r6): serial recurrence, 4 CHUNKS PER BARRIER-GROUP (16 groups).
// T14 async split: body = {LDS-write next group (regs) ; issue g+2 loads into
// regs ; compute 4 chunks} -> the ~900cy Mc/Bc load latency hides under the
// 4-chunk MFMA/LDS chain instead of being drained once per chunk.
// Op order per chunk identical to r5 -> bitwise-identical results.
// LDS: 2 groups x 4 chunks x (M+B) + Ssm = ~156.7 KB (fits 160 KB; 32 WGs
// get a CU each, occupancy is irrelevant).
// ---------------------------------------------------------------------------
__global__ __launch_bounds__(256) void chunk_state(const bf16* __restrict__ McT,
                                                   const bf16* __restrict__ Bc,
                                                   const float* __restrict__ lgws,
                                                   bf16* __restrict__ Sb) {
  __shared__ short Msm[2][4][64][72];
  __shared__ short Bsm[2][4][64][72];
  __shared__ short Ssm[64][72];   // bf16 state rows [v][k] (wave-private bands)
  __shared__ float lgsm[2][4];

  const int hb = blockIdx.x;      // b*16+h
  const int tid = threadIdx.x, wv = tid >> 6, l = tid & 63;
  const int lm = l & 15, lk8 = (l >> 4) << 3;
  const int r0 = (l >> 4) << 2, cn = l & 15;
  const int srow = tid >> 2, scol = (tid & 3) * 16;

  for (int i = tid; i < 64 * 72; i += 256) ((short*)Ssm)[i] = 0;
  f32x4 Sreg[4] = {};   // fp32 master: S[v = wv*16+r0+r][k = ni*16+cn]

  // next-group staging registers (4 chunks x (M,B) x 2 bf16x8 = 64 VGPRs)
  bf16x8 mr0[4], mr1[4], br0[4], br1[4];
  float lgn0, lgn1, lgn2, lgn3;

  auto gload = [&](int g) {   // issue global loads for group g into regs
#pragma unroll
    for (int cc = 0; cc < 4; ++cc) {
      const long tt = (long)hb * 64 + g * 4 + cc;
      const bf16* mp = McT + tt * 4096 + srow * 64 + scol;
      const bf16* bp = Bc + tt * 4096 + srow * 64 + scol;
      mr0[cc] = *(const bf16x8*)(mp);
      mr1[cc] = *(const bf16x8*)(mp + 8);
      br0[cc] = *(const bf16x8*)(bp);
      br1[cc] = *(const bf16x8*)(bp + 8);
    }
    const long tb = (long)hb * 64 + g * 4;
    lgn0 = lgws[(tb + 0) * 64 + 63];
    lgn1 = lgws[(tb + 1) * 64 + 63];
    lgn2 = lgws[(tb + 2) * 64 + 63];
    lgn3 = lgws[(tb + 3) * 64 + 63];
  };
  auto lwrite = [&](int g) {  // regs -> LDS buffer g&1
    const int bu = g & 1;
#pragma unroll
    for (int cc = 0; cc < 4; ++cc) {
      *(bf16x8*)&Msm[bu][cc][srow][scol]     = mr0[cc];
      *(bf16x8*)&Msm[bu][cc][srow][scol + 8] = mr1[cc];
      *(bf16x8*)&Bsm[bu][cc][srow][scol]     = br0[cc];
      *(bf16x8*)&Bsm[bu][cc][srow][scol + 8] = br1[cc];
    }
    if (tid == 0) {
      lgsm[bu][0] = lgn0; lgsm[bu][1] = lgn1;
      lgsm[bu][2] = lgn2; lgsm[bu][3] = lgn3;
    }
  };

  gload(0);
  lwrite(0);
  gload(1);
  __syncthreads();   // buffer 0 ready; group-1 loads drained (prologue cost)

  for (int g = 0; g < 16; ++g) {
    const int bu = g & 1;
    if (g + 1 < 16) lwrite(g + 1);   // regs (drained at prev barrier) -> LDS
    if (g + 2 < 16) gload(g + 2);    // issue early; hidden under 4-chunk compute
#pragma unroll
    for (int cc = 0; cc < 4; ++cc) {
      const int c = g * 4 + cc;
      // boundary state S_c (pre-update) -> global; off critical path
      {
        bf16* sp = Sb + ((long)hb * 64 + c) * 4096;
#pragma unroll
        for (int ni = 0; ni < 4; ++ni)
#pragma unroll
          for (int r = 0; r < 4; ++r)
            sp[(wv * 16 + r0 + r) * 64 + ni * 16 + cn] = __float2bfloat16(Sreg[ni][r]);
      }
      bf16x8 sfr0 = *(const bf16x8*)&Ssm[wv * 16 + lm][lk8];
      bf16x8 sfr1 = *(const bf16x8*)&Ssm[wv * 16 + lm][lk8 + 32];
      f32x4 kacc[4] = {};
#pragma unroll
      for (int ni = 0; ni < 4; ++ni) {
        bf16x8 b0 = *(const bf16x8*)&Msm[bu][cc][ni * 16 + lm][lk8];
        kacc[ni] = __builtin_amdgcn_mfma_f32_16x16x32_bf16(sfr0, b0, kacc[ni], 0, 0, 0);
        bf16x8 b1 = *(const bf16x8*)&Msm[bu][cc][ni * 16 + lm][lk8 + 32];
        kacc[ni] = __builtin_amdgcn_mfma_f32_16x16x32_bf16(sfr1, b1, kacc[ni], 0, 0, 0);
      }
      const float eend = __expf(lgsm[bu][cc]);
#pragma unroll
      for (int ni = 0; ni < 4; ++ni)
#pragma unroll
        for (int r = 0; r < 4; ++r) {
          const float bv = bsh2f(Bsm[bu][cc][wv * 16 + r0 + r][ni * 16 + cn]);
          Sreg[ni][r] = eend * Sreg[ni][r] + kacc[ni][r] + bv;
          Ssm[wv * 16 + r0 + r][ni * 16 + cn] = f2bsh(Sreg[ni][r]);
        }
    }
    __syncthreads();   // group g reads done; g+1 LDS writes + g+2 loads drained
  }
}

// ---------------------------------------------------------------------------
// chunk_out (r2-validated): fully parallel over 2048 (b,h,chunk) tasks.
//   A[t,i]  = (q_t.k_i) * exp(lg_t - lg_i), i<=t
//   Dt[v,t] = U0[t,v] - (S0v . W^T)[v,t]
//   O[t,v]  = (e^{lg} q)_t . S0v  +  A . Dt
// ---------------------------------------------------------------------------
__global__ __launch_bounds__(256) void chunk_out(const bf16* __restrict__ qkv,
                                                 const bf16* __restrict__ Wws,
                                                 const bf16* __restrict__ U0ws,
                                                 const float* __restrict__ lgws,
                                                 const bf16* __restrict__ Sb,
                                                 float* __restrict__ o) {
  __shared__ short Qsm[64][72];   // q rows (later scaled in place by exp(lg_t))
  __shared__ short Ksm[64][72];   // k rows
  __shared__ short Wsm[64][72];   // W rows [t][dk]
  __shared__ short Usm[64][72];   // U0 rows [t][v]
  __shared__ short Amm[64][72];   // A rows [t][i]
  __shared__ short Dsm[64][72];   // Dt rows [v][t] (wave-private 16-row bands)
  __shared__ float lgs[64];

  const int blk = blockIdx.x;
  const int hb = blk & 31, c = blk >> 5;      // hb fast: qkv-row L2 reuse
  const long task = (long)hb * 64 + c;
  const int h = hb & 15, b = hb >> 4, kh = h >> 1;
  const long sb = (long)b * S_ + (long)c * CS_;
  const int tid = threadIdx.x, wv = tid >> 6, l = tid & 63;
  const int lm = l & 15, lk8 = (l >> 4) << 3;
  const int r0 = (l >> 4) << 2, cn = l & 15;
  const int srow = tid >> 2, scol = (tid & 3) * 16;

  // S0 fragments straight from global (L2-resident after chunk_state).
  const bf16* sp = Sb + task * 4096 + (wv * 16 + lm) * 64 + lk8;
  bf16x8 sfr0 = *(const bf16x8*)(sp);
  bf16x8 sfr1 = *(const bf16x8*)(sp + 32);

  {
    const bf16* qp = qkv + (sb + srow) * CDIM_ + kh * 64 + scol;
    const bf16* kp = qkv + (sb + srow) * CDIM_ + KEYD_ + kh * 64 + scol;
    const bf16* wp = Wws + task * 4096 + srow * 64 + scol;
    const bf16* up = U0ws + task * 4096 + srow * 64 + scol;
    *(bf16x8*)&Qsm[srow][scol]     = *(const bf16x8*)(qp);
    *(bf16x8*)&Qsm[srow][scol + 8] = *(const bf16x8*)(qp + 8);
    *(bf16x8*)&Ksm[srow][scol]     = *(const bf16x8*)(kp);
    *(bf16x8*)&Ksm[srow][scol + 8] = *(const bf16x8*)(kp + 8);
    *(bf16x8*)&Wsm[srow][scol]     = *(const bf16x8*)(wp);
    *(bf16x8*)&Wsm[srow][scol + 8] = *(const bf16x8*)(wp + 8);
    *(bf16x8*)&Usm[srow][scol]     = *(const bf16x8*)(up);
    *(bf16x8*)&Usm[srow][scol + 8] = *(const bf16x8*)(up + 8);
    if (tid < 64) lgs[tid] = lgws[task * 64 + tid];
  }
  __syncthreads();

  // A matrix: wave computes its 16 t-rows x all i.
  {
    f32x4 aacc[4] = {};
#pragma unroll
    for (int ks = 0; ks < 2; ++ks) {
      bf16x8 qa = *(const bf16x8*)&Qsm[wv * 16 + lm][lk8 + ks * 32];
#pragma unroll
      for (int ni = 0; ni < 4; ++ni) {
        bf16x8 kb = *(const bf16x8*)&Ksm[ni * 16 + lm][lk8 + ks * 32];
        aacc[ni] = __builtin_amdgcn_mfma_f32_16x16x32_bf16(qa, kb, aacc[ni], 0, 0, 0);
      }
    }
#pragma unroll
    for (int ni = 0; ni < 4; ++ni)
#pragma unroll
      for (int r = 0; r < 4; ++r) {
        const int t = wv * 16 + r0 + r, i = ni * 16 + cn;
        Amm[t][i] = f2bsh((i <= t) ? aacc[ni][r] * __expf(lgs[t] - lgs[i]) : 0.f);
      }
  }
  __syncthreads();  // all A-reads of Qsm done; now safe to scale Q in place

  {
    const float sc = __expf(lgs[srow]);       // Lambda_t
#pragma unroll
    for (int j = 0; j < 16; ++j)
      Qsm[srow][scol + j] = f2bsh(sc * bsh2f(Qsm[srow][scol + j]));
  }
  __syncthreads();

  // M1: Dt[v,t] = U0[t,v] - sum_k S0v[v,k] W[t,k]
  {
    f32x4 dacc[4] = {};
#pragma unroll
    for (int ni = 0; ni < 4; ++ni) {
      bf16x8 w0 = *(const bf16x8*)&Wsm[ni * 16 + lm][lk8];
      dacc[ni] = __builtin_amdgcn_mfma_f32_16x16x32_bf16(sfr0, w0, dacc[ni], 0, 0, 0);
      bf16x8 w1 = *(const bf16x8*)&Wsm[ni * 16 + lm][lk8 + 32];
      dacc[ni] = __builtin_amdgcn_mfma_f32_16x16x32_bf16(sfr1, w1, dacc[ni], 0, 0, 0);
    }
#pragma unroll
    for (int ni = 0; ni < 4; ++ni)
#pragma unroll
      for (int r = 0; r < 4; ++r) {
        const int t = ni * 16 + cn, v = r0 + r;
        Dsm[wv * 16 + v][t] = f2bsh(bsh2f(Usm[t][wv * 16 + v]) - dacc[ni][r]);
      }
  }
  // wave-private Dsm: in-wave ds ordering + compiler lgkmcnt suffice (no barrier)
  bf16x8 dfr0 = *(const bf16x8*)&Dsm[wv * 16 + lm][lk8];
  bf16x8 dfr1 = *(const bf16x8*)&Dsm[wv * 16 + lm][lk8 + 32];

  // M2+M3: O[t, v16] = LambdaQ . S0v + A . Dt
  {
    f32x4 oacc[4] = {};
#pragma unroll
    for (int mi = 0; mi < 4; ++mi) {
      bf16x8 q0 = *(const bf16x8*)&Qsm[mi * 16 + lm][lk8];
      oacc[mi] = __builtin_amdgcn_mfma_f32_16x16x32_bf16(q0, sfr0, oacc[mi], 0, 0, 0);
      bf16x8 q1 = *(const bf16x8*)&Qsm[mi * 16 + lm][lk8 + 32];
      oacc[mi] = __builtin_amdgcn_mfma_f32_16x16x32_bf16(q1, sfr1, oacc[mi], 0, 0, 0);
    }
#pragma unroll
    for (int mi = 0; mi < 4; ++mi) {
      bf16x8 a0 = *(const bf16x8*)&Amm[mi * 16 + lm][lk8];
      oacc[mi] = __builtin_amdgcn_mfma_f32_16x16x32_bf16(a0, dfr0, oacc[mi], 0, 0, 0);
      bf16x8 a1 = *(const bf16x8*)&Amm[mi * 16 + lm][lk8 + 32];
      oacc[mi] = __builtin_amdgcn_mfma_f32_16x16x32_bf16(a1, dfr1, oacc[mi], 0, 0, 0);
    }
#pragma unroll
    for (int mi = 0; mi < 4; ++mi)
#pragma unroll
      for (int r = 0; r < 4; ++r) {
        const int t = mi * 16 + r0 + r;
        o[(sb + t) * VALD_ + h * 64 + wv * 16 + cn] = oacc[mi][r];
      }
  }
}

// ---------------------------------------------------------------------------
// gnorm3 (r5-validated): h = o*silu(z); rmsnorm; *w -> bf16 hn. Vectorized.
// ---------------------------------------------------------------------------
__global__ __launch_bounds__(256) void gnorm3(const float* __restrict__ o,
                                              const float* __restrict__ z,
                                              const float* __restrict__ nw,
                                              bf16* __restrict__ hn) {
  const long idx = (long)blockIdx.x * 256 + threadIdx.x;  // M*16
  const float* op = o + idx * 64;
  const float* zp = z + idx * 64;
  float4 hv[16];
  float ss = 0.f;
#pragma unroll
  for (int i = 0; i < 16; ++i) {
    const float4 ov = *(const float4*)(op + i * 4);
    const float4 zv = *(const float4*)(zp + i * 4);
    float4 h;
    h.x = ov.x * (zv.x / (1.f + __expf(-zv.x)));
    h.y = ov.y * (zv.y / (1.f + __expf(-zv.y)));
    h.z = ov.z * (zv.z / (1.f + __expf(-zv.z)));
    h.w = ov.w * (zv.w / (1.f + __expf(-zv.w)));
    hv[i] = h;
    ss = fmaf(h.x, h.x, ss); ss = fmaf(h.y, h.y, ss);
    ss = fmaf(h.z, h.z, ss); ss = fmaf(h.w, h.w, ss);
  }
  const float r = rsqrtf(ss * (1.f / 64.f) + 1e-6f);
#pragma unroll
  for (int i = 0; i < 16; i += 2) {
    const float4 w0 = *(const float4*)(nw + i * 4);
    const float4 w1 = *(const float4*)(nw + i * 4 + 4);
    bf16x8 pk;
    pk[0] = f2bsh(hv[i].x * r * w0.x);     pk[1] = f2bsh(hv[i].y * r * w0.y);
    pk[2] = f2bsh(hv[i].z * r * w0.z);     pk[3] = f2bsh(hv[i].w * r * w0.w);
    pk[4] = f2bsh(hv[i + 1].x * r * w1.x); pk[5] = f2bsh(hv[i + 1].y * r * w1.y);
    pk[6] = f2bsh(hv[i + 1].z * r * w1.z); pk[7] = f2bsh(hv[i + 1].w * r * w1.w);
    *(bf16x8*)((uint16_t*)hn + idx * 64 + i * 4) = pk;
  }
}

// ---------------------------------------------------------------------------
extern "C" void kernel_launch(void* const* d_in, const int* in_sizes, int n_in,
                              void* d_out, int out_size, void* d_ws, size_t ws_size,
                              hipStream_t stream) {
  float* out = (float*)d_out;   // fp32 output (r8-confirmed)
  const int M = B_ * S_;        // 8192

  // input mapping (dict order confirmed; size-based fallback kept)
  int ih, iqkv, icw, iz, ib, ia, idtb, ialog, inw, iout;
  if (n_in >= 10 && in_sizes[0] == 8388608) {
    ih = 0; iqkv = 1; icw = 2; iz = 3; ib = 4; ia = 5;
    idtb = 6; ialog = 7; inw = 8; iout = 9;
  } else {
    ih = iqkv = icw = iz = ib = ia = idtb = ialog = inw = iout = -1;
    for (int i = 0; i < n_in; ++i) {
      switch (in_sizes[i]) {
        case 8388608: ih = i; break;
        case 2097152: iqkv = i; break;
        case 8192:    icw = i; break;
        case 64:      inw = i; break;
        case 1048576: if (iz < 0) iz = i; else iout = i; break;
        case 16384:   if (ib < 0) ib = i; else ia = i; break;
        case 16:      if (idtb < 0) idtb = i; else ialog = i; break;
        default: break;
      }
    }
  }
  const float* hs   = (const float*)d_in[ih];
  const float* Wqkv = (const float*)d_in[iqkv];
  const float* cw   = (const float*)d_in[icw];
  const float* Wz   = (const float*)d_in[iz];
  const float* Wb   = (const float*)d_in[ib];
  const float* Wa   = (const float*)d_in[ia];
  const float* dtb  = (const float*)d_in[idtb];
  const float* Alog = (const float*)d_in[ialog];
  const float* nwv  = (const float*)d_in[inw];
  const float* Wout = (const float*)d_in[iout];

  // workspace (~122 MiB): r2 layout; Mc/Bc alias region1 (mixed dead after
  // conv; of not written until chunk_out).
  char* p = (char*)d_ws;
  bf16*  mixed = (bf16*)p;                                 // region1: 32 MiB
  float* of    = (float*)p;                                //   of aliases mixed
  bf16*  McTw  = (bf16*)p;                                 //   McT: first 16 MiB
  bf16*  Bcw   = (bf16*)(p + (size_t)2048 * 4096 * 2);     //   Bc: second 16 MiB
  p += (size_t)M * CDIM_ * 2;
  bf16*  hs_b  = (bf16*)p;                                 // region2 (16 MiB; dead after z-gemm)
  bf16*  qkvb  = (bf16*)p;                                 //   full region2
  bf16*  hn    = (bf16*)p; p += (size_t)M * CDIM_ * 2;     //   hn aliases qkvb
  bf16*  Wqkv_b= (bf16*)p; p += (size_t)CDIM_ * H_ * 2;    // 4 MiB
  bf16*  Wz_b  = (bf16*)p; p += (size_t)H_ * H_ * 2;       // 2 MiB
  bf16*  Wout_b= (bf16*)p; p += (size_t)H_ * H_ * 2;       // 2 MiB
  float* betaf = (float*)p; p += (size_t)M * NVH_ * 4;     // 512 KiB
  float* gf    = (float*)p; p += (size_t)M * NVH_ * 4;     // 512 KiB
  bf16*  Wws   = (bf16*)p; p += (size_t)2048 * 4096 * 2;   // 16 MiB
  bf16*  U0ws  = (bf16*)p; p += (size_t)2048 * 4096 * 2;   // 16 MiB
  float* lgws  = (float*)p; p += (size_t)2048 * 64 * 4;    // 512 KiB
  bf16*  Sbw   = (bf16*)p; p += (size_t)2048 * 4096 * 2;   // 16 MiB (boundary states)
  float* zb    = out;   // z fp32 staged in d_out, consumed by gnorm3

  // 0) casts fp32 -> bf16 for MFMA operands
  {
    long n;
    n = (long)M * H_;     castf2b<<<(int)(n / 4 / 256), 256, 0, stream>>>(hs,   hs_b,   n);
    n = (long)CDIM_ * H_; castf2b<<<(int)(n / 4 / 256), 256, 0, stream>>>(Wqkv, Wqkv_b, n);
    n = (long)H_ * H_;    castf2b<<<(int)(n / 4 / 256), 256, 0, stream>>>(Wz,   Wz_b,   n);
    n = (long)H_ * H_;    castf2b<<<(int)(n / 4 / 256), 256, 0, stream>>>(Wout, Wout_b, n);
  }
  // 1) mixed = hs @ Wqkv^T  [8192 x 2048] -> bf16 (MFMA)
  gemm_bt<bf16><<<(M / 128) * (CDIM_ / 128), 256, 0, stream>>>(hs_b, Wqkv_b, mixed, M, CDIM_, H_);
  // 2) z = hs @ Wz^T  [8192 x 1024] -> fp32 in d_out (MFMA)
  gemm_bt<float><<<(M / 128) * (H_ / 128), 256, 0, stream>>>(hs_b, Wz_b, zb, M, H_, H_);
  // 3) beta, g (8 rows per block)
  proj_ba2<<<M / 8, 256, 0, stream>>>(hs, Wb, Wa, dtb, Alog, betaf, gf);
  // 4) causal depthwise conv + silu + q-scale -> bf16 (8 ch/thread vectorized)
  conv3<<<(int)(((long)M * CDIM_) / 8 / 256), 256, 0, stream>>>(mixed, cw, qkvb);
  // 5) chunked delta-rule, decoupled:
  //    a) UT-transform precompute + affine transition pieces (fused; 2048 WGs)
  chunk_pre<<<2048, 256, 0, stream>>>(qkvb, betaf, gf, Wws, U0ws, lgws, McTw, Bcw);
  //    b) serial boundary-state recurrence (32 WGs, 4 chunks/barrier-group)
  chunk_state<<<32, 256, 0, stream>>>(McTw, Bcw, lgws, Sbw);
  //    c) per-chunk outputs (parallel 2048)
  chunk_out<<<2048, 256, 0, stream>>>(qkvb, Wws, U0ws, lgws, Sbw, of);
  // 6) gated RMSNorm -> hn bf16 (vectorized)
  gnorm3<<<(M * NVH_) / 256, 256, 0, stream>>>(of, zb, nwv, hn);
  // 7) out = hn @ Wout^T -> d_out fp32 (MFMA)
  gemm_bt<float><<<(M / 128) * (H_ / 128), 256, 0, stream>>>(hn, Wout_b, out, M, H_, H_);
}